// Round 1
// baseline (5586.741 us; speedup 1.0000x reference)
//
#include <hip/hip_runtime.h>
#include <float.h>
#include <math.h>

// Problem constants
#define BB 256
#define DD 512
#define NN 50000
#define KK 32
#define CHUNK 12500

// Workspace layout (float offsets)
#define OFF_G     0         // 512*512  Gram X^TX -> SigmaX (zeroed)
#define OFF_SC    262144    // 64 scalars (zeroed): 0=sumTc2 1=trCX 2=S_total 3=knn 4=wreg
#define OFF_CS    262208    // 512 colsum X (zeroed)
#define OFF_CSS   262720    // 512 colsumsq X (zeroed)
#define ZERO_F    263232    // bytes to memset = ZERO_F*4
#define OFF_T     263232    // 256*512
#define OFF_TC    394304    // 256*512
#define OFF_P     525376    // 256*512
#define OFF_H     656448    // 256*256
#define OFF_DDI   721984    // 256 tridiag diag
#define OFF_EEO   722240    // 256 tridiag offdiag
#define OFF_MUT   722496    // 512
#define OFF_XSQ   723008    // 50000
#define OFF_RUNV  773008    // 256*32
#define OFF_RUNI  781200    // 256*32 (int)
#define OFF_PW    789392    // 256*32 post_w
#define OFF_PRW   797584    // 256*32 pre_w normalized
#define OFF_D2    805776    // 256*12500

__device__ __forceinline__ float waveSum(float v) {
#pragma unroll
  for (int off = 32; off > 0; off >>= 1) v += __shfl_xor(v, off);
  return v;
}

// ---------------- T = A[256,512] @ B[512,512] ----------------
__global__ void k_gemm_nn(const float* __restrict__ A, const float* __restrict__ Bm,
                          float* __restrict__ C) {
  __shared__ float As[16][17], Bs[16][17];
  int tx = threadIdx.x, ty = threadIdx.y;
  int row = blockIdx.y * 16 + ty;
  int col = blockIdx.x * 16 + tx;
  float acc = 0.f;
  for (int k0 = 0; k0 < 512; k0 += 16) {
    As[ty][tx] = A[row * 512 + k0 + tx];
    Bs[ty][tx] = Bm[(k0 + ty) * 512 + col];
    __syncthreads();
#pragma unroll
    for (int kk = 0; kk < 16; ++kk) acc += As[ty][kk] * Bs[kk][tx];
    __syncthreads();
  }
  C[row * 512 + col] = acc;
}

// ---------------- H = P[256,512] @ Tc[256,512]^T / 255 ----------------
__global__ void k_gemm_nt_H(const float* __restrict__ A, const float* __restrict__ Bm,
                            float* __restrict__ C) {
  __shared__ float As[16][17], Bs[16][17];
  int tx = threadIdx.x, ty = threadIdx.y;
  int row = blockIdx.y * 16 + ty;
  int col0 = blockIdx.x * 16;
  float acc = 0.f;
  for (int k0 = 0; k0 < 512; k0 += 16) {
    As[ty][tx] = A[row * 512 + k0 + tx];
    Bs[ty][tx] = Bm[(col0 + ty) * 512 + k0 + tx];  // Bs[jlocal][klocal]
    __syncthreads();
#pragma unroll
    for (int kk = 0; kk < 16; ++kk) acc += As[ty][kk] * Bs[tx][kk];
    __syncthreads();
  }
  C[row * 256 + col0 + tx] = acc * (1.0f / 255.0f);
}

// ---------------- column sums & sumsq of X (atomic) ----------------
__global__ void k_colstatX(const float* __restrict__ X, float* __restrict__ colsum,
                           float* __restrict__ colss) {
  int b = blockIdx.x, t = threadIdx.x;
  int r0 = b * 196;
  int r1 = r0 + 196; if (r1 > NN) r1 = NN;
  float s1 = 0, ss1 = 0, s2 = 0, ss2 = 0;
  for (int r = r0; r < r1; ++r) {
    float v1 = X[r * 512 + t], v2 = X[r * 512 + t + 256];
    s1 += v1; ss1 += v1 * v1; s2 += v2; ss2 += v2 * v2;
  }
  atomicAdd(&colsum[t], s1);       atomicAdd(&colss[t], ss1);
  atomicAdd(&colsum[t + 256], s2); atomicAdd(&colss[t + 256], ss2);
}

// ---------------- per-row squared norm of X ----------------
__global__ void k_xsq(const float* __restrict__ X, float* __restrict__ xsq) {
  int row = blockIdx.x * 4 + (threadIdx.x >> 6);
  int lane = threadIdx.x & 63;
  const float* Xr = X + row * 512;
  float s = 0.f;
#pragma unroll
  for (int d = 0; d < 8; ++d) { float v = Xr[lane + 64 * d]; s += v * v; }
  s = waveSum(s);
  if (lane == 0) xsq[row] = s;
}

// ---------------- G += X^T X  (split-K, atomic) ----------------
__global__ void __launch_bounds__(256) k_xtx(const float* __restrict__ X, float* __restrict__ G) {
  __shared__ float Ai[16][132], Aj[16][132];
  int bi = blockIdx.x, bj = blockIdx.y;
  int k0 = blockIdx.z * 2000;
  int t = threadIdx.x;
  int tr = t >> 4, tc = t & 15;
  float acc[8][8] = {{0.f}};
  const float* Xi = X + k0 * 512 + bi * 128;
  const float* Xj = X + k0 * 512 + bj * 128;
  for (int kb = 0; kb < 2000; kb += 16) {
#pragma unroll
    for (int p2 = 0; p2 < 8; ++p2) {
      int l = t + 256 * p2;
      int kk = l >> 7, ii = l & 127;
      Ai[kk][ii] = Xi[(kb + kk) * 512 + ii];
      Aj[kk][ii] = Xj[(kb + kk) * 512 + ii];
    }
    __syncthreads();
#pragma unroll
    for (int kk = 0; kk < 16; ++kk) {
      float a[8], b[8];
#pragma unroll
      for (int u = 0; u < 8; ++u) a[u] = Ai[kk][tr * 8 + u];
#pragma unroll
      for (int v = 0; v < 8; ++v) b[v] = Aj[kk][tc * 8 + v];
#pragma unroll
      for (int u = 0; u < 8; ++u)
#pragma unroll
        for (int v = 0; v < 8; ++v) acc[u][v] += a[u] * b[v];
    }
    __syncthreads();
  }
#pragma unroll
  for (int u = 0; u < 8; ++u)
#pragma unroll
    for (int v = 0; v < 8; ++v)
      atomicAdd(&G[(bi * 128 + tr * 8 + u) * 512 + bj * 128 + tc * 8 + v], acc[u][v]);
}

// ---------------- column means of T ----------------
__global__ void k_colmeanT(const float* __restrict__ T, float* __restrict__ mu) {
  int c = threadIdx.x;
  float s = 0.f;
  for (int r = 0; r < 256; ++r) s += T[r * 512 + c];
  mu[c] = s * (1.0f / 256.0f);
}

// ---------------- Tc = T - mu, accumulate sum(Tc^2) ----------------
__global__ void k_centerT(const float* __restrict__ T, const float* __restrict__ mu,
                          float* __restrict__ Tc, float* __restrict__ scal) {
  __shared__ float red[4];
  int t = threadIdx.x;
  int base = blockIdx.x * 1024;
  float ss = 0.f;
#pragma unroll
  for (int p = 0; p < 4; ++p) {
    int l = base + p * 256 + t;
    float v = T[l] - mu[l & 511];
    Tc[l] = v;
    ss += v * v;
  }
  ss = waveSum(ss);
  if ((t & 63) == 0) red[t >> 6] = ss;
  __syncthreads();
  if (t == 0) atomicAdd(&scal[0], red[0] + red[1] + red[2] + red[3]);
}

// ---------------- trace of cov(X) ----------------
__global__ void k_trCX(const float* __restrict__ colsum, const float* __restrict__ colss,
                       float* __restrict__ scal) {
  __shared__ float red[8];
  int t = threadIdx.x;  // 512
  float mu = colsum[t] * (1.0f / 50000.0f);
  float v = (colss[t] - 50000.0f * mu * mu) * (1.0f / 49999.0f);
  v = waveSum(v);
  if ((t & 63) == 0) red[t >> 6] = v;
  __syncthreads();
  if (t == 0) {
    float s = 0;
    for (int i = 0; i < 8; ++i) s += red[i];
    scal[1] = s;
  }
}

// ---------------- finalize SigmaX in place on G ----------------
__global__ void k_finSX(float* __restrict__ G, const float* __restrict__ colsum,
                        const float* __restrict__ scal) {
  int i = blockIdx.y * 16 + threadIdx.y, j = blockIdx.x * 16 + threadIdx.x;
  if (i > j) return;
  float mi = colsum[i] * (1.0f / 50000.0f), mj = colsum[j] * (1.0f / 50000.0f);
  float g = 0.5f * (G[i * 512 + j] + G[j * 512 + i]);
  float v = (g - 50000.0f * mi * mj) * (1.0f / 49999.0f);
  if (i == j) v += scal[1] * (1e-3f / 512.0f);
  G[i * 512 + j] = v;
  G[j * 512 + i] = v;
}

// ---------------- Householder tridiagonalization of H (256x256), single block ----------------
__global__ void __launch_bounds__(1024) k_tridiag(float* __restrict__ A, float* __restrict__ dd,
                                                  float* __restrict__ ee) {
  const int n = 256;
  __shared__ float xv[256], vsh[256], wsh[256], pr[4][256];
  __shared__ float red[4];
  __shared__ float sc[3];
  int t = threadIdx.x;
  int ii = t & 255, jj = t >> 8;
  for (int k = 0; k < n - 2; ++k) {
    int m = n - 1 - k;
    if (jj == 0) xv[ii] = (ii < m) ? A[k * n + (k + 1) + ii] : 0.f;
    __syncthreads();
    if (t < 256) {
      float s = xv[t] * xv[t];
      s = waveSum(s);
      if ((t & 63) == 0) red[t >> 6] = s;
    }
    __syncthreads();
    if (t == 0) {
      float sigma2 = red[0] + red[1] + red[2] + red[3];
      float x0 = xv[0];
      float sg = sqrtf(sigma2);
      float alpha = (x0 >= 0.f) ? -sg : sg;
      float v0 = x0 - alpha;
      float vn2 = sigma2 - x0 * x0 + v0 * v0;
      sc[0] = alpha;
      sc[1] = (vn2 > 1e-30f) ? 2.0f / vn2 : 0.f;
      dd[k] = A[k * n + k];
      ee[k] = alpha;
    }
    __syncthreads();
    float beta = sc[1];
    if (jj == 0) vsh[ii] = (ii == 0) ? (xv[0] - sc[0]) : xv[ii];
    __syncthreads();
    float pa = 0.f;
    if (ii < m) {
      for (int j2 = jj; j2 < m; j2 += 4)
        pa += A[(k + 1 + j2) * n + (k + 1) + ii] * vsh[j2];
    }
    pr[jj][ii] = pa;
    __syncthreads();
    if (t < 256) {
      float pi = beta * (pr[0][t] + pr[1][t] + pr[2][t] + pr[3][t]);
      wsh[t] = pi;
      float pvp = pi * vsh[t];
      pvp = waveSum(pvp);
      if ((t & 63) == 0) red[t >> 6] = pvp;
    }
    __syncthreads();
    if (t == 0) sc[2] = beta * (red[0] + red[1] + red[2] + red[3]) * 0.5f;
    __syncthreads();
    if (t < 256) wsh[t] = wsh[t] - sc[2] * vsh[t];
    __syncthreads();
    if (ii < m) {
      float wi = wsh[ii], vi = vsh[ii];
      for (int i2 = jj; i2 < m; i2 += 4) {
        int rowb = (k + 1 + i2) * n + (k + 1);
        A[rowb + ii] -= vsh[i2] * wi + wsh[i2] * vi;
      }
    }
    __syncthreads();
  }
  if (t == 0) {
    dd[n - 2] = A[(n - 2) * n + (n - 2)];
    ee[n - 2] = A[(n - 2) * n + (n - 1)];
    dd[n - 1] = A[(n - 1) * n + (n - 1)];
    ee[n - 1] = 0.f;
  }
}

// ---------------- Sturm bisection: S_total = sum sqrt(r_t + lambda_k) + 256*sqrt(r_t) ----------------
__global__ void __launch_bounds__(256) k_bisect(const float* __restrict__ ddg,
                                                const float* __restrict__ eeg,
                                                float* __restrict__ scal) {
  __shared__ float d[256], e2[256];
  __shared__ float rlo[4], rhi[4], red[4];
  int t = threadIdx.x;
  d[t] = ddg[t];
  float ev = (t < 255) ? eeg[t] : 0.f;
  e2[t] = ev * ev;
  __syncthreads();
  float rr = ((t > 0) ? fabsf(eeg[t - 1]) : 0.f) + ((t < 255) ? fabsf(eeg[t]) : 0.f);
  float lo = d[t] - rr, hi = d[t] + rr;
#pragma unroll
  for (int off = 32; off > 0; off >>= 1) {
    lo = fminf(lo, __shfl_xor(lo, off));
    hi = fmaxf(hi, __shfl_xor(hi, off));
  }
  if ((t & 63) == 0) { rlo[t >> 6] = lo; rhi[t >> 6] = hi; }
  __syncthreads();
  float LO = fminf(fminf(rlo[0], rlo[1]), fminf(rlo[2], rlo[3])) - 1e-2f;
  float HI = fmaxf(fmaxf(rhi[0], rhi[1]), fmaxf(rhi[2], rhi[3])) + 1e-2f;
  float a2 = LO, b2 = HI;
  for (int itr = 0; itr < 44; ++itr) {
    float mid = 0.5f * (a2 + b2);
    int cnt = 0;
    float qq = d[0] - mid;
    if (fabsf(qq) < 1e-25f) qq = -1e-25f;
    if (qq < 0.f) cnt++;
    for (int i = 1; i < 256; ++i) {
      qq = d[i] - mid - e2[i - 1] / qq;
      if (fabsf(qq) < 1e-25f) qq = -1e-25f;
      if (qq < 0.f) cnt++;
    }
    if (cnt <= t) a2 = mid; else b2 = mid;
  }
  float lam = 0.5f * (a2 + b2);
  float rt = scal[0] * (1.0f / 255.0f) * (1e-3f / 512.0f);
  float val = sqrtf(fmaxf(rt + lam, 0.f));
  val = waveSum(val);
  if ((t & 63) == 0) red[t >> 6] = val;
  __syncthreads();
  if (t == 0) scal[2] = red[0] + red[1] + red[2] + red[3] + 256.0f * sqrtf(rt);
}

// ---------------- d2 chunk GEMM: out[i][j] = xsq[base+j] - 2*dot(T[i],X[base+j]) ----------------
__global__ void __launch_bounds__(256) k_d2(const float* __restrict__ T, const float* __restrict__ X,
                                            const float* __restrict__ xsq, float* __restrict__ out,
                                            int base) {
  __shared__ float Ts[16][132], Xs[16][132];
  int bi = blockIdx.x, bj = blockIdx.y;
  int t = threadIdx.x;
  int tr = t >> 4, tc = t & 15;
  float acc[8][8] = {{0.f}};
  for (int k0 = 0; k0 < 512; k0 += 16) {
#pragma unroll
    for (int p2 = 0; p2 < 8; ++p2) {
      int l = t + 256 * p2;
      int kk = l & 15, r = l >> 4;
      Ts[kk][r] = T[(bi * 128 + r) * 512 + k0 + kk];
      int jg = bj * 128 + r;
      if (jg > CHUNK - 1) jg = CHUNK - 1;
      Xs[kk][r] = X[(base + jg) * 512 + k0 + kk];
    }
    __syncthreads();
#pragma unroll
    for (int kk = 0; kk < 16; ++kk) {
      float a[8], b[8];
#pragma unroll
      for (int u = 0; u < 8; ++u) a[u] = Ts[kk][tr * 8 + u];
#pragma unroll
      for (int v = 0; v < 8; ++v) b[v] = Xs[kk][tc * 8 + v];
#pragma unroll
      for (int u = 0; u < 8; ++u)
#pragma unroll
        for (int v = 0; v < 8; ++v) acc[u][v] += a[u] * b[v];
    }
    __syncthreads();
  }
#pragma unroll
  for (int u = 0; u < 8; ++u) {
    int i = bi * 128 + tr * 8 + u;
#pragma unroll
    for (int v = 0; v < 8; ++v) {
      int j = bj * 128 + tc * 8 + v;
      if (j < CHUNK) out[i * CHUNK + j] = xsq[base + j] - 2.0f * acc[u][v];
    }
  }
}

// ---------------- init running top-k ----------------
__global__ void k_topk_init(float* __restrict__ runv, int* __restrict__ runi) {
  int i = blockIdx.x * 256 + threadIdx.x;
  runv[i] = FLT_MAX;
  runi[i] = 0x7fffffff;
}

// ---------------- per-query top-32 merge over one chunk ----------------
__global__ void __launch_bounds__(128) k_topk_merge(const float* __restrict__ d2c,
                                                    float* __restrict__ runv, int* __restrict__ runi,
                                                    int base) {
  __shared__ float cv[128 * 32];
  __shared__ int ci[128 * 32];
  __shared__ float rv[2];
  __shared__ int rgi[2], rsl[2];
  int q = blockIdx.x, t = threadIdx.x;
  float* mv = &cv[t * 32];
  int* mi = &ci[t * 32];
  int cnt = 0;
  float wval = -FLT_MAX; int widx = 0, wpos = 0;
  auto recompute = [&]() {
    wval = mv[0]; widx = mi[0]; wpos = 0;
    for (int s = 1; s < 32; ++s) {
      float a = mv[s]; int b2 = mi[s];
      if (a > wval || (a == wval && b2 > widx)) { wval = a; widx = b2; wpos = s; }
    }
  };
  auto push = [&](float val, int idx) {
    if (cnt < 32) {
      mv[cnt] = val; mi[cnt] = idx;
      if (++cnt == 32) recompute();
    } else if (val < wval || (val == wval && idx < widx)) {
      mv[wpos] = val; mi[wpos] = idx;
      recompute();
    }
  };
  if (t < 32) push(runv[q * 32 + t], runi[q * 32 + t]);
  for (int j = t; j < CHUNK; j += 128) push(d2c[q * CHUNK + j], base + j);
  for (int s = cnt; s < 32; ++s) { mv[s] = FLT_MAX; mi[s] = 0x7fffffff; }
  __syncthreads();
  for (int r = 0; r < 32; ++r) {
    float bv = FLT_MAX; int bi2 = 0x7fffffff, bs = t * 32;
    for (int s = 0; s < 32; ++s) {
      float a = cv[t * 32 + s]; int b2 = ci[t * 32 + s];
      if (a < bv || (a == bv && b2 < bi2)) { bv = a; bi2 = b2; bs = t * 32 + s; }
    }
#pragma unroll
    for (int off = 32; off > 0; off >>= 1) {
      float ov = __shfl_down(bv, off);
      int oi = __shfl_down(bi2, off);
      int os = __shfl_down(bs, off);
      if (ov < bv || (ov == bv && oi < bi2)) { bv = ov; bi2 = oi; bs = os; }
    }
    int w = t >> 6;
    if ((t & 63) == 0) { rv[w] = bv; rgi[w] = bi2; rsl[w] = bs; }
    __syncthreads();
    if (t == 0) {
      float v0 = rv[0]; int i0 = rgi[0], s0 = rsl[0];
      if (rv[1] < v0 || (rv[1] == v0 && rgi[1] < i0)) { v0 = rv[1]; i0 = rgi[1]; s0 = rsl[1]; }
      runv[q * 32 + r] = v0;
      runi[q * 32 + r] = i0;
      cv[s0] = FLT_MAX; ci[s0] = 0x7fffffff;
    }
    __syncthreads();
  }
}

// ---------------- l2 to neighbors, softmax post_w, normalized pre_w ----------------
__global__ void __launch_bounds__(64) k_l2soft(const float* __restrict__ T, const float* __restrict__ X,
                                               const int* __restrict__ runi, const int* __restrict__ qidx,
                                               const float* __restrict__ prew, float* __restrict__ postw,
                                               float* __restrict__ prewn) {
  __shared__ float l2s[32];
  int b = blockIdx.x, lane = threadIdx.x;
  int qi = qidx[b];
  float pwv = (lane < 32) ? fmaxf(prew[qi * 32 + lane], 1e-8f) : 0.f;
  float psum = waveSum(pwv);
  if (lane < 32) prewn[b * 32 + lane] = pwv / psum;
  const float* Tb = T + b * 512;
  for (int n = 0; n < 32; ++n) {
    int nb = runi[b * 32 + n];
    const float* Xr = X + nb * 512;
    float acc = 0.f;
#pragma unroll
    for (int d = 0; d < 8; ++d) {
      float df = Tb[lane + 64 * d] - Xr[lane + 64 * d];
      acc += df * df;
    }
    acc = waveSum(acc);
    if (lane == 0) l2s[n] = acc;
  }
  __syncthreads();
  float lg = (lane < 32) ? (-l2s[lane] * 10.0f) : -FLT_MAX;
  float mx = lg;
#pragma unroll
  for (int off = 32; off > 0; off >>= 1) mx = fmaxf(mx, __shfl_xor(mx, off));
  float e = (lane < 32) ? expf(lg - mx) : 0.f;
  float es = waveSum(e);
  float wv = e / es;
  wv = fmaxf(wv, 1e-8f);
  float ws2 = (lane < 32) ? wv : 0.f;
  ws2 = waveSum(ws2);
  if (lane < 32) postw[b * 32 + lane] = wv / ws2;
}

// ---------------- fused per-batch: Gram -> C -> median -> Sinkhorn(200) -> loss ----------------
__global__ void __launch_bounds__(256) k_batch(const float* __restrict__ X, const int* __restrict__ qidx,
                                               const int* __restrict__ pre_idx, const int* __restrict__ runi,
                                               const float* __restrict__ prewn, const float* __restrict__ postw,
                                               float* __restrict__ scal) {
  __shared__ float G[64][65];   // Gram, later reused as Kmat
  __shared__ float Cm[64][65];
  __shared__ float SB[4160];    // staging / sort buffer
  __shared__ int supp[64];
  __shared__ float pv[64], qv[64], uu[64], vv[64];
  __shared__ float rbuf[4][64];
  __shared__ float medsh;
  int b = blockIdx.x, t = threadIdx.x;
  if (t < 32) supp[t] = pre_idx[qidx[b] * 32 + t];
  else if (t < 64) supp[t] = runi[b * 32 + t - 32];
  __syncthreads();
  int tr = t >> 4, tc = t & 15;
  float acc[4][4] = {{0.f}};
  for (int kc = 0; kc < 512; kc += 64) {
    __syncthreads();
#pragma unroll
    for (int p2 = 0; p2 < 16; ++p2) {
      int l = t + 256 * p2;
      int r = l >> 6, c = l & 63;
      SB[r * 65 + c] = X[supp[r] * 512 + kc + c];
    }
    __syncthreads();
#pragma unroll 8
    for (int kk = 0; kk < 64; ++kk) {
      float a[4], bb[4];
#pragma unroll
      for (int u = 0; u < 4; ++u) a[u] = SB[(tr * 4 + u) * 65 + kk];
#pragma unroll
      for (int v = 0; v < 4; ++v) bb[v] = SB[(tc * 4 + v) * 65 + kk];
#pragma unroll
      for (int u = 0; u < 4; ++u)
#pragma unroll
        for (int v = 0; v < 4; ++v) acc[u][v] += a[u] * bb[v];
    }
  }
  __syncthreads();
#pragma unroll
  for (int u = 0; u < 4; ++u)
#pragma unroll
    for (int v = 0; v < 4; ++v) G[tr * 4 + u][tc * 4 + v] = acc[u][v];
  __syncthreads();
  for (int l = t; l < 4096; l += 256) {
    int i = l >> 6, j = l & 63;
    float cc = fmaxf(G[i][i] + G[j][j] - 2.0f * G[i][j], 0.f);
    Cm[i][j] = cc;
    SB[l] = cc;
  }
  // bitonic sort 4096 ascending
  for (int ssz = 2; ssz <= 4096; ssz <<= 1) {
    for (int st = ssz >> 1; st > 0; st >>= 1) {
      __syncthreads();
      for (int l = t; l < 2048; l += 256) {
        int i = 2 * l - (l & (st - 1));
        int j = i + st;
        bool up = ((i & ssz) == 0);
        float a = SB[i], b2 = SB[j];
        if ((a > b2) == up) { SB[i] = b2; SB[j] = a; }
      }
    }
  }
  __syncthreads();
  if (t == 0) medsh = 0.5f * (SB[2047] + SB[2048]) + 1e-8f;
  __syncthreads();
  float inv = 1.0f / medsh;
  for (int l = t; l < 4096; l += 256) {
    int i = l >> 6, j = l & 63;
    float cn = Cm[i][j] * inv;
    Cm[i][j] = cn;
    G[i][j] = expf(-cn * 10.0f);   // K = exp(-C/eps), eps=0.1
  }
  if (t < 64) {
    pv[t] = (t < 32) ? prewn[b * 32 + t] : 0.f;
    qv[t] = (t < 32) ? 0.f : postw[b * 32 + (t - 32)];
    uu[t] = 1.f; vv[t] = 1.f;
  }
  __syncthreads();
  int g = t >> 6, i0 = t & 63;
  for (int it = 0; it < 200; ++it) {
    float s2 = 0.f;
#pragma unroll
    for (int j2 = 0; j2 < 16; ++j2) s2 += G[i0][g * 16 + j2] * vv[g * 16 + j2];
    rbuf[g][i0] = s2;
    __syncthreads();
    if (t < 64) uu[t] = pv[t] / (rbuf[0][t] + rbuf[1][t] + rbuf[2][t] + rbuf[3][t] + 1e-16f);
    __syncthreads();
    s2 = 0.f;
#pragma unroll
    for (int j2 = 0; j2 < 16; ++j2) s2 += G[g * 16 + j2][i0] * uu[g * 16 + j2];
    rbuf[g][i0] = s2;
    __syncthreads();
    if (t < 64) vv[t] = qv[t] / (rbuf[0][t] + rbuf[1][t] + rbuf[2][t] + rbuf[3][t] + 1e-16f);
    __syncthreads();
  }
  float lacc = 0.f;
  for (int l = t; l < 4096; l += 256) {
    int i = l >> 6, j = l & 63;
    lacc += uu[i] * G[i][j] * vv[j] * Cm[i][j];
  }
  lacc = waveSum(lacc);
  if ((t & 63) == 0) rbuf[0][t >> 6] = lacc;
  __syncthreads();
  if (t == 0)
    atomicAdd(&scal[3], (rbuf[0][0] + rbuf[0][1] + rbuf[0][2] + rbuf[0][3]) * (1.0f / 256.0f));
}

// ---------------- sum(W^2) ----------------
__global__ void k_wreg(const float* __restrict__ W, float* __restrict__ scal) {
  __shared__ float red[4];
  int t = threadIdx.x;
  int base = blockIdx.x * 2048;
  float ss = 0.f;
#pragma unroll
  for (int p = 0; p < 8; ++p) {
    float v = W[base + p * 256 + t];
    ss += v * v;
  }
  ss = waveSum(ss);
  if ((t & 63) == 0) red[t >> 6] = ss;
  __syncthreads();
  if (t == 0) atomicAdd(&scal[4], red[0] + red[1] + red[2] + red[3]);
}

// ---------------- final combine ----------------
__global__ void k_combine(const float* __restrict__ mu_t, const float* __restrict__ colsum,
                          const float* __restrict__ scal, float* __restrict__ out) {
  __shared__ float red[8];
  int t = threadIdx.x;  // 512
  float dm = mu_t[t] - colsum[t] * (1.0f / 50000.0f);
  float v = dm * dm;
  v = waveSum(v);
  if ((t & 63) == 0) red[t >> 6] = v;
  __syncthreads();
  if (t == 0) {
    float term_mean = 0.f;
    for (int i = 0; i < 8; ++i) term_mean += red[i];
    float trCT = scal[0] * (1.0f / 255.0f);
    float trCX = scal[1];
    float S = scal[2];
    float term_cov = trCX * 1.001f + trCT * 1.001f - 2.0f * S;
    term_cov = fmaxf(term_cov, 0.f);
    float loss_dist = term_mean + term_cov;
    float loss_knn = scal[3];
    float loss_reg = 0.5f * scal[4];
    out[0] = loss_dist + loss_knn + 1e-4f * loss_reg;
    out[1] = loss_dist;
    out[2] = loss_knn;
  }
}

extern "C" void kernel_launch(void* const* d_in, const int* in_sizes, int n_in,
                              void* d_out, int out_size, void* d_ws, size_t ws_size,
                              hipStream_t stream) {
  const float* q = (const float*)d_in[0];
  const int* qidx = (const int*)d_in[1];
  const float* W = (const float*)d_in[2];
  const float* X = (const float*)d_in[3];
  const int* pre_idx = (const int*)d_in[4];
  const float* prew = (const float*)d_in[5];
  float* out = (float*)d_out;
  float* ws = (float*)d_ws;

  float* G = ws + OFF_G;
  float* scal = ws + OFF_SC;
  float* colsum = ws + OFF_CS;
  float* colss = ws + OFF_CSS;
  float* T = ws + OFF_T;
  float* Tc = ws + OFF_TC;
  float* P = ws + OFF_P;
  float* H = ws + OFF_H;
  float* ddi = ws + OFF_DDI;
  float* eeo = ws + OFF_EEO;
  float* mu_t = ws + OFF_MUT;
  float* xsq = ws + OFF_XSQ;
  float* runv = ws + OFF_RUNV;
  int* runi = (int*)(ws + OFF_RUNI);
  float* postw = ws + OFF_PW;
  float* prewn = ws + OFF_PRW;
  float* d2c = ws + OFF_D2;

  hipMemsetAsync(d_ws, 0, (size_t)ZERO_F * 4, stream);

  // T = q @ W
  k_gemm_nn<<<dim3(32, 16), dim3(16, 16), 0, stream>>>(q, W, T);
  // X column stats, per-row sq norms, X^T X
  k_colstatX<<<256, 256, 0, stream>>>(X, colsum, colss);
  k_xsq<<<12500, 256, 0, stream>>>(X, xsq);
  k_xtx<<<dim3(4, 4, 25), 256, 0, stream>>>(X, G);
  // T stats
  k_colmeanT<<<1, 512, 0, stream>>>(T, mu_t);
  k_centerT<<<128, 256, 0, stream>>>(T, mu_t, Tc, scal);
  // SigmaX
  k_trCX<<<1, 512, 0, stream>>>(colsum, colss, scal);
  k_finSX<<<dim3(32, 32), dim3(16, 16), 0, stream>>>(G, colsum, scal);
  // H = Tc SigmaX Tc^T / 255
  k_gemm_nn<<<dim3(32, 16), dim3(16, 16), 0, stream>>>(Tc, G, P);
  k_gemm_nt_H<<<dim3(16, 16), dim3(16, 16), 0, stream>>>(P, Tc, H);
  // spectral sum
  k_tridiag<<<1, 1024, 0, stream>>>(H, ddi, eeo);
  k_bisect<<<1, 256, 0, stream>>>(ddi, eeo, scal);
  // kNN
  k_topk_init<<<32, 256, 0, stream>>>(runv, runi);
  for (int c = 0; c < 4; ++c) {
    k_d2<<<dim3(2, 98), 256, 0, stream>>>(T, X, xsq, d2c, c * CHUNK);
    k_topk_merge<<<256, 128, 0, stream>>>(d2c, runv, runi, c * CHUNK);
  }
  k_l2soft<<<256, 64, 0, stream>>>(T, X, runi, qidx, prew, postw, prewn);
  k_batch<<<256, 256, 0, stream>>>(X, qidx, pre_idx, runi, prewn, postw, scal);
  k_wreg<<<128, 256, 0, stream>>>(W, scal);
  k_combine<<<1, 512, 0, stream>>>(mu_t, colsum, scal, out);
}

// Round 2
// 3684.886 us; speedup vs baseline: 1.5161x; 1.5161x over previous
//
#include <hip/hip_runtime.h>
#include <float.h>
#include <math.h>

// Problem constants
#define BB 256
#define DD 512
#define NN 50000
#define KK 32
#define CHUNK 12500
#define NS_ITERS 18

// Workspace layout (float offsets)
#define OFF_G     0         // 512*512  Gram X^TX -> SigmaX (zeroed); later NS "Pm" scratch
#define OFF_SC    262144    // 64 scalars (zeroed): 0=sumTc2 1=trCX 2=S_total 3=knn 4=wreg 5=gersh
#define OFF_CS    262208    // 512 colsum X (zeroed)
#define OFF_CSS   262720    // 512 colsumsq X (zeroed)
#define ZERO_F    263232    // floats to memset
#define OFF_T     263232    // 256*512
#define OFF_TC    394304    // 256*512 (dead after H -> NS Y/Z)
#define OFF_P     525376    // 256*512 (dead after H -> NS Y2/Z2)
#define OFF_H     656448    // 256*256
#define OFF_DDI   721984    // 256 (rowsum scratch)
#define OFF_EEO   722240    // 256
#define OFF_MUT   722496    // 512
#define OFF_XSQ   723008    // 50000
#define OFF_RUNV  773008    // 256*32
#define OFF_RUNI  781200    // 256*32 (int)
#define OFF_PW    789392    // 256*32 post_w
#define OFF_PRW   797584    // 256*32 pre_w normalized
#define OFF_D2    805776    // 256*12500

__device__ __forceinline__ float waveSum(float v) {
#pragma unroll
  for (int off = 32; off > 0; off >>= 1) v += __shfl_xor(v, off);
  return v;
}

// ---------------- T = A[256,512] @ B[512,512] ----------------
__global__ void k_gemm_nn(const float* __restrict__ A, const float* __restrict__ Bm,
                          float* __restrict__ C) {
  __shared__ float As[16][17], Bs[16][17];
  int tx = threadIdx.x, ty = threadIdx.y;
  int row = blockIdx.y * 16 + ty;
  int col = blockIdx.x * 16 + tx;
  float acc = 0.f;
  for (int k0 = 0; k0 < 512; k0 += 16) {
    As[ty][tx] = A[row * 512 + k0 + tx];
    Bs[ty][tx] = Bm[(k0 + ty) * 512 + col];
    __syncthreads();
#pragma unroll
    for (int kk = 0; kk < 16; ++kk) acc += As[ty][kk] * Bs[kk][tx];
    __syncthreads();
  }
  C[row * 512 + col] = acc;
}

// ---------------- H = P[256,512] @ Tc[256,512]^T / 255 ----------------
__global__ void k_gemm_nt_H(const float* __restrict__ A, const float* __restrict__ Bm,
                            float* __restrict__ C) {
  __shared__ float As[16][17], Bs[16][17];
  int tx = threadIdx.x, ty = threadIdx.y;
  int row = blockIdx.y * 16 + ty;
  int col0 = blockIdx.x * 16;
  float acc = 0.f;
  for (int k0 = 0; k0 < 512; k0 += 16) {
    As[ty][tx] = A[row * 512 + k0 + tx];
    Bs[ty][tx] = Bm[(col0 + ty) * 512 + k0 + tx];  // Bs[jlocal][klocal]
    __syncthreads();
#pragma unroll
    for (int kk = 0; kk < 16; ++kk) acc += As[ty][kk] * Bs[tx][kk];
    __syncthreads();
  }
  C[row * 256 + col0 + tx] = acc * (1.0f / 255.0f);
}

// ---------------- column sums & sumsq of X (atomic) ----------------
__global__ void k_colstatX(const float* __restrict__ X, float* __restrict__ colsum,
                           float* __restrict__ colss) {
  int b = blockIdx.x, t = threadIdx.x;
  int r0 = b * 196;
  int r1 = r0 + 196; if (r1 > NN) r1 = NN;
  float s1 = 0, ss1 = 0, s2 = 0, ss2 = 0;
  for (int r = r0; r < r1; ++r) {
    float v1 = X[r * 512 + t], v2 = X[r * 512 + t + 256];
    s1 += v1; ss1 += v1 * v1; s2 += v2; ss2 += v2 * v2;
  }
  atomicAdd(&colsum[t], s1);       atomicAdd(&colss[t], ss1);
  atomicAdd(&colsum[t + 256], s2); atomicAdd(&colss[t + 256], ss2);
}

// ---------------- per-row squared norm of X ----------------
__global__ void k_xsq(const float* __restrict__ X, float* __restrict__ xsq) {
  int row = blockIdx.x * 4 + (threadIdx.x >> 6);
  int lane = threadIdx.x & 63;
  const float* Xr = X + row * 512;
  float s = 0.f;
#pragma unroll
  for (int d = 0; d < 8; ++d) { float v = Xr[lane + 64 * d]; s += v * v; }
  s = waveSum(s);
  if (lane == 0) xsq[row] = s;
}

// ---------------- G += X^T X  (split-K, atomic, upper block-triangle only) ----------------
__global__ void __launch_bounds__(256) k_xtx(const float* __restrict__ X, float* __restrict__ G) {
  const int pi_[10] = {0, 0, 0, 0, 1, 1, 1, 2, 2, 3};
  const int pj_[10] = {0, 1, 2, 3, 1, 2, 3, 2, 3, 3};
  __shared__ float Ai[16][132], Aj[16][132];
  int bi = pi_[blockIdx.x], bj = pj_[blockIdx.x];
  int k0 = blockIdx.y * 2000;
  int t = threadIdx.x;
  int tr = t >> 4, tc = t & 15;
  float acc[8][8] = {{0.f}};
  const float* Xi = X + k0 * 512 + bi * 128;
  const float* Xj = X + k0 * 512 + bj * 128;
  for (int kb = 0; kb < 2000; kb += 16) {
#pragma unroll
    for (int p2 = 0; p2 < 8; ++p2) {
      int l = t + 256 * p2;
      int kk = l >> 7, ii = l & 127;
      Ai[kk][ii] = Xi[(kb + kk) * 512 + ii];
      Aj[kk][ii] = Xj[(kb + kk) * 512 + ii];
    }
    __syncthreads();
#pragma unroll
    for (int kk = 0; kk < 16; ++kk) {
      float a[8], b[8];
#pragma unroll
      for (int u = 0; u < 8; ++u) a[u] = Ai[kk][tr * 8 + u];
#pragma unroll
      for (int v = 0; v < 8; ++v) b[v] = Aj[kk][tc * 8 + v];
#pragma unroll
      for (int u = 0; u < 8; ++u)
#pragma unroll
        for (int v = 0; v < 8; ++v) acc[u][v] += a[u] * b[v];
    }
    __syncthreads();
  }
#pragma unroll
  for (int u = 0; u < 8; ++u)
#pragma unroll
    for (int v = 0; v < 8; ++v)
      atomicAdd(&G[(bi * 128 + tr * 8 + u) * 512 + bj * 128 + tc * 8 + v], acc[u][v]);
}

// ---------------- column means of T ----------------
__global__ void k_colmeanT(const float* __restrict__ T, float* __restrict__ mu) {
  int c = threadIdx.x;
  float s = 0.f;
  for (int r = 0; r < 256; ++r) s += T[r * 512 + c];
  mu[c] = s * (1.0f / 256.0f);
}

// ---------------- Tc = T - mu, accumulate sum(Tc^2) ----------------
__global__ void k_centerT(const float* __restrict__ T, const float* __restrict__ mu,
                          float* __restrict__ Tc, float* __restrict__ scal) {
  __shared__ float red[4];
  int t = threadIdx.x;
  int base = blockIdx.x * 1024;
  float ss = 0.f;
#pragma unroll
  for (int p = 0; p < 4; ++p) {
    int l = base + p * 256 + t;
    float v = T[l] - mu[l & 511];
    Tc[l] = v;
    ss += v * v;
  }
  ss = waveSum(ss);
  if ((t & 63) == 0) red[t >> 6] = ss;
  __syncthreads();
  if (t == 0) atomicAdd(&scal[0], red[0] + red[1] + red[2] + red[3]);
}

// ---------------- trace of cov(X) ----------------
__global__ void k_trCX(const float* __restrict__ colsum, const float* __restrict__ colss,
                       float* __restrict__ scal) {
  __shared__ float red[8];
  int t = threadIdx.x;  // 512
  float mu = colsum[t] * (1.0f / 50000.0f);
  float v = (colss[t] - 50000.0f * mu * mu) * (1.0f / 49999.0f);
  v = waveSum(v);
  if ((t & 63) == 0) red[t >> 6] = v;
  __syncthreads();
  if (t == 0) {
    float s = 0;
    for (int i = 0; i < 8; ++i) s += red[i];
    scal[1] = s;
  }
}

// ---------------- finalize SigmaX in place on G (upper triangle valid) ----------------
__global__ void k_finSX(float* __restrict__ G, const float* __restrict__ colsum,
                        const float* __restrict__ scal) {
  int i = blockIdx.y * 16 + threadIdx.y, j = blockIdx.x * 16 + threadIdx.x;
  if (i > j) return;
  float mi = colsum[i] * (1.0f / 50000.0f), mj = colsum[j] * (1.0f / 50000.0f);
  float g = G[i * 512 + j];
  float v = (g - 50000.0f * mi * mj) * (1.0f / 49999.0f);
  if (i == j) v += scal[1] * (1e-3f / 512.0f);
  G[i * 512 + j] = v;
  G[j * 512 + i] = v;
}

// ---------------- Gershgorin row sums of H' = H + rt*I ----------------
__global__ void k_rowsum(const float* __restrict__ H, const float* __restrict__ scal,
                         float* __restrict__ rows) {
  int b = blockIdx.x, lane = threadIdx.x;  // 64 threads
  float rt = scal[0] * (1.0f / 255.0f) * (1e-3f / 512.0f);
  float s = 0.f;
#pragma unroll
  for (int p = 0; p < 4; ++p) {
    int j = lane + 64 * p;
    float v = H[b * 256 + j] + ((j == b) ? rt : 0.f);
    s += fabsf(v);
  }
  s = waveSum(s);
  if (lane == 0) rows[b] = s;
}

// ---------------- max row sum -> scal[5] ----------------
__global__ void k_nsmax(const float* __restrict__ rows, float* __restrict__ scal) {
  __shared__ float red[4];
  int t = threadIdx.x;  // 256
  float m = rows[t];
#pragma unroll
  for (int off = 32; off > 0; off >>= 1) m = fmaxf(m, __shfl_xor(m, off));
  if ((t & 63) == 0) red[t >> 6] = m;
  __syncthreads();
  if (t == 0) scal[5] = fmaxf(fmaxf(red[0], red[1]), fmaxf(red[2], red[3]));
}

// ---------------- Y0 = (H + rt I)/s, Z0 = I ----------------
__global__ void k_nsinit(const float* __restrict__ H, const float* __restrict__ scal,
                         float* __restrict__ Y, float* __restrict__ Z) {
  int l = blockIdx.x * 256 + threadIdx.x;
  int i = l >> 8, j = l & 255;
  float rt = scal[0] * (1.0f / 255.0f) * (1e-3f / 512.0f);
  float inv = 1.0f / scal[5];
  Y[l] = (H[l] + ((i == j) ? rt : 0.f)) * inv;
  Z[l] = (i == j) ? 1.0f : 0.f;
}

// ---------------- P = Z @ Y (256x256x256) ----------------
__global__ void __launch_bounds__(256) k_mm256(const float* __restrict__ A,
                                               const float* __restrict__ B,
                                               float* __restrict__ C) {
  __shared__ float As[64][65], Bs[64][65];
  int bi = blockIdx.x, bj = blockIdx.y;
  int t = threadIdx.x;
  int tr = t >> 4, tc = t & 15;
  float acc[4][4] = {{0.f}};
  for (int k0 = 0; k0 < 256; k0 += 64) {
#pragma unroll
    for (int p = 0; p < 16; ++p) {
      int l = t + 256 * p;
      int r = l >> 6, c = l & 63;
      As[r][c] = A[(bi * 64 + r) * 256 + k0 + c];
      Bs[r][c] = B[(k0 + r) * 256 + bj * 64 + c];
    }
    __syncthreads();
#pragma unroll 16
    for (int kk = 0; kk < 64; ++kk) {
      float a[4], b[4];
#pragma unroll
      for (int u = 0; u < 4; ++u) a[u] = As[tr * 4 + u][kk];
#pragma unroll
      for (int v = 0; v < 4; ++v) b[v] = Bs[kk][tc * 4 + v];
#pragma unroll
      for (int u = 0; u < 4; ++u)
#pragma unroll
        for (int v = 0; v < 4; ++v) acc[u][v] += a[u] * b[v];
    }
    __syncthreads();
  }
#pragma unroll
  for (int u = 0; u < 4; ++u)
#pragma unroll
    for (int v = 0; v < 4; ++v)
      C[(bi * 64 + tr * 4 + u) * 256 + bj * 64 + tc * 4 + v] = acc[u][v];
}

// ---------------- NS update: z=0 Yn=1.5Y-0.5*Y@P ; z=1 Zn=1.5Z-0.5*P@Z ----------------
__global__ void __launch_bounds__(256) k_ns_upd(const float* __restrict__ Y, const float* __restrict__ Z,
                                                const float* __restrict__ P,
                                                float* __restrict__ Yn, float* __restrict__ Zn) {
  __shared__ float As[64][65], Bs[64][65];
  int bi = blockIdx.x, bj = blockIdx.y, zz = blockIdx.z;
  const float* A = zz ? P : Y;
  const float* B = zz ? Z : P;
  const float* D = zz ? Z : Y;
  float* O = zz ? Zn : Yn;
  int t = threadIdx.x;
  int tr = t >> 4, tc = t & 15;
  float acc[4][4] = {{0.f}};
  for (int k0 = 0; k0 < 256; k0 += 64) {
#pragma unroll
    for (int p = 0; p < 16; ++p) {
      int l = t + 256 * p;
      int r = l >> 6, c = l & 63;
      As[r][c] = A[(bi * 64 + r) * 256 + k0 + c];
      Bs[r][c] = B[(k0 + r) * 256 + bj * 64 + c];
    }
    __syncthreads();
#pragma unroll 16
    for (int kk = 0; kk < 64; ++kk) {
      float a[4], b[4];
#pragma unroll
      for (int u = 0; u < 4; ++u) a[u] = As[tr * 4 + u][kk];
#pragma unroll
      for (int v = 0; v < 4; ++v) b[v] = Bs[kk][tc * 4 + v];
#pragma unroll
      for (int u = 0; u < 4; ++u)
#pragma unroll
        for (int v = 0; v < 4; ++v) acc[u][v] += a[u] * b[v];
    }
    __syncthreads();
  }
#pragma unroll
  for (int u = 0; u < 4; ++u)
#pragma unroll
    for (int v = 0; v < 4; ++v) {
      int idx = (bi * 64 + tr * 4 + u) * 256 + bj * 64 + tc * 4 + v;
      O[idx] = 1.5f * D[idx] - 0.5f * acc[u][v];
    }
}

// ---------------- S_total = sqrt(s)*tr(Y) + 256*sqrt(rt) ----------------
__global__ void k_ns_trace(const float* __restrict__ Y, float* __restrict__ scal) {
  __shared__ float red[4];
  int t = threadIdx.x;  // 256
  float v = Y[t * 256 + t];
  v = waveSum(v);
  if ((t & 63) == 0) red[t >> 6] = v;
  __syncthreads();
  if (t == 0) {
    float tr = red[0] + red[1] + red[2] + red[3];
    float rt = scal[0] * (1.0f / 255.0f) * (1e-3f / 512.0f);
    scal[2] = sqrtf(scal[5]) * tr + 256.0f * sqrtf(rt);
  }
}

// ---------------- d2 chunk GEMM: out[i][j] = xsq[base+j] - 2*dot(T[i],X[base+j]) ----------------
__global__ void __launch_bounds__(256) k_d2(const float* __restrict__ T, const float* __restrict__ X,
                                            const float* __restrict__ xsq, float* __restrict__ out,
                                            int base) {
  __shared__ float Ts[16][132], Xs[16][132];
  int bi = blockIdx.x, bj = blockIdx.y;
  int t = threadIdx.x;
  int tr = t >> 4, tc = t & 15;
  float acc[8][8] = {{0.f}};
  for (int k0 = 0; k0 < 512; k0 += 16) {
#pragma unroll
    for (int p2 = 0; p2 < 8; ++p2) {
      int l = t + 256 * p2;
      int kk = l & 15, r = l >> 4;
      Ts[kk][r] = T[(bi * 128 + r) * 512 + k0 + kk];
      int jg = bj * 128 + r;
      if (jg > CHUNK - 1) jg = CHUNK - 1;
      Xs[kk][r] = X[(base + jg) * 512 + k0 + kk];
    }
    __syncthreads();
#pragma unroll
    for (int kk = 0; kk < 16; ++kk) {
      float a[8], b[8];
#pragma unroll
      for (int u = 0; u < 8; ++u) a[u] = Ts[kk][tr * 8 + u];
#pragma unroll
      for (int v = 0; v < 8; ++v) b[v] = Xs[kk][tc * 8 + v];
#pragma unroll
      for (int u = 0; u < 8; ++u)
#pragma unroll
        for (int v = 0; v < 8; ++v) acc[u][v] += a[u] * b[v];
    }
    __syncthreads();
  }
#pragma unroll
  for (int u = 0; u < 8; ++u) {
    int i = bi * 128 + tr * 8 + u;
#pragma unroll
    for (int v = 0; v < 8; ++v) {
      int j = bj * 128 + tc * 8 + v;
      if (j < CHUNK) out[i * CHUNK + j] = xsq[base + j] - 2.0f * acc[u][v];
    }
  }
}

// ---------------- init running top-k ----------------
__global__ void k_topk_init(float* __restrict__ runv, int* __restrict__ runi) {
  int i = blockIdx.x * 256 + threadIdx.x;
  runv[i] = FLT_MAX;
  runi[i] = 0x7fffffff;
}

// ---------------- per-query top-32 merge over one chunk ----------------
__global__ void __launch_bounds__(128) k_topk_merge(const float* __restrict__ d2c,
                                                    float* __restrict__ runv, int* __restrict__ runi,
                                                    int base) {
  __shared__ float cv[128 * 32];
  __shared__ int ci[128 * 32];
  __shared__ float rv[2];
  __shared__ int rgi[2], rsl[2];
  int q = blockIdx.x, t = threadIdx.x;
  float* mv = &cv[t * 32];
  int* mi = &ci[t * 32];
  int cnt = 0;
  float wval = -FLT_MAX; int widx = 0, wpos = 0;
  auto recompute = [&]() {
    wval = mv[0]; widx = mi[0]; wpos = 0;
    for (int s = 1; s < 32; ++s) {
      float a = mv[s]; int b2 = mi[s];
      if (a > wval || (a == wval && b2 > widx)) { wval = a; widx = b2; wpos = s; }
    }
  };
  auto push = [&](float val, int idx) {
    if (cnt < 32) {
      mv[cnt] = val; mi[cnt] = idx;
      if (++cnt == 32) recompute();
    } else if (val < wval || (val == wval && idx < widx)) {
      mv[wpos] = val; mi[wpos] = idx;
      recompute();
    }
  };
  if (t < 32) push(runv[q * 32 + t], runi[q * 32 + t]);
  for (int j = t; j < CHUNK; j += 128) push(d2c[q * CHUNK + j], base + j);
  for (int s = cnt; s < 32; ++s) { mv[s] = FLT_MAX; mi[s] = 0x7fffffff; }
  __syncthreads();
  for (int r = 0; r < 32; ++r) {
    float bv = FLT_MAX; int bi2 = 0x7fffffff, bs = t * 32;
    for (int s = 0; s < 32; ++s) {
      float a = cv[t * 32 + s]; int b2 = ci[t * 32 + s];
      if (a < bv || (a == bv && b2 < bi2)) { bv = a; bi2 = b2; bs = t * 32 + s; }
    }
#pragma unroll
    for (int off = 32; off > 0; off >>= 1) {
      float ov = __shfl_down(bv, off);
      int oi = __shfl_down(bi2, off);
      int os = __shfl_down(bs, off);
      if (ov < bv || (ov == bv && oi < bi2)) { bv = ov; bi2 = oi; bs = os; }
    }
    int w = t >> 6;
    if ((t & 63) == 0) { rv[w] = bv; rgi[w] = bi2; rsl[w] = bs; }
    __syncthreads();
    if (t == 0) {
      float v0 = rv[0]; int i0 = rgi[0], s0 = rsl[0];
      if (rv[1] < v0 || (rv[1] == v0 && rgi[1] < i0)) { v0 = rv[1]; i0 = rgi[1]; s0 = rsl[1]; }
      runv[q * 32 + r] = v0;
      runi[q * 32 + r] = i0;
      cv[s0] = FLT_MAX; ci[s0] = 0x7fffffff;
    }
    __syncthreads();
  }
}

// ---------------- l2 to neighbors, softmax post_w, normalized pre_w ----------------
__global__ void __launch_bounds__(64) k_l2soft(const float* __restrict__ T, const float* __restrict__ X,
                                               const int* __restrict__ runi, const int* __restrict__ qidx,
                                               const float* __restrict__ prew, float* __restrict__ postw,
                                               float* __restrict__ prewn) {
  __shared__ float l2s[32];
  int b = blockIdx.x, lane = threadIdx.x;
  int qi = qidx[b];
  float pwv = (lane < 32) ? fmaxf(prew[qi * 32 + lane], 1e-8f) : 0.f;
  float psum = waveSum(pwv);
  if (lane < 32) prewn[b * 32 + lane] = pwv / psum;
  const float* Tb = T + b * 512;
  for (int n = 0; n < 32; ++n) {
    int nb = runi[b * 32 + n];
    const float* Xr = X + nb * 512;
    float acc = 0.f;
#pragma unroll
    for (int d = 0; d < 8; ++d) {
      float df = Tb[lane + 64 * d] - Xr[lane + 64 * d];
      acc += df * df;
    }
    acc = waveSum(acc);
    if (lane == 0) l2s[n] = acc;
  }
  __syncthreads();
  float lg = (lane < 32) ? (-l2s[lane] * 10.0f) : -FLT_MAX;
  float mx = lg;
#pragma unroll
  for (int off = 32; off > 0; off >>= 1) mx = fmaxf(mx, __shfl_xor(mx, off));
  float e = (lane < 32) ? expf(lg - mx) : 0.f;
  float es = waveSum(e);
  float wv = e / es;
  wv = fmaxf(wv, 1e-8f);
  float ws2 = (lane < 32) ? wv : 0.f;
  ws2 = waveSum(ws2);
  if (lane < 32) postw[b * 32 + lane] = wv / ws2;
}

// ---------------- fused per-batch: Gram -> C -> median -> Sinkhorn(200) -> loss ----------------
__global__ void __launch_bounds__(256) k_batch(const float* __restrict__ X, const int* __restrict__ qidx,
                                               const int* __restrict__ pre_idx, const int* __restrict__ runi,
                                               const float* __restrict__ prewn, const float* __restrict__ postw,
                                               float* __restrict__ scal) {
  __shared__ float G[64][65];   // Gram, later reused as Kmat
  __shared__ float Cm[64][65];
  __shared__ float SB[4160];    // staging / sort buffer
  __shared__ int supp[64];
  __shared__ float pv[64], qv[64], uu[64], vv[64];
  __shared__ float rbuf[4][64];
  __shared__ float medsh;
  int b = blockIdx.x, t = threadIdx.x;
  if (t < 32) supp[t] = pre_idx[qidx[b] * 32 + t];
  else if (t < 64) supp[t] = runi[b * 32 + t - 32];
  __syncthreads();
  int tr = t >> 4, tc = t & 15;
  float acc[4][4] = {{0.f}};
  for (int kc = 0; kc < 512; kc += 64) {
    __syncthreads();
#pragma unroll
    for (int p2 = 0; p2 < 16; ++p2) {
      int l = t + 256 * p2;
      int r = l >> 6, c = l & 63;
      SB[r * 65 + c] = X[supp[r] * 512 + kc + c];
    }
    __syncthreads();
#pragma unroll 8
    for (int kk = 0; kk < 64; ++kk) {
      float a[4], bb[4];
#pragma unroll
      for (int u = 0; u < 4; ++u) a[u] = SB[(tr * 4 + u) * 65 + kk];
#pragma unroll
      for (int v = 0; v < 4; ++v) bb[v] = SB[(tc * 4 + v) * 65 + kk];
#pragma unroll
      for (int u = 0; u < 4; ++u)
#pragma unroll
        for (int v = 0; v < 4; ++v) acc[u][v] += a[u] * bb[v];
    }
  }
  __syncthreads();
#pragma unroll
  for (int u = 0; u < 4; ++u)
#pragma unroll
    for (int v = 0; v < 4; ++v) G[tr * 4 + u][tc * 4 + v] = acc[u][v];
  __syncthreads();
  for (int l = t; l < 4096; l += 256) {
    int i = l >> 6, j = l & 63;
    float cc = fmaxf(G[i][i] + G[j][j] - 2.0f * G[i][j], 0.f);
    Cm[i][j] = cc;
    SB[l] = cc;
  }
  // bitonic sort 4096 ascending
  for (int ssz = 2; ssz <= 4096; ssz <<= 1) {
    for (int st = ssz >> 1; st > 0; st >>= 1) {
      __syncthreads();
      for (int l = t; l < 2048; l += 256) {
        int i = 2 * l - (l & (st - 1));
        int j = i + st;
        bool up = ((i & ssz) == 0);
        float a = SB[i], b2 = SB[j];
        if ((a > b2) == up) { SB[i] = b2; SB[j] = a; }
      }
    }
  }
  __syncthreads();
  if (t == 0) medsh = 0.5f * (SB[2047] + SB[2048]) + 1e-8f;
  __syncthreads();
  float inv = 1.0f / medsh;
  for (int l = t; l < 4096; l += 256) {
    int i = l >> 6, j = l & 63;
    float cn = Cm[i][j] * inv;
    Cm[i][j] = cn;
    G[i][j] = expf(-cn * 10.0f);   // K = exp(-C/eps), eps=0.1
  }
  if (t < 64) {
    pv[t] = (t < 32) ? prewn[b * 32 + t] : 0.f;
    qv[t] = (t < 32) ? 0.f : postw[b * 32 + (t - 32)];
    uu[t] = 1.f; vv[t] = 1.f;
  }
  __syncthreads();
  int g = t >> 6, i0 = t & 63;
  for (int it = 0; it < 200; ++it) {
    float s2 = 0.f;
#pragma unroll
    for (int j2 = 0; j2 < 16; ++j2) s2 += G[i0][g * 16 + j2] * vv[g * 16 + j2];
    rbuf[g][i0] = s2;
    __syncthreads();
    if (t < 64) uu[t] = pv[t] / (rbuf[0][t] + rbuf[1][t] + rbuf[2][t] + rbuf[3][t] + 1e-16f);
    __syncthreads();
    s2 = 0.f;
#pragma unroll
    for (int j2 = 0; j2 < 16; ++j2) s2 += G[g * 16 + j2][i0] * uu[g * 16 + j2];
    rbuf[g][i0] = s2;
    __syncthreads();
    if (t < 64) vv[t] = qv[t] / (rbuf[0][t] + rbuf[1][t] + rbuf[2][t] + rbuf[3][t] + 1e-16f);
    __syncthreads();
  }
  float lacc = 0.f;
  for (int l = t; l < 4096; l += 256) {
    int i = l >> 6, j = l & 63;
    lacc += uu[i] * G[i][j] * vv[j] * Cm[i][j];
  }
  lacc = waveSum(lacc);
  if ((t & 63) == 0) rbuf[0][t >> 6] = lacc;
  __syncthreads();
  if (t == 0)
    atomicAdd(&scal[3], (rbuf[0][0] + rbuf[0][1] + rbuf[0][2] + rbuf[0][3]) * (1.0f / 256.0f));
}

// ---------------- sum(W^2) ----------------
__global__ void k_wreg(const float* __restrict__ W, float* __restrict__ scal) {
  __shared__ float red[4];
  int t = threadIdx.x;
  int base = blockIdx.x * 2048;
  float ss = 0.f;
#pragma unroll
  for (int p = 0; p < 8; ++p) {
    float v = W[base + p * 256 + t];
    ss += v * v;
  }
  ss = waveSum(ss);
  if ((t & 63) == 0) red[t >> 6] = ss;
  __syncthreads();
  if (t == 0) atomicAdd(&scal[4], red[0] + red[1] + red[2] + red[3]);
}

// ---------------- final combine ----------------
__global__ void k_combine(const float* __restrict__ mu_t, const float* __restrict__ colsum,
                          const float* __restrict__ scal, float* __restrict__ out) {
  __shared__ float red[8];
  int t = threadIdx.x;  // 512
  float dm = mu_t[t] - colsum[t] * (1.0f / 50000.0f);
  float v = dm * dm;
  v = waveSum(v);
  if ((t & 63) == 0) red[t >> 6] = v;
  __syncthreads();
  if (t == 0) {
    float term_mean = 0.f;
    for (int i = 0; i < 8; ++i) term_mean += red[i];
    float trCT = scal[0] * (1.0f / 255.0f);
    float trCX = scal[1];
    float S = scal[2];
    float term_cov = trCX * 1.001f + trCT * 1.001f - 2.0f * S;
    term_cov = fmaxf(term_cov, 0.f);
    float loss_dist = term_mean + term_cov;
    float loss_knn = scal[3];
    float loss_reg = 0.5f * scal[4];
    out[0] = loss_dist + loss_knn + 1e-4f * loss_reg;
    out[1] = loss_dist;
    out[2] = loss_knn;
  }
}

extern "C" void kernel_launch(void* const* d_in, const int* in_sizes, int n_in,
                              void* d_out, int out_size, void* d_ws, size_t ws_size,
                              hipStream_t stream) {
  const float* q = (const float*)d_in[0];
  const int* qidx = (const int*)d_in[1];
  const float* W = (const float*)d_in[2];
  const float* X = (const float*)d_in[3];
  const int* pre_idx = (const int*)d_in[4];
  const float* prew = (const float*)d_in[5];
  float* out = (float*)d_out;
  float* ws = (float*)d_ws;

  float* G = ws + OFF_G;
  float* scal = ws + OFF_SC;
  float* colsum = ws + OFF_CS;
  float* colss = ws + OFF_CSS;
  float* T = ws + OFF_T;
  float* Tc = ws + OFF_TC;
  float* P = ws + OFF_P;
  float* H = ws + OFF_H;
  float* rows = ws + OFF_DDI;
  float* mu_t = ws + OFF_MUT;
  float* xsq = ws + OFF_XSQ;
  float* runv = ws + OFF_RUNV;
  int* runi = (int*)(ws + OFF_RUNI);
  float* postw = ws + OFF_PW;
  float* prewn = ws + OFF_PRW;
  float* d2c = ws + OFF_D2;

  hipMemsetAsync(d_ws, 0, (size_t)ZERO_F * 4, stream);

  // T = q @ W
  k_gemm_nn<<<dim3(32, 16), dim3(16, 16), 0, stream>>>(q, W, T);
  // X column stats, per-row sq norms, X^T X (upper block-triangle)
  k_colstatX<<<256, 256, 0, stream>>>(X, colsum, colss);
  k_xsq<<<12500, 256, 0, stream>>>(X, xsq);
  k_xtx<<<dim3(10, 25), 256, 0, stream>>>(X, G);
  // T stats
  k_colmeanT<<<1, 512, 0, stream>>>(T, mu_t);
  k_centerT<<<128, 256, 0, stream>>>(T, mu_t, Tc, scal);
  // SigmaX
  k_trCX<<<1, 512, 0, stream>>>(colsum, colss, scal);
  k_finSX<<<dim3(32, 32), dim3(16, 16), 0, stream>>>(G, colsum, scal);
  // H = Tc SigmaX Tc^T / 255
  k_gemm_nn<<<dim3(32, 16), dim3(16, 16), 0, stream>>>(Tc, G, P);
  k_gemm_nt_H<<<dim3(16, 16), dim3(16, 16), 0, stream>>>(P, Tc, H);
  // spectral sum via coupled Newton-Schulz sqrt of H' = H + rt*I
  // buffers: Tc dead -> Y,Z ; P dead -> Y2,Z2 ; G dead -> Pm
  {
    float* Y = ws + OFF_TC;
    float* Z = ws + OFF_TC + 65536;
    float* Y2 = ws + OFF_P;
    float* Z2 = ws + OFF_P + 65536;
    float* Pm = ws + OFF_G;
    k_rowsum<<<256, 64, 0, stream>>>(H, scal, rows);
    k_nsmax<<<1, 256, 0, stream>>>(rows, scal);
    k_nsinit<<<256, 256, 0, stream>>>(H, scal, Y, Z);
    for (int it = 0; it < NS_ITERS; ++it) {
      k_mm256<<<dim3(4, 4), 256, 0, stream>>>(Z, Y, Pm);
      k_ns_upd<<<dim3(4, 4, 2), 256, 0, stream>>>(Y, Z, Pm, Y2, Z2);
      float* tmp = Y; Y = Y2; Y2 = tmp;
      tmp = Z; Z = Z2; Z2 = tmp;
    }
    k_ns_trace<<<1, 256, 0, stream>>>(Y, scal);
  }
  // kNN
  k_topk_init<<<32, 256, 0, stream>>>(runv, runi);
  for (int c = 0; c < 4; ++c) {
    k_d2<<<dim3(2, 98), 256, 0, stream>>>(T, X, xsq, d2c, c * CHUNK);
    k_topk_merge<<<256, 128, 0, stream>>>(d2c, runv, runi, c * CHUNK);
  }
  k_l2soft<<<256, 64, 0, stream>>>(T, X, runi, qidx, prew, postw, prewn);
  k_batch<<<256, 256, 0, stream>>>(X, qidx, pre_idx, runi, prewn, postw, scal);
  k_wreg<<<128, 256, 0, stream>>>(W, scal);
  k_combine<<<1, 512, 0, stream>>>(mu_t, colsum, scal, out);
}

// Round 3
// 3056.459 us; speedup vs baseline: 1.8278x; 1.2056x over previous
//
#include <hip/hip_runtime.h>
#include <float.h>
#include <math.h>

// Problem constants
#define BB 256
#define DD 512
#define NN 50000
#define KK 32
#define CHUNK 12500
#define NS_ITERS 18

// Workspace layout (float offsets)
#define OFF_G     0         // 512*512  Gram X^TX -> SigmaX (zeroed); later NS "Pm" scratch
#define OFF_SC    262144    // 64 scalars (zeroed): 0=sumTc2 1=trCX 2=S_total 3=knn 4=wreg 5=gersh
#define OFF_CS    262208    // 512 colsum X (zeroed)
#define OFF_CSS   262720    // 512 colsumsq X (zeroed)
#define ZERO_F    263232    // floats to memset
#define OFF_T     263232    // 256*512
#define OFF_TC    394304    // 256*512 (dead after H -> NS Y/Z)
#define OFF_P     525376    // 256*512 (dead after H -> NS Y2/Z2)
#define OFF_H     656448    // 256*256
#define OFF_DDI   721984    // 256 (rowsum scratch)
#define OFF_EEO   722240    // 256
#define OFF_MUT   722496    // 512
#define OFF_XSQ   723008    // 50000
#define OFF_RUNV  773008    // 256*32
#define OFF_RUNI  781200    // 256*32 (int)
#define OFF_PW    789392    // 256*32 post_w
#define OFF_PRW   797584    // 256*32 pre_w normalized
#define OFF_D2    805776    // 256*12500 (chunked) or 256*50000 (full, if ws allows)

__device__ __forceinline__ float waveSum(float v) {
#pragma unroll
  for (int off = 32; off > 0; off >>= 1) v += __shfl_xor(v, off);
  return v;
}

// ---------------- generic 64x64-tile GEMM, C = scale * A @ B (nn) ----------------
// grid (N/64, M/64), 256 threads, 4x4 micro-tile, interleaved (conflict-free) mapping
__global__ void __launch_bounds__(256) k_g64_nn(const float* __restrict__ A,
                                                const float* __restrict__ B,
                                                float* __restrict__ C,
                                                int K, int lda, int ldb, int ldc, float scale) {
  __shared__ float As[64][65], Bs[64][65];
  int m0 = blockIdx.y * 64, n0 = blockIdx.x * 64;
  int t = threadIdx.x, tr = t >> 4, tc = t & 15;
  float acc[4][4] = {{0.f}};
  for (int k0 = 0; k0 < K; k0 += 64) {
#pragma unroll
    for (int p = 0; p < 16; ++p) {
      int l = t + 256 * p;
      int r = l >> 6, c = l & 63;
      As[r][c] = A[(m0 + r) * lda + k0 + c];
      Bs[r][c] = B[(k0 + r) * ldb + n0 + c];
    }
    __syncthreads();
#pragma unroll 16
    for (int kk = 0; kk < 64; ++kk) {
      float a[4], b[4];
#pragma unroll
      for (int u = 0; u < 4; ++u) a[u] = As[tr + 16 * u][kk];
#pragma unroll
      for (int v = 0; v < 4; ++v) b[v] = Bs[kk][tc + 16 * v];
#pragma unroll
      for (int u = 0; u < 4; ++u)
#pragma unroll
        for (int v = 0; v < 4; ++v) acc[u][v] += a[u] * b[v];
    }
    __syncthreads();
  }
#pragma unroll
  for (int u = 0; u < 4; ++u)
#pragma unroll
    for (int v = 0; v < 4; ++v)
      C[(m0 + tr + 16 * u) * ldc + n0 + tc + 16 * v] = acc[u][v] * scale;
}

// ---------------- generic 64x64-tile GEMM, C = scale * A @ B^T (nt) ----------------
__global__ void __launch_bounds__(256) k_g64_nt(const float* __restrict__ A,
                                                const float* __restrict__ B,
                                                float* __restrict__ C,
                                                int K, int lda, int ldb, int ldc, float scale) {
  __shared__ float As[64][65], Bs[64][65];
  int m0 = blockIdx.y * 64, n0 = blockIdx.x * 64;
  int t = threadIdx.x, tr = t >> 4, tc = t & 15;
  float acc[4][4] = {{0.f}};
  for (int k0 = 0; k0 < K; k0 += 64) {
#pragma unroll
    for (int p = 0; p < 16; ++p) {
      int l = t + 256 * p;
      int r = l >> 6, c = l & 63;
      As[r][c] = A[(m0 + r) * lda + k0 + c];
      Bs[r][c] = B[(n0 + r) * ldb + k0 + c];  // Bs[n][k]
    }
    __syncthreads();
#pragma unroll 16
    for (int kk = 0; kk < 64; ++kk) {
      float a[4], b[4];
#pragma unroll
      for (int u = 0; u < 4; ++u) a[u] = As[tr + 16 * u][kk];
#pragma unroll
      for (int v = 0; v < 4; ++v) b[v] = Bs[tc + 16 * v][kk];
#pragma unroll
      for (int u = 0; u < 4; ++u)
#pragma unroll
        for (int v = 0; v < 4; ++v) acc[u][v] += a[u] * b[v];
    }
    __syncthreads();
  }
#pragma unroll
  for (int u = 0; u < 4; ++u)
#pragma unroll
    for (int v = 0; v < 4; ++v)
      C[(m0 + tr + 16 * u) * ldc + n0 + tc + 16 * v] = acc[u][v] * scale;
}

// ---------------- column sums & sumsq of X (atomic) ----------------
__global__ void k_colstatX(const float* __restrict__ X, float* __restrict__ colsum,
                           float* __restrict__ colss) {
  int b = blockIdx.x, t = threadIdx.x;
  int r0 = b * 196;
  int r1 = r0 + 196; if (r1 > NN) r1 = NN;
  float s1 = 0, ss1 = 0, s2 = 0, ss2 = 0;
  for (int r = r0; r < r1; ++r) {
    float v1 = X[r * 512 + t], v2 = X[r * 512 + t + 256];
    s1 += v1; ss1 += v1 * v1; s2 += v2; ss2 += v2 * v2;
  }
  atomicAdd(&colsum[t], s1);       atomicAdd(&colss[t], ss1);
  atomicAdd(&colsum[t + 256], s2); atomicAdd(&colss[t + 256], ss2);
}

// ---------------- per-row squared norm of X ----------------
__global__ void k_xsq(const float* __restrict__ X, float* __restrict__ xsq) {
  int row = blockIdx.x * 4 + (threadIdx.x >> 6);
  int lane = threadIdx.x & 63;
  const float* Xr = X + row * 512;
  float s = 0.f;
#pragma unroll
  for (int d = 0; d < 8; ++d) { float v = Xr[lane + 64 * d]; s += v * v; }
  s = waveSum(s);
  if (lane == 0) xsq[row] = s;
}

// ---------------- G += X^T X  (split-K, atomic, upper block-triangle only) ----------------
// 50 K-chunks of 1008 rows (zero-guarded tail), interleaved conflict-free b mapping
__global__ void __launch_bounds__(256) k_xtx(const float* __restrict__ X, float* __restrict__ G) {
  const int pi_[10] = {0, 0, 0, 0, 1, 1, 1, 2, 2, 3};
  const int pj_[10] = {0, 1, 2, 3, 1, 2, 3, 2, 3, 3};
  __shared__ float Ai[16][132], Aj[16][132];
  int bi = pi_[blockIdx.x], bj = pj_[blockIdx.x];
  int kstart = blockIdx.y * 1008;
  int t = threadIdx.x;
  int tr = t >> 4, tc = t & 15;
  float acc[8][8] = {{0.f}};
  for (int kb = 0; kb < 1008; kb += 16) {
#pragma unroll
    for (int p2 = 0; p2 < 8; ++p2) {
      int l = t + 256 * p2;
      int kk = l >> 7, ii = l & 127;
      int gr = kstart + kb + kk;
      bool ok = gr < NN;
      Ai[kk][ii] = ok ? X[gr * 512 + bi * 128 + ii] : 0.f;
      Aj[kk][ii] = ok ? X[gr * 512 + bj * 128 + ii] : 0.f;
    }
    __syncthreads();
#pragma unroll
    for (int kk = 0; kk < 16; ++kk) {
      float a[8], b[8];
#pragma unroll
      for (int u = 0; u < 8; ++u) a[u] = Ai[kk][tr * 8 + u];
#pragma unroll
      for (int v = 0; v < 8; ++v) b[v] = Aj[kk][tc + 16 * v];
#pragma unroll
      for (int u = 0; u < 8; ++u)
#pragma unroll
        for (int v = 0; v < 8; ++v) acc[u][v] += a[u] * b[v];
    }
    __syncthreads();
  }
#pragma unroll
  for (int u = 0; u < 8; ++u)
#pragma unroll
    for (int v = 0; v < 8; ++v)
      atomicAdd(&G[(bi * 128 + tr * 8 + u) * 512 + bj * 128 + tc + 16 * v], acc[u][v]);
}

// ---------------- column means of T ----------------
__global__ void k_colmeanT(const float* __restrict__ T, float* __restrict__ mu) {
  int c = threadIdx.x;
  float s = 0.f;
  for (int r = 0; r < 256; ++r) s += T[r * 512 + c];
  mu[c] = s * (1.0f / 256.0f);
}

// ---------------- Tc = T - mu, accumulate sum(Tc^2) ----------------
__global__ void k_centerT(const float* __restrict__ T, const float* __restrict__ mu,
                          float* __restrict__ Tc, float* __restrict__ scal) {
  __shared__ float red[4];
  int t = threadIdx.x;
  int base = blockIdx.x * 1024;
  float ss = 0.f;
#pragma unroll
  for (int p = 0; p < 4; ++p) {
    int l = base + p * 256 + t;
    float v = T[l] - mu[l & 511];
    Tc[l] = v;
    ss += v * v;
  }
  ss = waveSum(ss);
  if ((t & 63) == 0) red[t >> 6] = ss;
  __syncthreads();
  if (t == 0) atomicAdd(&scal[0], red[0] + red[1] + red[2] + red[3]);
}

// ---------------- trace of cov(X) ----------------
__global__ void k_trCX(const float* __restrict__ colsum, const float* __restrict__ colss,
                       float* __restrict__ scal) {
  __shared__ float red[8];
  int t = threadIdx.x;  // 512
  float mu = colsum[t] * (1.0f / 50000.0f);
  float v = (colss[t] - 50000.0f * mu * mu) * (1.0f / 49999.0f);
  v = waveSum(v);
  if ((t & 63) == 0) red[t >> 6] = v;
  __syncthreads();
  if (t == 0) {
    float s = 0;
    for (int i = 0; i < 8; ++i) s += red[i];
    scal[1] = s;
  }
}

// ---------------- finalize SigmaX in place on G (upper triangle valid) ----------------
__global__ void k_finSX(float* __restrict__ G, const float* __restrict__ colsum,
                        const float* __restrict__ scal) {
  int i = blockIdx.y * 16 + threadIdx.y, j = blockIdx.x * 16 + threadIdx.x;
  if (i > j) return;
  float mi = colsum[i] * (1.0f / 50000.0f), mj = colsum[j] * (1.0f / 50000.0f);
  float g = G[i * 512 + j];
  float v = (g - 50000.0f * mi * mj) * (1.0f / 49999.0f);
  if (i == j) v += scal[1] * (1e-3f / 512.0f);
  G[i * 512 + j] = v;
  G[j * 512 + i] = v;
}

// ---------------- Gershgorin row sums of H' = H + rt*I ----------------
__global__ void k_rowsum(const float* __restrict__ H, const float* __restrict__ scal,
                         float* __restrict__ rows) {
  int b = blockIdx.x, lane = threadIdx.x;  // 64 threads
  float rt = scal[0] * (1.0f / 255.0f) * (1e-3f / 512.0f);
  float s = 0.f;
#pragma unroll
  for (int p = 0; p < 4; ++p) {
    int j = lane + 64 * p;
    float v = H[b * 256 + j] + ((j == b) ? rt : 0.f);
    s += fabsf(v);
  }
  s = waveSum(s);
  if (lane == 0) rows[b] = s;
}

// ---------------- max row sum -> scal[5] ----------------
__global__ void k_nsmax(const float* __restrict__ rows, float* __restrict__ scal) {
  __shared__ float red[4];
  int t = threadIdx.x;  // 256
  float m = rows[t];
#pragma unroll
  for (int off = 32; off > 0; off >>= 1) m = fmaxf(m, __shfl_xor(m, off));
  if ((t & 63) == 0) red[t >> 6] = m;
  __syncthreads();
  if (t == 0) scal[5] = fmaxf(fmaxf(red[0], red[1]), fmaxf(red[2], red[3]));
}

// ---------------- Y0 = (H + rt I)/s, Z0 = I ----------------
__global__ void k_nsinit(const float* __restrict__ H, const float* __restrict__ scal,
                         float* __restrict__ Y, float* __restrict__ Z) {
  int l = blockIdx.x * 256 + threadIdx.x;
  int i = l >> 8, j = l & 255;
  float rt = scal[0] * (1.0f / 255.0f) * (1e-3f / 512.0f);
  float inv = 1.0f / scal[5];
  Y[l] = (H[l] + ((i == j) ? rt : 0.f)) * inv;
  Z[l] = (i == j) ? 1.0f : 0.f;
}

// ---------------- NS update: z=0 Yn=1.5Y-0.5*Y@P ; z=1 Zn=1.5Z-0.5*P@Z ----------------
__global__ void __launch_bounds__(256) k_ns_upd(const float* __restrict__ Y, const float* __restrict__ Z,
                                                const float* __restrict__ P,
                                                float* __restrict__ Yn, float* __restrict__ Zn) {
  __shared__ float As[64][65], Bs[64][65];
  int bi = blockIdx.x, bj = blockIdx.y, zz = blockIdx.z;
  const float* A = zz ? P : Y;
  const float* B = zz ? Z : P;
  const float* D = zz ? Z : Y;
  float* O = zz ? Zn : Yn;
  int t = threadIdx.x;
  int tr = t >> 4, tc = t & 15;
  float acc[4][4] = {{0.f}};
  for (int k0 = 0; k0 < 256; k0 += 64) {
#pragma unroll
    for (int p = 0; p < 16; ++p) {
      int l = t + 256 * p;
      int r = l >> 6, c = l & 63;
      As[r][c] = A[(bi * 64 + r) * 256 + k0 + c];
      Bs[r][c] = B[(k0 + r) * 256 + bj * 64 + c];
    }
    __syncthreads();
#pragma unroll 16
    for (int kk = 0; kk < 64; ++kk) {
      float a[4], b[4];
#pragma unroll
      for (int u = 0; u < 4; ++u) a[u] = As[tr + 16 * u][kk];
#pragma unroll
      for (int v = 0; v < 4; ++v) b[v] = Bs[kk][tc + 16 * v];
#pragma unroll
      for (int u = 0; u < 4; ++u)
#pragma unroll
        for (int v = 0; v < 4; ++v) acc[u][v] += a[u] * b[v];
    }
    __syncthreads();
  }
#pragma unroll
  for (int u = 0; u < 4; ++u)
#pragma unroll
    for (int v = 0; v < 4; ++v) {
      int idx = (bi * 64 + tr + 16 * u) * 256 + bj * 64 + tc + 16 * v;
      O[idx] = 1.5f * D[idx] - 0.5f * acc[u][v];
    }
}

// ---------------- S_total = sqrt(s)*tr(Y) + 256*sqrt(rt) ----------------
__global__ void k_ns_trace(const float* __restrict__ Y, float* __restrict__ scal) {
  __shared__ float red[4];
  int t = threadIdx.x;  // 256
  float v = Y[t * 256 + t];
  v = waveSum(v);
  if ((t & 63) == 0) red[t >> 6] = v;
  __syncthreads();
  if (t == 0) {
    float tr = red[0] + red[1] + red[2] + red[3];
    float rt = scal[0] * (1.0f / 255.0f) * (1e-3f / 512.0f);
    scal[2] = sqrtf(scal[5]) * tr + 256.0f * sqrtf(rt);
  }
}

// ---------------- d2: out[i][j] = xsq[base+j] - 2*dot(T[i],X[base+j]) ----------------
// interleaved conflict-free b mapping; width/base parametrized
__global__ void __launch_bounds__(256) k_d2(const float* __restrict__ T, const float* __restrict__ X,
                                            const float* __restrict__ xsq, float* __restrict__ out,
                                            int base, int width) {
  __shared__ float Ts[16][132], Xs[16][132];
  int bi = blockIdx.x, bj = blockIdx.y;
  int t = threadIdx.x;
  int tr = t >> 4, tc = t & 15;
  float acc[8][8] = {{0.f}};
  for (int k0 = 0; k0 < 512; k0 += 16) {
#pragma unroll
    for (int p2 = 0; p2 < 8; ++p2) {
      int l = t + 256 * p2;
      int kk = l & 15, r = l >> 4;
      Ts[kk][r] = T[(bi * 128 + r) * 512 + k0 + kk];
      int jg = base + bj * 128 + r;
      if (jg > NN - 1) jg = NN - 1;
      Xs[kk][r] = X[jg * 512 + k0 + kk];
    }
    __syncthreads();
#pragma unroll
    for (int kk = 0; kk < 16; ++kk) {
      float a[8], b[8];
#pragma unroll
      for (int u = 0; u < 8; ++u) a[u] = Ts[kk][tr * 8 + u];
#pragma unroll
      for (int v = 0; v < 8; ++v) b[v] = Xs[kk][tc + 16 * v];
#pragma unroll
      for (int u = 0; u < 8; ++u)
#pragma unroll
        for (int v = 0; v < 8; ++v) acc[u][v] += a[u] * b[v];
    }
    __syncthreads();
  }
#pragma unroll
  for (int u = 0; u < 8; ++u) {
    int i = bi * 128 + tr * 8 + u;
#pragma unroll
    for (int v = 0; v < 8; ++v) {
      int j = bj * 128 + tc + 16 * v;
      if (j < width) out[(size_t)i * width + j] = xsq[base + j] - 2.0f * acc[u][v];
    }
  }
}

// ---------------- init running top-k ----------------
__global__ void k_topk_init(float* __restrict__ runv, int* __restrict__ runi) {
  int i = blockIdx.x * 256 + threadIdx.x;
  runv[i] = FLT_MAX;
  runi[i] = 0x7fffffff;
}

// ---------------- per-query top-32 merge over one chunk ----------------
__global__ void __launch_bounds__(128) k_topk_merge(const float* __restrict__ d2c,
                                                    float* __restrict__ runv, int* __restrict__ runi,
                                                    int base, int width) {
  __shared__ float cv[128 * 32];
  __shared__ int ci[128 * 32];
  __shared__ float rv[2];
  __shared__ int rgi[2], rsl[2];
  int q = blockIdx.x, t = threadIdx.x;
  float* mv = &cv[t * 32];
  int* mi = &ci[t * 32];
  int cnt = 0;
  float wval = -FLT_MAX; int widx = 0, wpos = 0;
  auto recompute = [&]() {
    wval = mv[0]; widx = mi[0]; wpos = 0;
    for (int s = 1; s < 32; ++s) {
      float a = mv[s]; int b2 = mi[s];
      if (a > wval || (a == wval && b2 > widx)) { wval = a; widx = b2; wpos = s; }
    }
  };
  auto push = [&](float val, int idx) {
    if (cnt < 32) {
      mv[cnt] = val; mi[cnt] = idx;
      if (++cnt == 32) recompute();
    } else if (val < wval || (val == wval && idx < widx)) {
      mv[wpos] = val; mi[wpos] = idx;
      recompute();
    }
  };
  if (t < 32) push(runv[q * 32 + t], runi[q * 32 + t]);
  for (int j = t; j < width; j += 128) push(d2c[(size_t)q * width + j], base + j);
  for (int s = cnt; s < 32; ++s) { mv[s] = FLT_MAX; mi[s] = 0x7fffffff; }
  __syncthreads();
  for (int r = 0; r < 32; ++r) {
    float bv = FLT_MAX; int bi2 = 0x7fffffff, bs = t * 32;
    for (int s = 0; s < 32; ++s) {
      float a = cv[t * 32 + s]; int b2 = ci[t * 32 + s];
      if (a < bv || (a == bv && b2 < bi2)) { bv = a; bi2 = b2; bs = t * 32 + s; }
    }
#pragma unroll
    for (int off = 32; off > 0; off >>= 1) {
      float ov = __shfl_down(bv, off);
      int oi = __shfl_down(bi2, off);
      int os = __shfl_down(bs, off);
      if (ov < bv || (ov == bv && oi < bi2)) { bv = ov; bi2 = oi; bs = os; }
    }
    int w = t >> 6;
    if ((t & 63) == 0) { rv[w] = bv; rgi[w] = bi2; rsl[w] = bs; }
    __syncthreads();
    if (t == 0) {
      float v0 = rv[0]; int i0 = rgi[0], s0 = rsl[0];
      if (rv[1] < v0 || (rv[1] == v0 && rgi[1] < i0)) { v0 = rv[1]; i0 = rgi[1]; s0 = rsl[1]; }
      runv[q * 32 + r] = v0;
      runi[q * 32 + r] = i0;
      cv[s0] = FLT_MAX; ci[s0] = 0x7fffffff;
    }
    __syncthreads();
  }
}

// ---------------- l2 to neighbors, softmax post_w, normalized pre_w ----------------
__global__ void __launch_bounds__(64) k_l2soft(const float* __restrict__ T, const float* __restrict__ X,
                                               const int* __restrict__ runi, const int* __restrict__ qidx,
                                               const float* __restrict__ prew, float* __restrict__ postw,
                                               float* __restrict__ prewn) {
  __shared__ float l2s[32];
  int b = blockIdx.x, lane = threadIdx.x;
  int qi = qidx[b];
  float pwv = (lane < 32) ? fmaxf(prew[qi * 32 + lane], 1e-8f) : 0.f;
  float psum = waveSum(pwv);
  if (lane < 32) prewn[b * 32 + lane] = pwv / psum;
  const float* Tb = T + b * 512;
  for (int n = 0; n < 32; ++n) {
    int nb = runi[b * 32 + n];
    const float* Xr = X + nb * 512;
    float acc = 0.f;
#pragma unroll
    for (int d = 0; d < 8; ++d) {
      float df = Tb[lane + 64 * d] - Xr[lane + 64 * d];
      acc += df * df;
    }
    acc = waveSum(acc);
    if (lane == 0) l2s[n] = acc;
  }
  __syncthreads();
  float lg = (lane < 32) ? (-l2s[lane] * 10.0f) : -FLT_MAX;
  float mx = lg;
#pragma unroll
  for (int off = 32; off > 0; off >>= 1) mx = fmaxf(mx, __shfl_xor(mx, off));
  float e = (lane < 32) ? expf(lg - mx) : 0.f;
  float es = waveSum(e);
  float wv = e / es;
  wv = fmaxf(wv, 1e-8f);
  float ws2 = (lane < 32) ? wv : 0.f;
  ws2 = waveSum(ws2);
  if (lane < 32) postw[b * 32 + lane] = wv / ws2;
}

// ---------------- fused per-batch: Gram -> C -> median -> Sinkhorn(200) -> loss ----------------
__global__ void __launch_bounds__(256) k_batch(const float* __restrict__ X, const int* __restrict__ qidx,
                                               const int* __restrict__ pre_idx, const int* __restrict__ runi,
                                               const float* __restrict__ prewn, const float* __restrict__ postw,
                                               float* __restrict__ scal) {
  __shared__ float G[64][65];   // Gram, later reused as Kmat
  __shared__ float Cm[64][65];
  __shared__ float SB[4160];    // staging / sort buffer
  __shared__ int supp[64];
  __shared__ float pv[64], qv[64], uu[64], vv[64];
  __shared__ float rbuf[4][64];
  __shared__ float medsh;
  int b = blockIdx.x, t = threadIdx.x;
  if (t < 32) supp[t] = pre_idx[qidx[b] * 32 + t];
  else if (t < 64) supp[t] = runi[b * 32 + t - 32];
  __syncthreads();
  int tr = t >> 4, tc = t & 15;
  float acc[4][4] = {{0.f}};
  for (int kc = 0; kc < 512; kc += 64) {
    __syncthreads();
#pragma unroll
    for (int p2 = 0; p2 < 16; ++p2) {
      int l = t + 256 * p2;
      int r = l >> 6, c = l & 63;
      SB[r * 65 + c] = X[supp[r] * 512 + kc + c];
    }
    __syncthreads();
#pragma unroll 8
    for (int kk = 0; kk < 64; ++kk) {
      float a[4], bb[4];
#pragma unroll
      for (int u = 0; u < 4; ++u) a[u] = SB[(tr * 4 + u) * 65 + kk];
#pragma unroll
      for (int v = 0; v < 4; ++v) bb[v] = SB[(tc * 4 + v) * 65 + kk];
#pragma unroll
      for (int u = 0; u < 4; ++u)
#pragma unroll
        for (int v = 0; v < 4; ++v) acc[u][v] += a[u] * bb[v];
    }
  }
  __syncthreads();
#pragma unroll
  for (int u = 0; u < 4; ++u)
#pragma unroll
    for (int v = 0; v < 4; ++v) G[tr * 4 + u][tc * 4 + v] = acc[u][v];
  __syncthreads();
  for (int l = t; l < 4096; l += 256) {
    int i = l >> 6, j = l & 63;
    float cc = fmaxf(G[i][i] + G[j][j] - 2.0f * G[i][j], 0.f);
    Cm[i][j] = cc;
    SB[l] = cc;
  }
  // bitonic sort 4096 ascending
  for (int ssz = 2; ssz <= 4096; ssz <<= 1) {
    for (int st = ssz >> 1; st > 0; st >>= 1) {
      __syncthreads();
      for (int l = t; l < 2048; l += 256) {
        int i = 2 * l - (l & (st - 1));
        int j = i + st;
        bool up = ((i & ssz) == 0);
        float a = SB[i], b2 = SB[j];
        if ((a > b2) == up) { SB[i] = b2; SB[j] = a; }
      }
    }
  }
  __syncthreads();
  if (t == 0) medsh = 0.5f * (SB[2047] + SB[2048]) + 1e-8f;
  __syncthreads();
  float inv = 1.0f / medsh;
  for (int l = t; l < 4096; l += 256) {
    int i = l >> 6, j = l & 63;
    float cn = Cm[i][j] * inv;
    Cm[i][j] = cn;
    G[i][j] = expf(-cn * 10.0f);   // K = exp(-C/eps), eps=0.1
  }
  if (t < 64) {
    pv[t] = (t < 32) ? prewn[b * 32 + t] : 0.f;
    qv[t] = (t < 32) ? 0.f : postw[b * 32 + (t - 32)];
    uu[t] = 1.f; vv[t] = 1.f;
  }
  __syncthreads();
  int g = t >> 6, i0 = t & 63;
  for (int it = 0; it < 200; ++it) {
    float s2 = 0.f;
#pragma unroll
    for (int j2 = 0; j2 < 16; ++j2) s2 += G[i0][g * 16 + j2] * vv[g * 16 + j2];
    rbuf[g][i0] = s2;
    __syncthreads();
    if (t < 64) uu[t] = pv[t] / (rbuf[0][t] + rbuf[1][t] + rbuf[2][t] + rbuf[3][t] + 1e-16f);
    __syncthreads();
    s2 = 0.f;
#pragma unroll
    for (int j2 = 0; j2 < 16; ++j2) s2 += G[g * 16 + j2][i0] * uu[g * 16 + j2];
    rbuf[g][i0] = s2;
    __syncthreads();
    if (t < 64) vv[t] = qv[t] / (rbuf[0][t] + rbuf[1][t] + rbuf[2][t] + rbuf[3][t] + 1e-16f);
    __syncthreads();
  }
  float lacc = 0.f;
  for (int l = t; l < 4096; l += 256) {
    int i = l >> 6, j = l & 63;
    lacc += uu[i] * G[i][j] * vv[j] * Cm[i][j];
  }
  lacc = waveSum(lacc);
  if ((t & 63) == 0) rbuf[0][t >> 6] = lacc;
  __syncthreads();
  if (t == 0)
    atomicAdd(&scal[3], (rbuf[0][0] + rbuf[0][1] + rbuf[0][2] + rbuf[0][3]) * (1.0f / 256.0f));
}

// ---------------- sum(W^2) ----------------
__global__ void k_wreg(const float* __restrict__ W, float* __restrict__ scal) {
  __shared__ float red[4];
  int t = threadIdx.x;
  int base = blockIdx.x * 2048;
  float ss = 0.f;
#pragma unroll
  for (int p = 0; p < 8; ++p) {
    float v = W[base + p * 256 + t];
    ss += v * v;
  }
  ss = waveSum(ss);
  if ((t & 63) == 0) red[t >> 6] = ss;
  __syncthreads();
  if (t == 0) atomicAdd(&scal[4], red[0] + red[1] + red[2] + red[3]);
}

// ---------------- final combine ----------------
__global__ void k_combine(const float* __restrict__ mu_t, const float* __restrict__ colsum,
                          const float* __restrict__ scal, float* __restrict__ out) {
  __shared__ float red[8];
  int t = threadIdx.x;  // 512
  float dm = mu_t[t] - colsum[t] * (1.0f / 50000.0f);
  float v = dm * dm;
  v = waveSum(v);
  if ((t & 63) == 0) red[t >> 6] = v;
  __syncthreads();
  if (t == 0) {
    float term_mean = 0.f;
    for (int i = 0; i < 8; ++i) term_mean += red[i];
    float trCT = scal[0] * (1.0f / 255.0f);
    float trCX = scal[1];
    float S = scal[2];
    float term_cov = trCX * 1.001f + trCT * 1.001f - 2.0f * S;
    term_cov = fmaxf(term_cov, 0.f);
    float loss_dist = term_mean + term_cov;
    float loss_knn = scal[3];
    float loss_reg = 0.5f * scal[4];
    out[0] = loss_dist + loss_knn + 1e-4f * loss_reg;
    out[1] = loss_dist;
    out[2] = loss_knn;
  }
}

extern "C" void kernel_launch(void* const* d_in, const int* in_sizes, int n_in,
                              void* d_out, int out_size, void* d_ws, size_t ws_size,
                              hipStream_t stream) {
  const float* q = (const float*)d_in[0];
  const int* qidx = (const int*)d_in[1];
  const float* W = (const float*)d_in[2];
  const float* X = (const float*)d_in[3];
  const int* pre_idx = (const int*)d_in[4];
  const float* prew = (const float*)d_in[5];
  float* out = (float*)d_out;
  float* ws = (float*)d_ws;

  float* G = ws + OFF_G;
  float* scal = ws + OFF_SC;
  float* colsum = ws + OFF_CS;
  float* colss = ws + OFF_CSS;
  float* T = ws + OFF_T;
  float* Tc = ws + OFF_TC;
  float* P = ws + OFF_P;
  float* H = ws + OFF_H;
  float* rows = ws + OFF_DDI;
  float* mu_t = ws + OFF_MUT;
  float* xsq = ws + OFF_XSQ;
  float* runv = ws + OFF_RUNV;
  int* runi = (int*)(ws + OFF_RUNI);
  float* postw = ws + OFF_PW;
  float* prewn = ws + OFF_PRW;
  float* d2c = ws + OFF_D2;

  hipMemsetAsync(d_ws, 0, (size_t)ZERO_F * 4, stream);

  // T = q @ W  [256x512 = 256x512 @ 512x512]
  k_g64_nn<<<dim3(8, 4), 256, 0, stream>>>(q, W, T, 512, 512, 512, 512, 1.0f);
  // X column stats, per-row sq norms, X^T X (upper block-triangle)
  k_colstatX<<<256, 256, 0, stream>>>(X, colsum, colss);
  k_xsq<<<12500, 256, 0, stream>>>(X, xsq);
  k_xtx<<<dim3(10, 50), 256, 0, stream>>>(X, G);
  // T stats
  k_colmeanT<<<1, 512, 0, stream>>>(T, mu_t);
  k_centerT<<<128, 256, 0, stream>>>(T, mu_t, Tc, scal);
  // SigmaX
  k_trCX<<<1, 512, 0, stream>>>(colsum, colss, scal);
  k_finSX<<<dim3(32, 32), dim3(16, 16), 0, stream>>>(G, colsum, scal);
  // H = Tc SigmaX Tc^T / 255
  k_g64_nn<<<dim3(8, 4), 256, 0, stream>>>(Tc, G, P, 512, 512, 512, 512, 1.0f);
  k_g64_nt<<<dim3(4, 4), 256, 0, stream>>>(P, Tc, H, 512, 512, 512, 256, 1.0f / 255.0f);
  // spectral sum via coupled Newton-Schulz sqrt of H' = H + rt*I
  {
    float* Y = ws + OFF_TC;
    float* Z = ws + OFF_TC + 65536;
    float* Y2 = ws + OFF_P;
    float* Z2 = ws + OFF_P + 65536;
    float* Pm = ws + OFF_G;
    k_rowsum<<<256, 64, 0, stream>>>(H, scal, rows);
    k_nsmax<<<1, 256, 0, stream>>>(rows, scal);
    k_nsinit<<<256, 256, 0, stream>>>(H, scal, Y, Z);
    for (int it = 0; it < NS_ITERS; ++it) {
      k_g64_nn<<<dim3(4, 4), 256, 0, stream>>>(Z, Y, Pm, 256, 256, 256, 256, 1.0f);
      k_ns_upd<<<dim3(4, 4, 2), 256, 0, stream>>>(Y, Z, Pm, Y2, Z2);
      float* tmp = Y; Y = Y2; Y2 = tmp;
      tmp = Z; Z = Z2; Z2 = tmp;
    }
    k_ns_trace<<<1, 256, 0, stream>>>(Y, scal);
  }
  // kNN: full-width single pass if workspace allows, else 4 chunks
  k_topk_init<<<32, 256, 0, stream>>>(runv, runi);
  size_t needF = (size_t)OFF_D2 + (size_t)256 * 50000 + 64;
  if (ws_size >= needF * 4) {
    k_d2<<<dim3(2, 391), 256, 0, stream>>>(T, X, xsq, d2c, 0, 50000);
    k_topk_merge<<<256, 128, 0, stream>>>(d2c, runv, runi, 0, 50000);
  } else {
    for (int c = 0; c < 4; ++c) {
      k_d2<<<dim3(2, 98), 256, 0, stream>>>(T, X, xsq, d2c, c * CHUNK, CHUNK);
      k_topk_merge<<<256, 128, 0, stream>>>(d2c, runv, runi, c * CHUNK, CHUNK);
    }
  }
  k_l2soft<<<256, 64, 0, stream>>>(T, X, runi, qidx, prew, postw, prewn);
  k_batch<<<256, 256, 0, stream>>>(X, qidx, pre_idx, runi, prewn, postw, scal);
  k_wreg<<<128, 256, 0, stream>>>(W, scal);
  k_combine<<<1, 512, 0, stream>>>(mu_t, colsum, scal, out);
}

// Round 4
// 2173.390 us; speedup vs baseline: 2.5705x; 1.4063x over previous
//
#include <hip/hip_runtime.h>
#include <float.h>
#include <math.h>

// Problem constants
#define BB 256
#define DD 512
#define NN 50000
#define KK 32
#define CHUNK 12500
#define NS_ITERS 18

// Workspace layout (float offsets)
#define OFF_G     0         // 512*512  Gram X^TX -> SigmaX (zeroed); later NS "Pm"; later top-k cand buf
#define OFF_SC    262144    // 64 scalars (zeroed): 0=sumTc2 1=trCX 2=S_total 3=knn 4=wreg 5=gersh
#define OFF_CS    262208    // 512 colsum X (zeroed)
#define OFF_CSS   262720    // 512 colsumsq X (zeroed)
#define ZERO_F    263232    // floats to memset
#define OFF_T     263232    // 256*512
#define OFF_TC    394304    // 256*512 (dead after H -> NS Y/Z)
#define OFF_P     525376    // 256*512 (dead after H -> NS Y2/Z2)
#define OFF_H     656448    // 256*256
#define OFF_DDI   721984    // 256 (rowsum scratch)
#define OFF_EEO   722240    // 256
#define OFF_MUT   722496    // 512
#define OFF_XSQ   723008    // 50000
#define OFF_RUNV  773008    // 256*32
#define OFF_RUNI  781200    // 256*32 (int)
#define OFF_PW    789392    // 256*32 post_w
#define OFF_PRW   797584    // 256*32 pre_w normalized
#define OFF_D2    805776    // 256*12500 (chunked) or 256*50000 (full, if ws allows)

__device__ __forceinline__ float waveSum(float v) {
#pragma unroll
  for (int off = 32; off > 0; off >>= 1) v += __shfl_xor(v, off);
  return v;
}

// ---------------- generic 64x64-tile GEMM, C = scale * A @ B (nn) ----------------
__global__ void __launch_bounds__(256) k_g64_nn(const float* __restrict__ A,
                                                const float* __restrict__ B,
                                                float* __restrict__ C,
                                                int K, int lda, int ldb, int ldc, float scale) {
  __shared__ float As[64][65], Bs[64][65];
  int m0 = blockIdx.y * 64, n0 = blockIdx.x * 64;
  int t = threadIdx.x, tr = t >> 4, tc = t & 15;
  float acc[4][4] = {{0.f}};
  for (int k0 = 0; k0 < K; k0 += 64) {
#pragma unroll
    for (int p = 0; p < 16; ++p) {
      int l = t + 256 * p;
      int r = l >> 6, c = l & 63;
      As[r][c] = A[(m0 + r) * lda + k0 + c];
      Bs[r][c] = B[(k0 + r) * ldb + n0 + c];
    }
    __syncthreads();
#pragma unroll 16
    for (int kk = 0; kk < 64; ++kk) {
      float a[4], b[4];
#pragma unroll
      for (int u = 0; u < 4; ++u) a[u] = As[tr + 16 * u][kk];
#pragma unroll
      for (int v = 0; v < 4; ++v) b[v] = Bs[kk][tc + 16 * v];
#pragma unroll
      for (int u = 0; u < 4; ++u)
#pragma unroll
        for (int v = 0; v < 4; ++v) acc[u][v] += a[u] * b[v];
    }
    __syncthreads();
  }
#pragma unroll
  for (int u = 0; u < 4; ++u)
#pragma unroll
    for (int v = 0; v < 4; ++v)
      C[(m0 + tr + 16 * u) * ldc + n0 + tc + 16 * v] = acc[u][v] * scale;
}

// ---------------- generic 64x64-tile GEMM, C = scale * A @ B^T (nt) ----------------
__global__ void __launch_bounds__(256) k_g64_nt(const float* __restrict__ A,
                                                const float* __restrict__ B,
                                                float* __restrict__ C,
                                                int K, int lda, int ldb, int ldc, float scale) {
  __shared__ float As[64][65], Bs[64][65];
  int m0 = blockIdx.y * 64, n0 = blockIdx.x * 64;
  int t = threadIdx.x, tr = t >> 4, tc = t & 15;
  float acc[4][4] = {{0.f}};
  for (int k0 = 0; k0 < K; k0 += 64) {
#pragma unroll
    for (int p = 0; p < 16; ++p) {
      int l = t + 256 * p;
      int r = l >> 6, c = l & 63;
      As[r][c] = A[(m0 + r) * lda + k0 + c];
      Bs[r][c] = B[(n0 + r) * ldb + k0 + c];  // Bs[n][k]
    }
    __syncthreads();
#pragma unroll 16
    for (int kk = 0; kk < 64; ++kk) {
      float a[4], b[4];
#pragma unroll
      for (int u = 0; u < 4; ++u) a[u] = As[tr + 16 * u][kk];
#pragma unroll
      for (int v = 0; v < 4; ++v) b[v] = Bs[tc + 16 * v][kk];
#pragma unroll
      for (int u = 0; u < 4; ++u)
#pragma unroll
        for (int v = 0; v < 4; ++v) acc[u][v] += a[u] * b[v];
    }
    __syncthreads();
  }
#pragma unroll
  for (int u = 0; u < 4; ++u)
#pragma unroll
    for (int v = 0; v < 4; ++v)
      C[(m0 + tr + 16 * u) * ldc + n0 + tc + 16 * v] = acc[u][v] * scale;
}

// ---------------- column sums & sumsq of X (atomic) ----------------
__global__ void k_colstatX(const float* __restrict__ X, float* __restrict__ colsum,
                           float* __restrict__ colss) {
  int b = blockIdx.x, t = threadIdx.x;
  int r0 = b * 196;
  int r1 = r0 + 196; if (r1 > NN) r1 = NN;
  float s1 = 0, ss1 = 0, s2 = 0, ss2 = 0;
  for (int r = r0; r < r1; ++r) {
    float v1 = X[r * 512 + t], v2 = X[r * 512 + t + 256];
    s1 += v1; ss1 += v1 * v1; s2 += v2; ss2 += v2 * v2;
  }
  atomicAdd(&colsum[t], s1);       atomicAdd(&colss[t], ss1);
  atomicAdd(&colsum[t + 256], s2); atomicAdd(&colss[t + 256], ss2);
}

// ---------------- per-row squared norm of X ----------------
__global__ void k_xsq(const float* __restrict__ X, float* __restrict__ xsq) {
  int row = blockIdx.x * 4 + (threadIdx.x >> 6);
  int lane = threadIdx.x & 63;
  const float* Xr = X + row * 512;
  float s = 0.f;
#pragma unroll
  for (int d = 0; d < 8; ++d) { float v = Xr[lane + 64 * d]; s += v * v; }
  s = waveSum(s);
  if (lane == 0) xsq[row] = s;
}

// ---------------- G += X^T X  (split-K, atomic, upper block-triangle only) ----------------
__global__ void __launch_bounds__(256) k_xtx(const float* __restrict__ X, float* __restrict__ G) {
  const int pi_[10] = {0, 0, 0, 0, 1, 1, 1, 2, 2, 3};
  const int pj_[10] = {0, 1, 2, 3, 1, 2, 3, 2, 3, 3};
  __shared__ float Ai[16][132], Aj[16][132];
  int bi = pi_[blockIdx.x], bj = pj_[blockIdx.x];
  int kstart = blockIdx.y * 1008;
  int t = threadIdx.x;
  int tr = t >> 4, tc = t & 15;
  float acc[8][8] = {{0.f}};
  for (int kb = 0; kb < 1008; kb += 16) {
#pragma unroll
    for (int p2 = 0; p2 < 8; ++p2) {
      int l = t + 256 * p2;
      int kk = l >> 7, ii = l & 127;
      int gr = kstart + kb + kk;
      bool ok = gr < NN;
      Ai[kk][ii] = ok ? X[gr * 512 + bi * 128 + ii] : 0.f;
      Aj[kk][ii] = ok ? X[gr * 512 + bj * 128 + ii] : 0.f;
    }
    __syncthreads();
#pragma unroll
    for (int kk = 0; kk < 16; ++kk) {
      float a[8], b[8];
#pragma unroll
      for (int u = 0; u < 8; ++u) a[u] = Ai[kk][tr * 8 + u];
#pragma unroll
      for (int v = 0; v < 8; ++v) b[v] = Aj[kk][tc + 16 * v];
#pragma unroll
      for (int u = 0; u < 8; ++u)
#pragma unroll
        for (int v = 0; v < 8; ++v) acc[u][v] += a[u] * b[v];
    }
    __syncthreads();
  }
#pragma unroll
  for (int u = 0; u < 8; ++u)
#pragma unroll
    for (int v = 0; v < 8; ++v)
      atomicAdd(&G[(bi * 128 + tr * 8 + u) * 512 + bj * 128 + tc + 16 * v], acc[u][v]);
}

// ---------------- column means of T ----------------
__global__ void k_colmeanT(const float* __restrict__ T, float* __restrict__ mu) {
  int c = threadIdx.x;
  float s = 0.f;
  for (int r = 0; r < 256; ++r) s += T[r * 512 + c];
  mu[c] = s * (1.0f / 256.0f);
}

// ---------------- Tc = T - mu, accumulate sum(Tc^2) ----------------
__global__ void k_centerT(const float* __restrict__ T, const float* __restrict__ mu,
                          float* __restrict__ Tc, float* __restrict__ scal) {
  __shared__ float red[4];
  int t = threadIdx.x;
  int base = blockIdx.x * 1024;
  float ss = 0.f;
#pragma unroll
  for (int p = 0; p < 4; ++p) {
    int l = base + p * 256 + t;
    float v = T[l] - mu[l & 511];
    Tc[l] = v;
    ss += v * v;
  }
  ss = waveSum(ss);
  if ((t & 63) == 0) red[t >> 6] = ss;
  __syncthreads();
  if (t == 0) atomicAdd(&scal[0], red[0] + red[1] + red[2] + red[3]);
}

// ---------------- trace of cov(X) ----------------
__global__ void k_trCX(const float* __restrict__ colsum, const float* __restrict__ colss,
                       float* __restrict__ scal) {
  __shared__ float red[8];
  int t = threadIdx.x;  // 512
  float mu = colsum[t] * (1.0f / 50000.0f);
  float v = (colss[t] - 50000.0f * mu * mu) * (1.0f / 49999.0f);
  v = waveSum(v);
  if ((t & 63) == 0) red[t >> 6] = v;
  __syncthreads();
  if (t == 0) {
    float s = 0;
    for (int i = 0; i < 8; ++i) s += red[i];
    scal[1] = s;
  }
}

// ---------------- finalize SigmaX in place on G (upper triangle valid) ----------------
__global__ void k_finSX(float* __restrict__ G, const float* __restrict__ colsum,
                        const float* __restrict__ scal) {
  int i = blockIdx.y * 16 + threadIdx.y, j = blockIdx.x * 16 + threadIdx.x;
  if (i > j) return;
  float mi = colsum[i] * (1.0f / 50000.0f), mj = colsum[j] * (1.0f / 50000.0f);
  float g = G[i * 512 + j];
  float v = (g - 50000.0f * mi * mj) * (1.0f / 49999.0f);
  if (i == j) v += scal[1] * (1e-3f / 512.0f);
  G[i * 512 + j] = v;
  G[j * 512 + i] = v;
}

// ---------------- Gershgorin row sums of H' = H + rt*I ----------------
__global__ void k_rowsum(const float* __restrict__ H, const float* __restrict__ scal,
                         float* __restrict__ rows) {
  int b = blockIdx.x, lane = threadIdx.x;  // 64 threads
  float rt = scal[0] * (1.0f / 255.0f) * (1e-3f / 512.0f);
  float s = 0.f;
#pragma unroll
  for (int p = 0; p < 4; ++p) {
    int j = lane + 64 * p;
    float v = H[b * 256 + j] + ((j == b) ? rt : 0.f);
    s += fabsf(v);
  }
  s = waveSum(s);
  if (lane == 0) rows[b] = s;
}

// ---------------- max row sum -> scal[5] ----------------
__global__ void k_nsmax(const float* __restrict__ rows, float* __restrict__ scal) {
  __shared__ float red[4];
  int t = threadIdx.x;  // 256
  float m = rows[t];
#pragma unroll
  for (int off = 32; off > 0; off >>= 1) m = fmaxf(m, __shfl_xor(m, off));
  if ((t & 63) == 0) red[t >> 6] = m;
  __syncthreads();
  if (t == 0) scal[5] = fmaxf(fmaxf(red[0], red[1]), fmaxf(red[2], red[3]));
}

// ---------------- Y0 = (H + rt I)/s, Z0 = I ----------------
__global__ void k_nsinit(const float* __restrict__ H, const float* __restrict__ scal,
                         float* __restrict__ Y, float* __restrict__ Z) {
  int l = blockIdx.x * 256 + threadIdx.x;
  int i = l >> 8, j = l & 255;
  float rt = scal[0] * (1.0f / 255.0f) * (1e-3f / 512.0f);
  float inv = 1.0f / scal[5];
  Y[l] = (H[l] + ((i == j) ? rt : 0.f)) * inv;
  Z[l] = (i == j) ? 1.0f : 0.f;
}

// ---------------- NS update: z=0 Yn=1.5Y-0.5*Y@P ; z=1 Zn=1.5Z-0.5*P@Z ----------------
__global__ void __launch_bounds__(256) k_ns_upd(const float* __restrict__ Y, const float* __restrict__ Z,
                                                const float* __restrict__ P,
                                                float* __restrict__ Yn, float* __restrict__ Zn) {
  __shared__ float As[64][65], Bs[64][65];
  int bi = blockIdx.x, bj = blockIdx.y, zz = blockIdx.z;
  const float* A = zz ? P : Y;
  const float* B = zz ? Z : P;
  const float* D = zz ? Z : Y;
  float* O = zz ? Zn : Yn;
  int t = threadIdx.x;
  int tr = t >> 4, tc = t & 15;
  float acc[4][4] = {{0.f}};
  for (int k0 = 0; k0 < 256; k0 += 64) {
#pragma unroll
    for (int p = 0; p < 16; ++p) {
      int l = t + 256 * p;
      int r = l >> 6, c = l & 63;
      As[r][c] = A[(bi * 64 + r) * 256 + k0 + c];
      Bs[r][c] = B[(k0 + r) * 256 + bj * 64 + c];
    }
    __syncthreads();
#pragma unroll 16
    for (int kk = 0; kk < 64; ++kk) {
      float a[4], b[4];
#pragma unroll
      for (int u = 0; u < 4; ++u) a[u] = As[tr + 16 * u][kk];
#pragma unroll
      for (int v = 0; v < 4; ++v) b[v] = Bs[kk][tc + 16 * v];
#pragma unroll
      for (int u = 0; u < 4; ++u)
#pragma unroll
        for (int v = 0; v < 4; ++v) acc[u][v] += a[u] * b[v];
    }
    __syncthreads();
  }
#pragma unroll
  for (int u = 0; u < 4; ++u)
#pragma unroll
    for (int v = 0; v < 4; ++v) {
      int idx = (bi * 64 + tr + 16 * u) * 256 + bj * 64 + tc + 16 * v;
      O[idx] = 1.5f * D[idx] - 0.5f * acc[u][v];
    }
}

// ---------------- S_total = sqrt(s)*tr(Y) + 256*sqrt(rt) ----------------
__global__ void k_ns_trace(const float* __restrict__ Y, float* __restrict__ scal) {
  __shared__ float red[4];
  int t = threadIdx.x;  // 256
  float v = Y[t * 256 + t];
  v = waveSum(v);
  if ((t & 63) == 0) red[t >> 6] = v;
  __syncthreads();
  if (t == 0) {
    float tr = red[0] + red[1] + red[2] + red[3];
    float rt = scal[0] * (1.0f / 255.0f) * (1e-3f / 512.0f);
    scal[2] = sqrtf(scal[5]) * tr + 256.0f * sqrtf(rt);
  }
}

// ---------------- d2: out[i][j] = xsq[base+j] - 2*dot(T[i],X[base+j]) ----------------
__global__ void __launch_bounds__(256) k_d2(const float* __restrict__ T, const float* __restrict__ X,
                                            const float* __restrict__ xsq, float* __restrict__ out,
                                            int base, int width) {
  __shared__ float Ts[16][132], Xs[16][132];
  int bi = blockIdx.x, bj = blockIdx.y;
  int t = threadIdx.x;
  int tr = t >> 4, tc = t & 15;
  float acc[8][8] = {{0.f}};
  for (int k0 = 0; k0 < 512; k0 += 16) {
#pragma unroll
    for (int p2 = 0; p2 < 8; ++p2) {
      int l = t + 256 * p2;
      int kk = l & 15, r = l >> 4;
      Ts[kk][r] = T[(bi * 128 + r) * 512 + k0 + kk];
      int jg = base + bj * 128 + r;
      if (jg > NN - 1) jg = NN - 1;
      Xs[kk][r] = X[jg * 512 + k0 + kk];
    }
    __syncthreads();
#pragma unroll
    for (int kk = 0; kk < 16; ++kk) {
      float a[8], b[8];
#pragma unroll
      for (int u = 0; u < 8; ++u) a[u] = Ts[kk][tr * 8 + u];
#pragma unroll
      for (int v = 0; v < 8; ++v) b[v] = Xs[kk][tc + 16 * v];
#pragma unroll
      for (int u = 0; u < 8; ++u)
#pragma unroll
        for (int v = 0; v < 8; ++v) acc[u][v] += a[u] * b[v];
    }
    __syncthreads();
  }
#pragma unroll
  for (int u = 0; u < 8; ++u) {
    int i = bi * 128 + tr * 8 + u;
#pragma unroll
    for (int v = 0; v < 8; ++v) {
      int j = bj * 128 + tc + 16 * v;
      if (j < width) out[(size_t)i * width + j] = xsq[base + j] - 2.0f * acc[u][v];
    }
  }
}

// ---------------- init running top-k (fallback path) ----------------
__global__ void k_topk_init(float* __restrict__ runv, int* __restrict__ runi) {
  int i = blockIdx.x * 256 + threadIdx.x;
  runv[i] = FLT_MAX;
  runi[i] = 0x7fffffff;
}

// ---------------- stage 1: per-(query, quarter) exact top-32 -> cand buffer ----------------
// grid (4, 256), 128 threads. Transposed LDS heap layout: cv[s][t] (conflict-free).
__global__ void __launch_bounds__(128) k_topk_part(const float* __restrict__ d2c,
                                                   float* __restrict__ candv,
                                                   int* __restrict__ candi) {
  __shared__ float cv[32][128];
  __shared__ int ci[32][128];
  __shared__ float rv[2];
  __shared__ int rgi[2], rsl[2];
  int part = blockIdx.x, q = blockIdx.y, t = threadIdx.x;
  int base = part * CHUNK;
  int cnt = 0;
  float wval = -FLT_MAX; int widx = 0, wpos = 0;
  auto recompute = [&]() {
    wval = cv[0][t]; widx = ci[0][t]; wpos = 0;
    for (int s = 1; s < 32; ++s) {
      float a = cv[s][t]; int b2 = ci[s][t];
      if (a > wval || (a == wval && b2 > widx)) { wval = a; widx = b2; wpos = s; }
    }
  };
  auto push = [&](float val, int idx) {
    if (cnt < 32) {
      cv[cnt][t] = val; ci[cnt][t] = idx;
      if (++cnt == 32) recompute();
    } else if (val < wval || (val == wval && idx < widx)) {
      cv[wpos][t] = val; ci[wpos][t] = idx;
      recompute();
    }
  };
  const float* row = d2c + (size_t)q * 50000 + base;
  for (int j = t; j < CHUNK; j += 128) push(row[j], base + j);
  for (int s = cnt; s < 32; ++s) { cv[s][t] = FLT_MAX; ci[s][t] = 0x7fffffff; }
  __syncthreads();
  for (int r = 0; r < 32; ++r) {
    float bv = FLT_MAX; int bi2 = 0x7fffffff, bs = t;
    for (int s = 0; s < 32; ++s) {
      float a = cv[s][t]; int b2 = ci[s][t];
      if (a < bv || (a == bv && b2 < bi2)) { bv = a; bi2 = b2; bs = s * 128 + t; }
    }
#pragma unroll
    for (int off = 32; off > 0; off >>= 1) {
      float ov = __shfl_down(bv, off);
      int oi = __shfl_down(bi2, off);
      int os = __shfl_down(bs, off);
      if (ov < bv || (ov == bv && oi < bi2)) { bv = ov; bi2 = oi; bs = os; }
    }
    int w = t >> 6;
    if ((t & 63) == 0) { rv[w] = bv; rgi[w] = bi2; rsl[w] = bs; }
    __syncthreads();
    if (t == 0) {
      float v0 = rv[0]; int i0 = rgi[0], s0 = rsl[0];
      if (rv[1] < v0 || (rv[1] == v0 && rgi[1] < i0)) { v0 = rv[1]; i0 = rgi[1]; s0 = rsl[1]; }
      candv[q * 128 + part * 32 + r] = v0;
      candi[q * 128 + part * 32 + r] = i0;
      cv[s0 >> 7][s0 & 127] = FLT_MAX; ci[s0 >> 7][s0 & 127] = 0x7fffffff;
    }
    __syncthreads();
  }
}

// ---------------- stage 2: bitonic-sort 128 candidates, emit top-32 indices ----------------
__global__ void __launch_bounds__(128) k_topk_final(const float* __restrict__ candv,
                                                    const int* __restrict__ candi,
                                                    int* __restrict__ runi) {
  __shared__ float v[128];
  __shared__ int ix[128];
  int q = blockIdx.x, t = threadIdx.x;
  v[t] = candv[q * 128 + t];
  ix[t] = candi[q * 128 + t];
  __syncthreads();
  for (int ssz = 2; ssz <= 128; ssz <<= 1) {
    for (int st = ssz >> 1; st > 0; st >>= 1) {
      if (t < 64) {
        int i = 2 * t - (t & (st - 1));
        int j = i + st;
        bool up = ((i & ssz) == 0);
        float a = v[i], b = v[j];
        int ai = ix[i], bi = ix[j];
        bool agtb = (a > b) || (a == b && ai > bi);
        if (agtb == up) { v[i] = b; v[j] = a; ix[i] = bi; ix[j] = ai; }
      }
      __syncthreads();
    }
  }
  if (t < 32) runi[q * 32 + t] = ix[t];
}

// ---------------- fallback: per-query top-32 merge over one chunk (transposed layout) ------
__global__ void __launch_bounds__(128) k_topk_merge(const float* __restrict__ d2c,
                                                    float* __restrict__ runv, int* __restrict__ runi,
                                                    int base, int width) {
  __shared__ float cv[32][128];
  __shared__ int ci[32][128];
  __shared__ float rv[2];
  __shared__ int rgi[2], rsl[2];
  int q = blockIdx.x, t = threadIdx.x;
  int cnt = 0;
  float wval = -FLT_MAX; int widx = 0, wpos = 0;
  auto recompute = [&]() {
    wval = cv[0][t]; widx = ci[0][t]; wpos = 0;
    for (int s = 1; s < 32; ++s) {
      float a = cv[s][t]; int b2 = ci[s][t];
      if (a > wval || (a == wval && b2 > widx)) { wval = a; widx = b2; wpos = s; }
    }
  };
  auto push = [&](float val, int idx) {
    if (cnt < 32) {
      cv[cnt][t] = val; ci[cnt][t] = idx;
      if (++cnt == 32) recompute();
    } else if (val < wval || (val == wval && idx < widx)) {
      cv[wpos][t] = val; ci[wpos][t] = idx;
      recompute();
    }
  };
  if (t < 32) push(runv[q * 32 + t], runi[q * 32 + t]);
  for (int j = t; j < width; j += 128) push(d2c[(size_t)q * width + j], base + j);
  for (int s = cnt; s < 32; ++s) { cv[s][t] = FLT_MAX; ci[s][t] = 0x7fffffff; }
  __syncthreads();
  for (int r = 0; r < 32; ++r) {
    float bv = FLT_MAX; int bi2 = 0x7fffffff, bs = t;
    for (int s = 0; s < 32; ++s) {
      float a = cv[s][t]; int b2 = ci[s][t];
      if (a < bv || (a == bv && b2 < bi2)) { bv = a; bi2 = b2; bs = s * 128 + t; }
    }
#pragma unroll
    for (int off = 32; off > 0; off >>= 1) {
      float ov = __shfl_down(bv, off);
      int oi = __shfl_down(bi2, off);
      int os = __shfl_down(bs, off);
      if (ov < bv || (ov == bv && oi < bi2)) { bv = ov; bi2 = oi; bs = os; }
    }
    int w = t >> 6;
    if ((t & 63) == 0) { rv[w] = bv; rgi[w] = bi2; rsl[w] = bs; }
    __syncthreads();
    if (t == 0) {
      float v0 = rv[0]; int i0 = rgi[0], s0 = rsl[0];
      if (rv[1] < v0 || (rv[1] == v0 && rgi[1] < i0)) { v0 = rv[1]; i0 = rgi[1]; s0 = rsl[1]; }
      runv[q * 32 + r] = v0;
      runi[q * 32 + r] = i0;
      cv[s0 >> 7][s0 & 127] = FLT_MAX; ci[s0 >> 7][s0 & 127] = 0x7fffffff;
    }
    __syncthreads();
  }
}

// ---------------- l2 to neighbors, softmax post_w, normalized pre_w ----------------
__global__ void __launch_bounds__(64) k_l2soft(const float* __restrict__ T, const float* __restrict__ X,
                                               const int* __restrict__ runi, const int* __restrict__ qidx,
                                               const float* __restrict__ prew, float* __restrict__ postw,
                                               float* __restrict__ prewn) {
  __shared__ float l2s[32];
  int b = blockIdx.x, lane = threadIdx.x;
  int qi = qidx[b];
  float pwv = (lane < 32) ? fmaxf(prew[qi * 32 + lane], 1e-8f) : 0.f;
  float psum = waveSum(pwv);
  if (lane < 32) prewn[b * 32 + lane] = pwv / psum;
  const float* Tb = T + b * 512;
  for (int n = 0; n < 32; ++n) {
    int nb = runi[b * 32 + n];
    const float* Xr = X + nb * 512;
    float acc = 0.f;
#pragma unroll
    for (int d = 0; d < 8; ++d) {
      float df = Tb[lane + 64 * d] - Xr[lane + 64 * d];
      acc += df * df;
    }
    acc = waveSum(acc);
    if (lane == 0) l2s[n] = acc;
  }
  __syncthreads();
  float lg = (lane < 32) ? (-l2s[lane] * 10.0f) : -FLT_MAX;
  float mx = lg;
#pragma unroll
  for (int off = 32; off > 0; off >>= 1) mx = fmaxf(mx, __shfl_xor(mx, off));
  float e = (lane < 32) ? expf(lg - mx) : 0.f;
  float es = waveSum(e);
  float wv = e / es;
  wv = fmaxf(wv, 1e-8f);
  float ws2 = (lane < 32) ? wv : 0.f;
  ws2 = waveSum(ws2);
  if (lane < 32) postw[b * 32 + lane] = wv / ws2;
}

// ---------------- fused per-batch: Gram -> C -> median -> Sinkhorn(200) -> loss ----------------
__global__ void __launch_bounds__(256) k_batch(const float* __restrict__ X, const int* __restrict__ qidx,
                                               const int* __restrict__ pre_idx, const int* __restrict__ runi,
                                               const float* __restrict__ prewn, const float* __restrict__ postw,
                                               float* __restrict__ scal) {
  __shared__ float G[64][65];   // Gram, later reused as Kmat
  __shared__ float Cm[64][65];
  __shared__ float SB[4160];    // staging / sort buffer
  __shared__ int supp[64];
  __shared__ float pv[64], qv[64], uu[64], vv[64];
  __shared__ float rbuf[4][64];
  __shared__ float medsh;
  int b = blockIdx.x, t = threadIdx.x;
  if (t < 32) supp[t] = pre_idx[qidx[b] * 32 + t];
  else if (t < 64) supp[t] = runi[b * 32 + t - 32];
  __syncthreads();
  int tr = t >> 4, tc = t & 15;
  float acc[4][4] = {{0.f}};
  for (int kc = 0; kc < 512; kc += 64) {
    __syncthreads();
#pragma unroll
    for (int p2 = 0; p2 < 16; ++p2) {
      int l = t + 256 * p2;
      int r = l >> 6, c = l & 63;
      SB[r * 65 + c] = X[supp[r] * 512 + kc + c];
    }
    __syncthreads();
#pragma unroll 8
    for (int kk = 0; kk < 64; ++kk) {
      float a[4], bb[4];
#pragma unroll
      for (int u = 0; u < 4; ++u) a[u] = SB[(tr * 4 + u) * 65 + kk];
#pragma unroll
      for (int v = 0; v < 4; ++v) bb[v] = SB[(tc * 4 + v) * 65 + kk];
#pragma unroll
      for (int u = 0; u < 4; ++u)
#pragma unroll
        for (int v = 0; v < 4; ++v) acc[u][v] += a[u] * bb[v];
    }
  }
  __syncthreads();
#pragma unroll
  for (int u = 0; u < 4; ++u)
#pragma unroll
    for (int v = 0; v < 4; ++v) G[tr * 4 + u][tc * 4 + v] = acc[u][v];
  __syncthreads();
  for (int l = t; l < 4096; l += 256) {
    int i = l >> 6, j = l & 63;
    float cc = fmaxf(G[i][i] + G[j][j] - 2.0f * G[i][j], 0.f);
    Cm[i][j] = cc;
    SB[l] = cc;
  }
  // bitonic sort 4096 ascending
  for (int ssz = 2; ssz <= 4096; ssz <<= 1) {
    for (int st = ssz >> 1; st > 0; st >>= 1) {
      __syncthreads();
      for (int l = t; l < 2048; l += 256) {
        int i = 2 * l - (l & (st - 1));
        int j = i + st;
        bool up = ((i & ssz) == 0);
        float a = SB[i], b2 = SB[j];
        if ((a > b2) == up) { SB[i] = b2; SB[j] = a; }
      }
    }
  }
  __syncthreads();
  if (t == 0) medsh = 0.5f * (SB[2047] + SB[2048]) + 1e-8f;
  __syncthreads();
  float inv = 1.0f / medsh;
  for (int l = t; l < 4096; l += 256) {
    int i = l >> 6, j = l & 63;
    float cn = Cm[i][j] * inv;
    Cm[i][j] = cn;
    G[i][j] = expf(-cn * 10.0f);   // K = exp(-C/eps), eps=0.1
  }
  if (t < 64) {
    pv[t] = (t < 32) ? prewn[b * 32 + t] : 0.f;
    qv[t] = (t < 32) ? 0.f : postw[b * 32 + (t - 32)];
    uu[t] = 1.f; vv[t] = 1.f;
  }
  __syncthreads();
  int g = t >> 6, i0 = t & 63;
  for (int it = 0; it < 200; ++it) {
    float s2 = 0.f;
#pragma unroll
    for (int j2 = 0; j2 < 16; ++j2) s2 += G[i0][g * 16 + j2] * vv[g * 16 + j2];
    rbuf[g][i0] = s2;
    __syncthreads();
    if (t < 64) uu[t] = pv[t] / (rbuf[0][t] + rbuf[1][t] + rbuf[2][t] + rbuf[3][t] + 1e-16f);
    __syncthreads();
    s2 = 0.f;
#pragma unroll
    for (int j2 = 0; j2 < 16; ++j2) s2 += G[g * 16 + j2][i0] * uu[g * 16 + j2];
    rbuf[g][i0] = s2;
    __syncthreads();
    if (t < 64) vv[t] = qv[t] / (rbuf[0][t] + rbuf[1][t] + rbuf[2][t] + rbuf[3][t] + 1e-16f);
    __syncthreads();
  }
  float lacc = 0.f;
  for (int l = t; l < 4096; l += 256) {
    int i = l >> 6, j = l & 63;
    lacc += uu[i] * G[i][j] * vv[j] * Cm[i][j];
  }
  lacc = waveSum(lacc);
  if ((t & 63) == 0) rbuf[0][t >> 6] = lacc;
  __syncthreads();
  if (t == 0)
    atomicAdd(&scal[3], (rbuf[0][0] + rbuf[0][1] + rbuf[0][2] + rbuf[0][3]) * (1.0f / 256.0f));
}

// ---------------- sum(W^2) ----------------
__global__ void k_wreg(const float* __restrict__ W, float* __restrict__ scal) {
  __shared__ float red[4];
  int t = threadIdx.x;
  int base = blockIdx.x * 2048;
  float ss = 0.f;
#pragma unroll
  for (int p = 0; p < 8; ++p) {
    float v = W[base + p * 256 + t];
    ss += v * v;
  }
  ss = waveSum(ss);
  if ((t & 63) == 0) red[t >> 6] = ss;
  __syncthreads();
  if (t == 0) atomicAdd(&scal[4], red[0] + red[1] + red[2] + red[3]);
}

// ---------------- final combine ----------------
__global__ void k_combine(const float* __restrict__ mu_t, const float* __restrict__ colsum,
                          const float* __restrict__ scal, float* __restrict__ out) {
  __shared__ float red[8];
  int t = threadIdx.x;  // 512
  float dm = mu_t[t] - colsum[t] * (1.0f / 50000.0f);
  float v = dm * dm;
  v = waveSum(v);
  if ((t & 63) == 0) red[t >> 6] = v;
  __syncthreads();
  if (t == 0) {
    float term_mean = 0.f;
    for (int i = 0; i < 8; ++i) term_mean += red[i];
    float trCT = scal[0] * (1.0f / 255.0f);
    float trCX = scal[1];
    float S = scal[2];
    float term_cov = trCX * 1.001f + trCT * 1.001f - 2.0f * S;
    term_cov = fmaxf(term_cov, 0.f);
    float loss_dist = term_mean + term_cov;
    float loss_knn = scal[3];
    float loss_reg = 0.5f * scal[4];
    out[0] = loss_dist + loss_knn + 1e-4f * loss_reg;
    out[1] = loss_dist;
    out[2] = loss_knn;
  }
}

extern "C" void kernel_launch(void* const* d_in, const int* in_sizes, int n_in,
                              void* d_out, int out_size, void* d_ws, size_t ws_size,
                              hipStream_t stream) {
  const float* q = (const float*)d_in[0];
  const int* qidx = (const int*)d_in[1];
  const float* W = (const float*)d_in[2];
  const float* X = (const float*)d_in[3];
  const int* pre_idx = (const int*)d_in[4];
  const float* prew = (const float*)d_in[5];
  float* out = (float*)d_out;
  float* ws = (float*)d_ws;

  float* G = ws + OFF_G;
  float* scal = ws + OFF_SC;
  float* colsum = ws + OFF_CS;
  float* colss = ws + OFF_CSS;
  float* T = ws + OFF_T;
  float* Tc = ws + OFF_TC;
  float* P = ws + OFF_P;
  float* H = ws + OFF_H;
  float* rows = ws + OFF_DDI;
  float* mu_t = ws + OFF_MUT;
  float* xsq = ws + OFF_XSQ;
  float* runv = ws + OFF_RUNV;
  int* runi = (int*)(ws + OFF_RUNI);
  float* postw = ws + OFF_PW;
  float* prewn = ws + OFF_PRW;
  float* d2c = ws + OFF_D2;

  hipMemsetAsync(d_ws, 0, (size_t)ZERO_F * 4, stream);

  // T = q @ W  [256x512 = 256x512 @ 512x512]
  k_g64_nn<<<dim3(8, 4), 256, 0, stream>>>(q, W, T, 512, 512, 512, 512, 1.0f);
  // X column stats, per-row sq norms, X^T X (upper block-triangle)
  k_colstatX<<<256, 256, 0, stream>>>(X, colsum, colss);
  k_xsq<<<12500, 256, 0, stream>>>(X, xsq);
  k_xtx<<<dim3(10, 50), 256, 0, stream>>>(X, G);
  // T stats
  k_colmeanT<<<1, 512, 0, stream>>>(T, mu_t);
  k_centerT<<<128, 256, 0, stream>>>(T, mu_t, Tc, scal);
  // SigmaX
  k_trCX<<<1, 512, 0, stream>>>(colsum, colss, scal);
  k_finSX<<<dim3(32, 32), dim3(16, 16), 0, stream>>>(G, colsum, scal);
  // H = Tc SigmaX Tc^T / 255
  k_g64_nn<<<dim3(8, 4), 256, 0, stream>>>(Tc, G, P, 512, 512, 512, 512, 1.0f);
  k_g64_nt<<<dim3(4, 4), 256, 0, stream>>>(P, Tc, H, 512, 512, 512, 256, 1.0f / 255.0f);
  // spectral sum via coupled Newton-Schulz sqrt of H' = H + rt*I
  {
    float* Y = ws + OFF_TC;
    float* Z = ws + OFF_TC + 65536;
    float* Y2 = ws + OFF_P;
    float* Z2 = ws + OFF_P + 65536;
    float* Pm = ws + OFF_G;
    k_rowsum<<<256, 64, 0, stream>>>(H, scal, rows);
    k_nsmax<<<1, 256, 0, stream>>>(rows, scal);
    k_nsinit<<<256, 256, 0, stream>>>(H, scal, Y, Z);
    for (int it = 0; it < NS_ITERS; ++it) {
      k_g64_nn<<<dim3(4, 4), 256, 0, stream>>>(Z, Y, Pm, 256, 256, 256, 256, 1.0f);
      k_ns_upd<<<dim3(4, 4, 2), 256, 0, stream>>>(Y, Z, Pm, Y2, Z2);
      float* tmp = Y; Y = Y2; Y2 = tmp;
      tmp = Z; Z = Z2; Z2 = tmp;
    }
    k_ns_trace<<<1, 256, 0, stream>>>(Y, scal);
  }
  // kNN: full-width single pass if workspace allows, else 4 chunks
  size_t needF = (size_t)OFF_D2 + (size_t)256 * 50000 + 64;
  if (ws_size >= needF * 4) {
    // G region is dead after NS -> reuse as candidate buffer (256*128 vals + 256*128 idx)
    float* candv = ws + OFF_G;
    int* candi = (int*)(ws + OFF_G + 32768);
    k_d2<<<dim3(2, 391), 256, 0, stream>>>(T, X, xsq, d2c, 0, 50000);
    k_topk_part<<<dim3(4, 256), 128, 0, stream>>>(d2c, candv, candi);
    k_topk_final<<<256, 128, 0, stream>>>(candv, candi, runi);
  } else {
    k_topk_init<<<32, 256, 0, stream>>>(runv, runi);
    for (int c = 0; c < 4; ++c) {
      k_d2<<<dim3(2, 98), 256, 0, stream>>>(T, X, xsq, d2c, c * CHUNK, CHUNK);
      k_topk_merge<<<256, 128, 0, stream>>>(d2c, runv, runi, c * CHUNK, CHUNK);
    }
  }
  k_l2soft<<<256, 64, 0, stream>>>(T, X, runi, qidx, prew, postw, prewn);
  k_batch<<<256, 256, 0, stream>>>(X, qidx, pre_idx, runi, prewn, postw, scal);
  k_wreg<<<128, 256, 0, stream>>>(W, scal);
  k_combine<<<1, 512, 0, stream>>>(mu_t, colsum, scal, out);
}

// Round 5
// 1596.577 us; speedup vs baseline: 3.4992x; 1.3613x over previous
//
#include <hip/hip_runtime.h>
#include <float.h>
#include <math.h>

// Problem constants
#define BB 256
#define DD 512
#define NN 50000
#define KK 32
#define CHUNK 12500
#define NS_ITERS 11

// Workspace layout (float offsets)
#define OFF_G     0         // 1M-float region: UUT(65536) + TcTc(65536) + w(256) + m(50000); NS Pm reuses +0
#define OFF_SC    262144    // 64 scalars: 0=sumTc2 1=trCX 2=S_total 3=knn 4=wreg 5=s_ns
#define OFF_CS    262208    // 512 colsum X
#define OFF_CSS   262720    // 512 colsumsq X
#define ZERO_F    263232    // floats to memset
#define OFF_T     263232    // 256*512
#define OFF_TC    394304    // 256*512 Tc; later NS Y/Z
#define OFF_P     525376    // 256*512: top-k cand buffers; later NS Y2/Z2
#define OFF_H     656448    // 256*256
#define OFF_MUT   722496    // 512
#define OFF_XSQ   723008    // 50000
#define OFF_RUNI  781200    // 256*32 (int)
#define OFF_PW    789392    // 256*32 post_w
#define OFF_PRW   797584    // 256*32 pre_w normalized
#define OFF_D2    805776    // V = T@X^T  (256*50000)

#define OFF_UUT   (OFF_G)
#define OFF_TCTC  (OFF_G + 65536)
#define OFF_W     (OFF_G + 131072)
#define OFF_M     (OFF_G + 131328)

typedef __attribute__((ext_vector_type(8))) short bf16x8;
typedef __attribute__((ext_vector_type(4))) float f32x4;

__device__ __forceinline__ float waveSum(float v) {
#pragma unroll
  for (int off = 32; off > 0; off >>= 1) v += __shfl_xor(v, off);
  return v;
}

// split fp32x4 -> bf16 hi/lo, write packed pairs to LDS at short-offset sa (16B-aligned rows)
__device__ __forceinline__ void cvt_write(float4 v, unsigned short* hi, unsigned short* lo, int sa) {
  unsigned int b0 = __float_as_uint(v.x), b1 = __float_as_uint(v.y);
  unsigned int b2 = __float_as_uint(v.z), b3 = __float_as_uint(v.w);
  unsigned int h0 = b0 & 0xffff0000u, h1 = b1 & 0xffff0000u;
  unsigned int h2 = b2 & 0xffff0000u, h3 = b3 & 0xffff0000u;
  float l0 = v.x - __uint_as_float(h0), l1 = v.y - __uint_as_float(h1);
  float l2 = v.z - __uint_as_float(h2), l3 = v.w - __uint_as_float(h3);
  *(unsigned int*)&hi[sa]     = (h0 >> 16) | h1;
  *(unsigned int*)&hi[sa + 2] = (h2 >> 16) | h3;
  *(unsigned int*)&lo[sa]     = (__float_as_uint(l0) >> 16) | (__float_as_uint(l1) & 0xffff0000u);
  *(unsigned int*)&lo[sa + 2] = (__float_as_uint(l2) >> 16) | (__float_as_uint(l3) & 0xffff0000u);
}

// ---------------- generic 64x64-tile GEMM, C = scale * A @ B (nn) ----------------
__global__ void __launch_bounds__(256) k_g64_nn(const float* __restrict__ A,
                                                const float* __restrict__ B,
                                                float* __restrict__ C,
                                                int K, int lda, int ldb, int ldc, float scale) {
  __shared__ float As[64][65], Bs[64][65];
  int m0 = blockIdx.y * 64, n0 = blockIdx.x * 64;
  int t = threadIdx.x, tr = t >> 4, tc = t & 15;
  float acc[4][4] = {{0.f}};
  for (int k0 = 0; k0 < K; k0 += 64) {
#pragma unroll
    for (int p = 0; p < 16; ++p) {
      int l = t + 256 * p;
      int r = l >> 6, c = l & 63;
      As[r][c] = A[(m0 + r) * lda + k0 + c];
      Bs[r][c] = B[(k0 + r) * ldb + n0 + c];
    }
    __syncthreads();
#pragma unroll 16
    for (int kk = 0; kk < 64; ++kk) {
      float a[4], b[4];
#pragma unroll
      for (int u = 0; u < 4; ++u) a[u] = As[tr + 16 * u][kk];
#pragma unroll
      for (int v = 0; v < 4; ++v) b[v] = Bs[kk][tc + 16 * v];
#pragma unroll
      for (int u = 0; u < 4; ++u)
#pragma unroll
        for (int v = 0; v < 4; ++v) acc[u][v] += a[u] * b[v];
    }
    __syncthreads();
  }
#pragma unroll
  for (int u = 0; u < 4; ++u)
#pragma unroll
    for (int v = 0; v < 4; ++v)
      C[(m0 + tr + 16 * u) * ldc + n0 + tc + 16 * v] = acc[u][v] * scale;
}

// ---------------- generic 64x64-tile GEMM, C = scale * A @ B^T (nt) ----------------
__global__ void __launch_bounds__(256) k_g64_nt(const float* __restrict__ A,
                                                const float* __restrict__ B,
                                                float* __restrict__ C,
                                                int K, int lda, int ldb, int ldc, float scale) {
  __shared__ float As[64][65], Bs[64][65];
  int m0 = blockIdx.y * 64, n0 = blockIdx.x * 64;
  int t = threadIdx.x, tr = t >> 4, tc = t & 15;
  float acc[4][4] = {{0.f}};
  for (int k0 = 0; k0 < K; k0 += 64) {
#pragma unroll
    for (int p = 0; p < 16; ++p) {
      int l = t + 256 * p;
      int r = l >> 6, c = l & 63;
      As[r][c] = A[(m0 + r) * lda + k0 + c];
      Bs[r][c] = B[(n0 + r) * ldb + k0 + c];
    }
    __syncthreads();
#pragma unroll 16
    for (int kk = 0; kk < 64; ++kk) {
      float a[4], b[4];
#pragma unroll
      for (int u = 0; u < 4; ++u) a[u] = As[tr + 16 * u][kk];
#pragma unroll
      for (int v = 0; v < 4; ++v) b[v] = Bs[tc + 16 * v][kk];
#pragma unroll
      for (int u = 0; u < 4; ++u)
#pragma unroll
        for (int v = 0; v < 4; ++v) acc[u][v] += a[u] * b[v];
    }
    __syncthreads();
  }
#pragma unroll
  for (int u = 0; u < 4; ++u)
#pragma unroll
    for (int v = 0; v < 4; ++v)
      C[(m0 + tr + 16 * u) * ldc + n0 + tc + 16 * v] = acc[u][v] * scale;
}

// ---------------- V = T @ X^T  (MFMA bf16-split, on-the-fly conversion) ----------------
__global__ void __launch_bounds__(256) k_vgemm(const float* __restrict__ T,
                                               const float* __restrict__ X,
                                               float* __restrict__ V) {
  __shared__ unsigned short Ah[128 * 72], Al[128 * 72], Bh[128 * 72], Bl[128 * 72];
  int bj = blockIdx.x, bi = blockIdx.y;
  int t = threadIdx.x;
  int wave = t >> 6, lane = t & 63;
  int m0 = (wave >> 1) * 64, n0 = (wave & 1) * 64;
  int lrow = lane & 15, lq = lane >> 4;
  f32x4 acc[4][4] = {};
  for (int kc = 0; kc < 512; kc += 64) {
#pragma unroll
    for (int f = 0; f < 8; ++f) {
      int lin = f * 256 + t;
      int r = lin >> 4, c4 = lin & 15;
      int sa = r * 72 + c4 * 4;
      float4 va = *(const float4*)&T[(bi * 128 + r) * 512 + kc + c4 * 4];
      cvt_write(va, Ah, Al, sa);
      int jg = bj * 128 + r;
      float4 vb = {0.f, 0.f, 0.f, 0.f};
      if (jg < NN) vb = *(const float4*)&X[(size_t)jg * 512 + kc + c4 * 4];
      cvt_write(vb, Bh, Bl, sa);
    }
    __syncthreads();
#pragma unroll
    for (int ks = 0; ks < 2; ++ks) {
      int kb = ks * 32 + lq * 8;
      bf16x8 ah[4], al[4], bh[4], bl[4];
#pragma unroll
      for (int mi = 0; mi < 4; ++mi) {
        int ro = (m0 + mi * 16 + lrow) * 72 + kb;
        ah[mi] = *(const bf16x8*)&Ah[ro];
        al[mi] = *(const bf16x8*)&Al[ro];
      }
#pragma unroll
      for (int nj = 0; nj < 4; ++nj) {
        int ro = (n0 + nj * 16 + lrow) * 72 + kb;
        bh[nj] = *(const bf16x8*)&Bh[ro];
        bl[nj] = *(const bf16x8*)&Bl[ro];
      }
#pragma unroll
      for (int mi = 0; mi < 4; ++mi)
#pragma unroll
        for (int nj = 0; nj < 4; ++nj) {
          acc[mi][nj] = __builtin_amdgcn_mfma_f32_16x16x32_bf16(ah[mi], bh[nj], acc[mi][nj], 0, 0, 0);
          acc[mi][nj] = __builtin_amdgcn_mfma_f32_16x16x32_bf16(ah[mi], bl[nj], acc[mi][nj], 0, 0, 0);
          acc[mi][nj] = __builtin_amdgcn_mfma_f32_16x16x32_bf16(al[mi], bh[nj], acc[mi][nj], 0, 0, 0);
        }
    }
    __syncthreads();
  }
#pragma unroll
  for (int mi = 0; mi < 4; ++mi)
#pragma unroll
    for (int nj = 0; nj < 4; ++nj)
#pragma unroll
      for (int r = 0; r < 4; ++r) {
        int row = bi * 128 + m0 + mi * 16 + lq * 4 + r;
        int col = bj * 128 + n0 + nj * 16 + lrow;
        if (col < NN) V[(size_t)row * NN + col] = acc[mi][nj][r];
      }
}

// ---------------- UUT += U @ U^T, U = V - m (MFMA bf16-split, split-K atomic) ----------------
__global__ void __launch_bounds__(256) k_uut(const float* __restrict__ V,
                                             const float* __restrict__ m,
                                             float* __restrict__ UUT) {
  __shared__ unsigned short Ah[128 * 72], Al[128 * 72], Bh[128 * 72], Bl[128 * 72];
  const int pi_[3] = {0, 0, 1}, pj_[3] = {0, 1, 1};
  int bi = pi_[blockIdx.x], bj = pj_[blockIdx.x];
  int j0 = blockIdx.y * 1000, jlim = j0 + 1000;
  int t = threadIdx.x;
  int wave = t >> 6, lane = t & 63;
  int m0 = (wave >> 1) * 64, n0 = (wave & 1) * 64;
  int lrow = lane & 15, lq = lane >> 4;
  f32x4 acc[4][4] = {};
  for (int ch = 0; ch < 16; ++ch) {
    int jc = j0 + ch * 64;
#pragma unroll
    for (int f = 0; f < 8; ++f) {
      int lin = f * 256 + t;
      int r = lin >> 4, c4 = lin & 15;
      int sa = r * 72 + c4 * 4;
      int jb = jc + c4 * 4;
      float4 va = {0.f, 0.f, 0.f, 0.f}, vb = {0.f, 0.f, 0.f, 0.f};
      if (jb < jlim) {
        float4 mm = *(const float4*)&m[jb];
        va = *(const float4*)&V[(size_t)(bi * 128 + r) * NN + jb];
        vb = *(const float4*)&V[(size_t)(bj * 128 + r) * NN + jb];
        va.x -= mm.x; va.y -= mm.y; va.z -= mm.z; va.w -= mm.w;
        vb.x -= mm.x; vb.y -= mm.y; vb.z -= mm.z; vb.w -= mm.w;
      }
      cvt_write(va, Ah, Al, sa);
      cvt_write(vb, Bh, Bl, sa);
    }
    __syncthreads();
#pragma unroll
    for (int ks = 0; ks < 2; ++ks) {
      int kb = ks * 32 + lq * 8;
      bf16x8 ah[4], al[4], bh[4], bl[4];
#pragma unroll
      for (int mi = 0; mi < 4; ++mi) {
        int ro = (m0 + mi * 16 + lrow) * 72 + kb;
        ah[mi] = *(const bf16x8*)&Ah[ro];
        al[mi] = *(const bf16x8*)&Al[ro];
      }
#pragma unroll
      for (int nj = 0; nj < 4; ++nj) {
        int ro = (n0 + nj * 16 + lrow) * 72 + kb;
        bh[nj] = *(const bf16x8*)&Bh[ro];
        bl[nj] = *(const bf16x8*)&Bl[ro];
      }
#pragma unroll
      for (int mi = 0; mi < 4; ++mi)
#pragma unroll
        for (int nj = 0; nj < 4; ++nj) {
          acc[mi][nj] = __builtin_amdgcn_mfma_f32_16x16x32_bf16(ah[mi], bh[nj], acc[mi][nj], 0, 0, 0);
          acc[mi][nj] = __builtin_amdgcn_mfma_f32_16x16x32_bf16(ah[mi], bl[nj], acc[mi][nj], 0, 0, 0);
          acc[mi][nj] = __builtin_amdgcn_mfma_f32_16x16x32_bf16(al[mi], bh[nj], acc[mi][nj], 0, 0, 0);
        }
    }
    __syncthreads();
  }
#pragma unroll
  for (int mi = 0; mi < 4; ++mi)
#pragma unroll
    for (int nj = 0; nj < 4; ++nj)
#pragma unroll
      for (int r = 0; r < 4; ++r) {
        int row = bi * 128 + m0 + mi * 16 + lq * 4 + r;
        int col = bj * 128 + n0 + nj * 16 + lrow;
        atomicAdd(&UUT[row * 256 + col], acc[mi][nj][r]);
      }
}

// ---------------- column sums & sumsq of X (atomic) ----------------
__global__ void k_colstatX(const float* __restrict__ X, float* __restrict__ colsum,
                           float* __restrict__ colss) {
  int b = blockIdx.x, t = threadIdx.x;
  int r0 = b * 196;
  int r1 = r0 + 196; if (r1 > NN) r1 = NN;
  float s1 = 0, ss1 = 0, s2 = 0, ss2 = 0;
  for (int r = r0; r < r1; ++r) {
    float v1 = X[(size_t)r * 512 + t], v2 = X[(size_t)r * 512 + t + 256];
    s1 += v1; ss1 += v1 * v1; s2 += v2; ss2 += v2 * v2;
  }
  atomicAdd(&colsum[t], s1);       atomicAdd(&colss[t], ss1);
  atomicAdd(&colsum[t + 256], s2); atomicAdd(&colss[t + 256], ss2);
}

// ---------------- per-row squared norm of X ----------------
__global__ void k_xsq(const float* __restrict__ X, float* __restrict__ xsq) {
  int row = blockIdx.x * 4 + (threadIdx.x >> 6);
  int lane = threadIdx.x & 63;
  const float* Xr = X + (size_t)row * 512;
  float s = 0.f;
#pragma unroll
  for (int d = 0; d < 8; ++d) { float v = Xr[lane + 64 * d]; s += v * v; }
  s = waveSum(s);
  if (lane == 0) xsq[row] = s;
}

// ---------------- column means of T ----------------
__global__ void k_colmeanT(const float* __restrict__ T, float* __restrict__ mu) {
  int c = threadIdx.x;
  float s = 0.f;
  for (int r = 0; r < 256; ++r) s += T[r * 512 + c];
  mu[c] = s * (1.0f / 256.0f);
}

// ---------------- Tc = T - mu, accumulate sum(Tc^2) ----------------
__global__ void k_centerT(const float* __restrict__ T, const float* __restrict__ mu,
                          float* __restrict__ Tc, float* __restrict__ scal) {
  __shared__ float red[4];
  int t = threadIdx.x;
  int base = blockIdx.x * 1024;
  float ss = 0.f;
#pragma unroll
  for (int p = 0; p < 4; ++p) {
    int l = base + p * 256 + t;
    float v = T[l] - mu[l & 511];
    Tc[l] = v;
    ss += v * v;
  }
  ss = waveSum(ss);
  if ((t & 63) == 0) red[t >> 6] = ss;
  __syncthreads();
  if (t == 0) atomicAdd(&scal[0], red[0] + red[1] + red[2] + red[3]);
}

// ---------------- trace of cov(X) ----------------
__global__ void k_trCX(const float* __restrict__ colsum, const float* __restrict__ colss,
                       float* __restrict__ scal) {
  __shared__ float red[8];
  int t = threadIdx.x;  // 512
  float mu = colsum[t] * (1.0f / 50000.0f);
  float v = (colss[t] - 50000.0f * mu * mu) * (1.0f / 49999.0f);
  v = waveSum(v);
  if ((t & 63) == 0) red[t >> 6] = v;
  __syncthreads();
  if (t == 0) {
    float s = 0;
    for (int i = 0; i < 8; ++i) s += red[i];
    scal[1] = s;
  }
}

// ---------------- colmeans of V -> m ----------------
__global__ void k_vstats(const float* __restrict__ V, float* __restrict__ m) {
  int j = blockIdx.x * 256 + threadIdx.x;
  if (j >= NN) return;
  float s = 0.f;
  for (int i = 0; i < 256; ++i) s += V[(size_t)i * NN + j];
  m[j] = s * (1.0f / 256.0f);
}

// ---------------- w_i = Tc_i . muX  (= a_i - mean(a), a_i = T_i . muX) ----------------
__global__ void __launch_bounds__(256) k_wvec(const float* __restrict__ T,
                                              const float* __restrict__ colsum,
                                              float* __restrict__ w) {
  __shared__ float cs[512];
  __shared__ float red[4];
  int t = threadIdx.x;
  cs[t] = colsum[t] * (1.0f / 50000.0f);
  cs[t + 256] = colsum[t + 256] * (1.0f / 50000.0f);
  __syncthreads();
  float a = 0.f;
  for (int c = 0; c < 512; ++c) a += T[t * 512 + c] * cs[c];
  float s = waveSum(a);
  if ((t & 63) == 0) red[t >> 6] = s;
  __syncthreads();
  float mean = (red[0] + red[1] + red[2] + red[3]) * (1.0f / 256.0f);
  w[t] = a - mean;
}

// ---------------- H = (UUT - N w w^T)/(49999*255) + rhoX * TcTc/255 ----------------
__global__ void k_hfix(const float* __restrict__ UUT, const float* __restrict__ TcTc,
                       const float* __restrict__ w, const float* __restrict__ scal,
                       float* __restrict__ H) {
  int l = blockIdx.x * 256 + threadIdx.x;
  int i = l >> 8, j = l & 255;
  float u = (i >= 128 && j < 128) ? UUT[j * 256 + i] : UUT[i * 256 + j];
  float rho = scal[1] * (1e-3f / 512.0f);
  H[l] = (u - 50000.0f * w[i] * w[j]) * (1.0f / (49999.0f * 255.0f))
       + rho * TcTc[i * 256 + j] * (1.0f / 255.0f);
}

// ---------------- power iteration: scal[5] = safe lambda_max bound of H' ----------------
__global__ void __launch_bounds__(256) k_power(const float* __restrict__ H,
                                               float* __restrict__ scal) {
  __shared__ float v[256], nv[256], red[4];
  int t = threadIdx.x;
  float rt = scal[0] * (1.0f / 255.0f) * (1e-3f / 512.0f);
  v[t] = 1.0f;
  __syncthreads();
  float n2 = 256.0f, n3 = 256.0f;
  for (int it = 0; it < 3; ++it) {
    float s = rt * v[t];
    for (int j = 0; j < 256; ++j) s += H[t * 256 + j] * v[j];
    nv[t] = s;
    float ss = waveSum(s * s);
    if ((t & 63) == 0) red[t >> 6] = ss;
    __syncthreads();
    float norm2 = red[0] + red[1] + red[2] + red[3];
    if (it == 1) n2 = norm2;
    if (it == 2) n3 = norm2;
    v[t] = nv[t];
    __syncthreads();
  }
  float d = H[t * 256 + t] + rt;
#pragma unroll
  for (int off = 32; off > 0; off >>= 1) d = fmaxf(d, __shfl_xor(d, off));
  if ((t & 63) == 0) red[t >> 6] = d;
  __syncthreads();
  if (t == 0) {
    float lam = sqrtf(n3 / n2);
    float md = fmaxf(fmaxf(red[0], red[1]), fmaxf(red[2], red[3]));
    scal[5] = fmaxf(1.3f * lam, md);
  }
}

// ---------------- Y0 = (H + rt I)/s, Z0 = I ----------------
__global__ void k_nsinit(const float* __restrict__ H, const float* __restrict__ scal,
                         float* __restrict__ Y, float* __restrict__ Z) {
  int l = blockIdx.x * 256 + threadIdx.x;
  int i = l >> 8, j = l & 255;
  float rt = scal[0] * (1.0f / 255.0f) * (1e-3f / 512.0f);
  float inv = 1.0f / scal[5];
  Y[l] = (H[l] + ((i == j) ? rt : 0.f)) * inv;
  Z[l] = (i == j) ? 1.0f : 0.f;
}

// ---------------- NS update: z=0 Yn=1.5Y-0.5*Y@P ; z=1 Zn=1.5Z-0.5*P@Z ----------------
__global__ void __launch_bounds__(256) k_ns_upd(const float* __restrict__ Y, const float* __restrict__ Z,
                                                const float* __restrict__ P,
                                                float* __restrict__ Yn, float* __restrict__ Zn) {
  __shared__ float As[64][65], Bs[64][65];
  int bi = blockIdx.x, bj = blockIdx.y, zz = blockIdx.z;
  const float* A = zz ? P : Y;
  const float* B = zz ? Z : P;
  const float* D = zz ? Z : Y;
  float* O = zz ? Zn : Yn;
  int t = threadIdx.x;
  int tr = t >> 4, tc = t & 15;
  float acc[4][4] = {{0.f}};
  for (int k0 = 0; k0 < 256; k0 += 64) {
#pragma unroll
    for (int p = 0; p < 16; ++p) {
      int l = t + 256 * p;
      int r = l >> 6, c = l & 63;
      As[r][c] = A[(bi * 64 + r) * 256 + k0 + c];
      Bs[r][c] = B[(k0 + r) * 256 + bj * 64 + c];
    }
    __syncthreads();
#pragma unroll 16
    for (int kk = 0; kk < 64; ++kk) {
      float a[4], b[4];
#pragma unroll
      for (int u = 0; u < 4; ++u) a[u] = As[tr + 16 * u][kk];
#pragma unroll
      for (int v = 0; v < 4; ++v) b[v] = Bs[kk][tc + 16 * v];
#pragma unroll
      for (int u = 0; u < 4; ++u)
#pragma unroll
        for (int v = 0; v < 4; ++v) acc[u][v] += a[u] * b[v];
    }
    __syncthreads();
  }
#pragma unroll
  for (int u = 0; u < 4; ++u)
#pragma unroll
    for (int v = 0; v < 4; ++v) {
      int idx = (bi * 64 + tr + 16 * u) * 256 + bj * 64 + tc + 16 * v;
      O[idx] = 1.5f * D[idx] - 0.5f * acc[u][v];
    }
}

// ---------------- S_total = sqrt(s)*tr(Y) + 256*sqrt(rt) ----------------
__global__ void k_ns_trace(const float* __restrict__ Y, float* __restrict__ scal) {
  __shared__ float red[4];
  int t = threadIdx.x;  // 256
  float v = Y[t * 256 + t];
  v = waveSum(v);
  if ((t & 63) == 0) red[t >> 6] = v;
  __syncthreads();
  if (t == 0) {
    float tr = red[0] + red[1] + red[2] + red[3];
    float rt = scal[0] * (1.0f / 255.0f) * (1e-3f / 512.0f);
    scal[2] = sqrtf(scal[5]) * tr + 256.0f * sqrtf(rt);
  }
}

// ---------------- stage 1: per-(query, quarter) exact top-32 from d2 = xsq - 2V ----------------
__global__ void __launch_bounds__(128) k_topk_part(const float* __restrict__ V,
                                                   const float* __restrict__ xsq,
                                                   float* __restrict__ candv,
                                                   int* __restrict__ candi) {
  __shared__ float cv[32][128];
  __shared__ int ci[32][128];
  __shared__ float rv[2];
  __shared__ int rgi[2], rsl[2];
  int part = blockIdx.x, q = blockIdx.y, t = threadIdx.x;
  int base = part * CHUNK;
  int cnt = 0;
  float wval = -FLT_MAX; int widx = 0, wpos = 0;
  auto recompute = [&]() {
    wval = cv[0][t]; widx = ci[0][t]; wpos = 0;
    for (int s = 1; s < 32; ++s) {
      float a = cv[s][t]; int b2 = ci[s][t];
      if (a > wval || (a == wval && b2 > widx)) { wval = a; widx = b2; wpos = s; }
    }
  };
  auto push = [&](float val, int idx) {
    if (cnt < 32) {
      cv[cnt][t] = val; ci[cnt][t] = idx;
      if (++cnt == 32) recompute();
    } else if (val < wval || (val == wval && idx < widx)) {
      cv[wpos][t] = val; ci[wpos][t] = idx;
      recompute();
    }
  };
  const float* row = V + (size_t)q * NN + base;
  const float* xs = xsq + base;
  for (int j = t; j < CHUNK; j += 128) push(xs[j] - 2.0f * row[j], base + j);
  for (int s = cnt; s < 32; ++s) { cv[s][t] = FLT_MAX; ci[s][t] = 0x7fffffff; }
  __syncthreads();
  for (int r = 0; r < 32; ++r) {
    float bv = FLT_MAX; int bi2 = 0x7fffffff, bs = t;
    for (int s = 0; s < 32; ++s) {
      float a = cv[s][t]; int b2 = ci[s][t];
      if (a < bv || (a == bv && b2 < bi2)) { bv = a; bi2 = b2; bs = s * 128 + t; }
    }
#pragma unroll
    for (int off = 32; off > 0; off >>= 1) {
      float ov = __shfl_down(bv, off);
      int oi = __shfl_down(bi2, off);
      int os = __shfl_down(bs, off);
      if (ov < bv || (ov == bv && oi < bi2)) { bv = ov; bi2 = oi; bs = os; }
    }
    int w = t >> 6;
    if ((t & 63) == 0) { rv[w] = bv; rgi[w] = bi2; rsl[w] = bs; }
    __syncthreads();
    if (t == 0) {
      float v0 = rv[0]; int i0 = rgi[0], s0 = rsl[0];
      if (rv[1] < v0 || (rv[1] == v0 && rgi[1] < i0)) { v0 = rv[1]; i0 = rgi[1]; s0 = rsl[1]; }
      candv[q * 128 + part * 32 + r] = v0;
      candi[q * 128 + part * 32 + r] = i0;
      cv[s0 >> 7][s0 & 127] = FLT_MAX; ci[s0 >> 7][s0 & 127] = 0x7fffffff;
    }
    __syncthreads();
  }
}

// ---------------- stage 2: bitonic-sort 128 candidates, emit top-32 indices ----------------
__global__ void __launch_bounds__(128) k_topk_final(const float* __restrict__ candv,
                                                    const int* __restrict__ candi,
                                                    int* __restrict__ runi) {
  __shared__ float v[128];
  __shared__ int ix[128];
  int q = blockIdx.x, t = threadIdx.x;
  v[t] = candv[q * 128 + t];
  ix[t] = candi[q * 128 + t];
  __syncthreads();
  for (int ssz = 2; ssz <= 128; ssz <<= 1) {
    for (int st = ssz >> 1; st > 0; st >>= 1) {
      if (t < 64) {
        int i = 2 * t - (t & (st - 1));
        int j = i + st;
        bool up = ((i & ssz) == 0);
        float a = v[i], b = v[j];
        int ai = ix[i], bi = ix[j];
        bool agtb = (a > b) || (a == b && ai > bi);
        if (agtb == up) { v[i] = b; v[j] = a; ix[i] = bi; ix[j] = ai; }
      }
      __syncthreads();
    }
  }
  if (t < 32) runi[q * 32 + t] = ix[t];
}

// ---------------- l2 to neighbors, softmax post_w, normalized pre_w ----------------
__global__ void __launch_bounds__(64) k_l2soft(const float* __restrict__ T, const float* __restrict__ X,
                                               const int* __restrict__ runi, const int* __restrict__ qidx,
                                               const float* __restrict__ prew, float* __restrict__ postw,
                                               float* __restrict__ prewn) {
  __shared__ float l2s[32];
  int b = blockIdx.x, lane = threadIdx.x;
  int qi = qidx[b];
  float pwv = (lane < 32) ? fmaxf(prew[qi * 32 + lane], 1e-8f) : 0.f;
  float psum = waveSum(pwv);
  if (lane < 32) prewn[b * 32 + lane] = pwv / psum;
  const float* Tb = T + b * 512;
  for (int n = 0; n < 32; ++n) {
    int nb = runi[b * 32 + n];
    const float* Xr = X + (size_t)nb * 512;
    float acc = 0.f;
#pragma unroll
    for (int d = 0; d < 8; ++d) {
      float df = Tb[lane + 64 * d] - Xr[lane + 64 * d];
      acc += df * df;
    }
    acc = waveSum(acc);
    if (lane == 0) l2s[n] = acc;
  }
  __syncthreads();
  float lg = (lane < 32) ? (-l2s[lane] * 10.0f) : -FLT_MAX;
  float mx = lg;
#pragma unroll
  for (int off = 32; off > 0; off >>= 1) mx = fmaxf(mx, __shfl_xor(mx, off));
  float e = (lane < 32) ? expf(lg - mx) : 0.f;
  float es = waveSum(e);
  float wv = e / es;
  wv = fmaxf(wv, 1e-8f);
  float ws2 = (lane < 32) ? wv : 0.f;
  ws2 = waveSum(ws2);
  if (lane < 32) postw[b * 32 + lane] = wv / ws2;
}

// ---------------- fused per-batch: Gram -> C -> median -> Sinkhorn(200) -> loss ----------------
__global__ void __launch_bounds__(256) k_batch(const float* __restrict__ X, const int* __restrict__ qidx,
                                               const int* __restrict__ pre_idx, const int* __restrict__ runi,
                                               const float* __restrict__ prewn, const float* __restrict__ postw,
                                               float* __restrict__ scal) {
  __shared__ float G[64][65];
  __shared__ float Cm[64][65];
  __shared__ float SB[4160];
  __shared__ int supp[64];
  __shared__ float pv[64], qv[64], uu[64], vv[64];
  __shared__ float rbuf[4][64];
  __shared__ float medsh;
  int b = blockIdx.x, t = threadIdx.x;
  if (t < 32) supp[t] = pre_idx[qidx[b] * 32 + t];
  else if (t < 64) supp[t] = runi[b * 32 + t - 32];
  __syncthreads();
  int tr = t >> 4, tc = t & 15;
  float acc[4][4] = {{0.f}};
  for (int kc = 0; kc < 512; kc += 64) {
    __syncthreads();
#pragma unroll
    for (int p2 = 0; p2 < 16; ++p2) {
      int l = t + 256 * p2;
      int r = l >> 6, c = l & 63;
      SB[r * 65 + c] = X[(size_t)supp[r] * 512 + kc + c];
    }
    __syncthreads();
#pragma unroll 8
    for (int kk = 0; kk < 64; ++kk) {
      float a[4], bb[4];
#pragma unroll
      for (int u = 0; u < 4; ++u) a[u] = SB[(tr * 4 + u) * 65 + kk];
#pragma unroll
      for (int v = 0; v < 4; ++v) bb[v] = SB[(tc * 4 + v) * 65 + kk];
#pragma unroll
      for (int u = 0; u < 4; ++u)
#pragma unroll
        for (int v = 0; v < 4; ++v) acc[u][v] += a[u] * bb[v];
    }
  }
  __syncthreads();
#pragma unroll
  for (int u = 0; u < 4; ++u)
#pragma unroll
    for (int v = 0; v < 4; ++v) G[tr * 4 + u][tc * 4 + v] = acc[u][v];
  __syncthreads();
  for (int l = t; l < 4096; l += 256) {
    int i = l >> 6, j = l & 63;
    float cc = fmaxf(G[i][i] + G[j][j] - 2.0f * G[i][j], 0.f);
    Cm[i][j] = cc;
    SB[l] = cc;
  }
  for (int ssz = 2; ssz <= 4096; ssz <<= 1) {
    for (int st = ssz >> 1; st > 0; st >>= 1) {
      __syncthreads();
      for (int l = t; l < 2048; l += 256) {
        int i = 2 * l - (l & (st - 1));
        int j = i + st;
        bool up = ((i & ssz) == 0);
        float a = SB[i], b2 = SB[j];
        if ((a > b2) == up) { SB[i] = b2; SB[j] = a; }
      }
    }
  }
  __syncthreads();
  if (t == 0) medsh = 0.5f * (SB[2047] + SB[2048]) + 1e-8f;
  __syncthreads();
  float inv = 1.0f / medsh;
  for (int l = t; l < 4096; l += 256) {
    int i = l >> 6, j = l & 63;
    float cn = Cm[i][j] * inv;
    Cm[i][j] = cn;
    G[i][j] = expf(-cn * 10.0f);
  }
  if (t < 64) {
    pv[t] = (t < 32) ? prewn[b * 32 + t] : 0.f;
    qv[t] = (t < 32) ? 0.f : postw[b * 32 + (t - 32)];
    uu[t] = 1.f; vv[t] = 1.f;
  }
  __syncthreads();
  int g = t >> 6, i0 = t & 63;
  for (int it = 0; it < 200; ++it) {
    float s2 = 0.f;
#pragma unroll
    for (int j2 = 0; j2 < 16; ++j2) s2 += G[i0][g * 16 + j2] * vv[g * 16 + j2];
    rbuf[g][i0] = s2;
    __syncthreads();
    if (t < 64) uu[t] = pv[t] / (rbuf[0][t] + rbuf[1][t] + rbuf[2][t] + rbuf[3][t] + 1e-16f);
    __syncthreads();
    s2 = 0.f;
#pragma unroll
    for (int j2 = 0; j2 < 16; ++j2) s2 += G[g * 16 + j2][i0] * uu[g * 16 + j2];
    rbuf[g][i0] = s2;
    __syncthreads();
    if (t < 64) vv[t] = qv[t] / (rbuf[0][t] + rbuf[1][t] + rbuf[2][t] + rbuf[3][t] + 1e-16f);
    __syncthreads();
  }
  float lacc = 0.f;
  for (int l = t; l < 4096; l += 256) {
    int i = l >> 6, j = l & 63;
    lacc += uu[i] * G[i][j] * vv[j] * Cm[i][j];
  }
  lacc = waveSum(lacc);
  if ((t & 63) == 0) rbuf[0][t >> 6] = lacc;
  __syncthreads();
  if (t == 0)
    atomicAdd(&scal[3], (rbuf[0][0] + rbuf[0][1] + rbuf[0][2] + rbuf[0][3]) * (1.0f / 256.0f));
}

// ---------------- sum(W^2) ----------------
__global__ void k_wreg(const float* __restrict__ W, float* __restrict__ scal) {
  __shared__ float red[4];
  int t = threadIdx.x;
  int base = blockIdx.x * 2048;
  float ss = 0.f;
#pragma unroll
  for (int p = 0; p < 8; ++p) {
    float v = W[base + p * 256 + t];
    ss += v * v;
  }
  ss = waveSum(ss);
  if ((t & 63) == 0) red[t >> 6] = ss;
  __syncthreads();
  if (t == 0) atomicAdd(&scal[4], red[0] + red[1] + red[2] + red[3]);
}

// ---------------- final combine ----------------
__global__ void k_combine(const float* __restrict__ mu_t, const float* __restrict__ colsum,
                          const float* __restrict__ scal, float* __restrict__ out) {
  __shared__ float red[8];
  int t = threadIdx.x;  // 512
  float dm = mu_t[t] - colsum[t] * (1.0f / 50000.0f);
  float v = dm * dm;
  v = waveSum(v);
  if ((t & 63) == 0) red[t >> 6] = v;
  __syncthreads();
  if (t == 0) {
    float term_mean = 0.f;
    for (int i = 0; i < 8; ++i) term_mean += red[i];
    float trCT = scal[0] * (1.0f / 255.0f);
    float trCX = scal[1];
    float S = scal[2];
    float term_cov = trCX * 1.001f + trCT * 1.001f - 2.0f * S;
    term_cov = fmaxf(term_cov, 0.f);
    float loss_dist = term_mean + term_cov;
    float loss_knn = scal[3];
    float loss_reg = 0.5f * scal[4];
    out[0] = loss_dist + loss_knn + 1e-4f * loss_reg;
    out[1] = loss_dist;
    out[2] = loss_knn;
  }
}

extern "C" void kernel_launch(void* const* d_in, const int* in_sizes, int n_in,
                              void* d_out, int out_size, void* d_ws, size_t ws_size,
                              hipStream_t stream) {
  const float* q = (const float*)d_in[0];
  const int* qidx = (const int*)d_in[1];
  const float* W = (const float*)d_in[2];
  const float* X = (const float*)d_in[3];
  const int* pre_idx = (const int*)d_in[4];
  const float* prew = (const float*)d_in[5];
  float* out = (float*)d_out;
  float* ws = (float*)d_ws;

  float* scal = ws + OFF_SC;
  float* colsum = ws + OFF_CS;
  float* colss = ws + OFF_CSS;
  float* T = ws + OFF_T;
  float* Tc = ws + OFF_TC;
  float* H = ws + OFF_H;
  float* mu_t = ws + OFF_MUT;
  float* xsq = ws + OFF_XSQ;
  int* runi = (int*)(ws + OFF_RUNI);
  float* postw = ws + OFF_PW;
  float* prewn = ws + OFF_PRW;
  float* V = ws + OFF_D2;
  float* UUT = ws + OFF_UUT;
  float* TcTc = ws + OFF_TCTC;
  float* wv = ws + OFF_W;
  float* m = ws + OFF_M;
  float* candv = ws + OFF_P;              // dead until NS Y2/Z2
  int* candi = (int*)(ws + OFF_P + 32768);

  hipMemsetAsync(d_ws, 0, (size_t)ZERO_F * 4, stream);

  // T = q @ W
  k_g64_nn<<<dim3(8, 4), 256, 0, stream>>>(q, W, T, 512, 512, 512, 512, 1.0f);
  // X stats
  k_colstatX<<<256, 256, 0, stream>>>(X, colsum, colss);
  k_xsq<<<12500, 256, 0, stream>>>(X, xsq);
  // T stats
  k_colmeanT<<<1, 512, 0, stream>>>(T, mu_t);
  k_centerT<<<128, 256, 0, stream>>>(T, mu_t, Tc, scal);
  k_trCX<<<1, 512, 0, stream>>>(colsum, colss, scal);
  // V = T @ X^T (MFMA)
  k_vgemm<<<dim3(391, 2), 256, 0, stream>>>(T, X, V);
  k_vstats<<<196, 256, 0, stream>>>(V, m);
  // kNN top-32 from d2 = xsq - 2V
  k_topk_part<<<dim3(4, 256), 128, 0, stream>>>(V, xsq, candv, candi);
  k_topk_final<<<256, 128, 0, stream>>>(candv, candi, runi);
  // H assembly: UUT (MFMA), TcTc, w
  k_g64_nt<<<dim3(4, 4), 256, 0, stream>>>(Tc, Tc, TcTc, 512, 512, 512, 256, 1.0f);
  k_wvec<<<1, 256, 0, stream>>>(T, colsum, wv);
  k_uut<<<dim3(3, 50), 256, 0, stream>>>(V, m, UUT);
  k_hfix<<<256, 256, 0, stream>>>(UUT, TcTc, wv, scal, H);
  // spectral sum via coupled Newton-Schulz, power-iter scaling
  {
    float* Y = ws + OFF_TC;
    float* Z = ws + OFF_TC + 65536;
    float* Y2 = ws + OFF_P;
    float* Z2 = ws + OFF_P + 65536;
    float* Pm = ws + OFF_G;  // UUT/TcTc dead after hfix
    k_power<<<1, 256, 0, stream>>>(H, scal);
    k_nsinit<<<256, 256, 0, stream>>>(H, scal, Y, Z);
    for (int it = 0; it < NS_ITERS; ++it) {
      k_g64_nn<<<dim3(4, 4), 256, 0, stream>>>(Z, Y, Pm, 256, 256, 256, 256, 1.0f);
      k_ns_upd<<<dim3(4, 4, 2), 256, 0, stream>>>(Y, Z, Pm, Y2, Z2);
      float* tmp = Y; Y = Y2; Y2 = tmp;
      tmp = Z; Z = Z2; Z2 = tmp;
    }
    k_ns_trace<<<1, 256, 0, stream>>>(Y, scal);
  }
  // kNN OT loss
  k_l2soft<<<256, 64, 0, stream>>>(T, X, runi, qidx, prew, postw, prewn);
  k_batch<<<256, 256, 0, stream>>>(X, qidx, pre_idx, runi, prewn, postw, scal);
  k_wreg<<<128, 256, 0, stream>>>(W, scal);
  k_combine<<<1, 512, 0, stream>>>(mu_t, colsum, scal, out);
}

// Round 6
// 1344.303 us; speedup vs baseline: 4.1559x; 1.1877x over previous
//
#include <hip/hip_runtime.h>
#include <float.h>
#include <math.h>

// Problem constants
#define BB 256
#define DD 512
#define NN 50000
#define KK 32
#define NS_ITERS 11
#define PARTS 8
#define PCH 6250

// Workspace layout (float offsets)
#define OFF_G     0         // 1M-float region: UUT(65536) + TcTc(65536) + w(256) + m(50000); NS Pm reuses +0
#define OFF_SC    262144    // 64 scalars: 0=sumTc2 1=trCX 2=S_total 3=knn 4=wreg 5=s_ns
#define OFF_CS    262208    // 512 colsum X
#define OFF_CSS   262720    // 512 colsumsq X
#define ZERO_F    263232    // floats to memset
#define OFF_T     263232    // 256*512
#define OFF_TC    394304    // 256*512 Tc; later NS Y/Z
#define OFF_P     525376    // 256*512: top-k cand buffers; later NS Y2/Z2
#define OFF_H     656448    // 256*256
#define OFF_MUT   722496    // 512
#define OFF_XSQ   723008    // 50000
#define OFF_RUNI  781200    // 256*32 (int)
#define OFF_PW    789392    // 256*32 post_w
#define OFF_PRW   797584    // 256*32 pre_w normalized
#define OFF_D2    805776    // V = T@X^T  (256*50000)

#define OFF_UUT   (OFF_G)
#define OFF_TCTC  (OFF_G + 65536)
#define OFF_W     (OFF_G + 131072)
#define OFF_M     (OFF_G + 131328)

typedef __attribute__((ext_vector_type(8))) short bf16x8;
typedef __attribute__((ext_vector_type(4))) float f32x4;

__device__ __forceinline__ float waveSum(float v) {
#pragma unroll
  for (int off = 32; off > 0; off >>= 1) v += __shfl_xor(v, off);
  return v;
}

// split fp32x4 -> bf16 hi/lo, write packed pairs to LDS at short-offset sa (16B-aligned rows)
__device__ __forceinline__ void cvt_write(float4 v, unsigned short* hi, unsigned short* lo, int sa) {
  unsigned int b0 = __float_as_uint(v.x), b1 = __float_as_uint(v.y);
  unsigned int b2 = __float_as_uint(v.z), b3 = __float_as_uint(v.w);
  unsigned int h0 = b0 & 0xffff0000u, h1 = b1 & 0xffff0000u;
  unsigned int h2 = b2 & 0xffff0000u, h3 = b3 & 0xffff0000u;
  float l0 = v.x - __uint_as_float(h0), l1 = v.y - __uint_as_float(h1);
  float l2 = v.z - __uint_as_float(h2), l3 = v.w - __uint_as_float(h3);
  *(unsigned int*)&hi[sa]     = (h0 >> 16) | h1;
  *(unsigned int*)&hi[sa + 2] = (h2 >> 16) | h3;
  *(unsigned int*)&lo[sa]     = (__float_as_uint(l0) >> 16) | (__float_as_uint(l1) & 0xffff0000u);
  *(unsigned int*)&lo[sa + 2] = (__float_as_uint(l2) >> 16) | (__float_as_uint(l3) & 0xffff0000u);
}

// ---------------- generic 64x64-tile GEMM, C = scale * A @ B (nn) ----------------
__global__ void __launch_bounds__(256) k_g64_nn(const float* __restrict__ A,
                                                const float* __restrict__ B,
                                                float* __restrict__ C,
                                                int K, int lda, int ldb, int ldc, float scale) {
  __shared__ float As[64][65], Bs[64][65];
  int m0 = blockIdx.y * 64, n0 = blockIdx.x * 64;
  int t = threadIdx.x, tr = t >> 4, tc = t & 15;
  float acc[4][4] = {{0.f}};
  for (int k0 = 0; k0 < K; k0 += 64) {
#pragma unroll
    for (int p = 0; p < 16; ++p) {
      int l = t + 256 * p;
      int r = l >> 6, c = l & 63;
      As[r][c] = A[(m0 + r) * lda + k0 + c];
      Bs[r][c] = B[(k0 + r) * ldb + n0 + c];
    }
    __syncthreads();
#pragma unroll 16
    for (int kk = 0; kk < 64; ++kk) {
      float a[4], b[4];
#pragma unroll
      for (int u = 0; u < 4; ++u) a[u] = As[tr + 16 * u][kk];
#pragma unroll
      for (int v = 0; v < 4; ++v) b[v] = Bs[kk][tc + 16 * v];
#pragma unroll
      for (int u = 0; u < 4; ++u)
#pragma unroll
        for (int v = 0; v < 4; ++v) acc[u][v] += a[u] * b[v];
    }
    __syncthreads();
  }
#pragma unroll
  for (int u = 0; u < 4; ++u)
#pragma unroll
    for (int v = 0; v < 4; ++v)
      C[(m0 + tr + 16 * u) * ldc + n0 + tc + 16 * v] = acc[u][v] * scale;
}

// ---------------- generic 64x64-tile GEMM, C = scale * A @ B^T (nt) ----------------
__global__ void __launch_bounds__(256) k_g64_nt(const float* __restrict__ A,
                                                const float* __restrict__ B,
                                                float* __restrict__ C,
                                                int K, int lda, int ldb, int ldc, float scale) {
  __shared__ float As[64][65], Bs[64][65];
  int m0 = blockIdx.y * 64, n0 = blockIdx.x * 64;
  int t = threadIdx.x, tr = t >> 4, tc = t & 15;
  float acc[4][4] = {{0.f}};
  for (int k0 = 0; k0 < K; k0 += 64) {
#pragma unroll
    for (int p = 0; p < 16; ++p) {
      int l = t + 256 * p;
      int r = l >> 6, c = l & 63;
      As[r][c] = A[(m0 + r) * lda + k0 + c];
      Bs[r][c] = B[(n0 + r) * ldb + k0 + c];
    }
    __syncthreads();
#pragma unroll 16
    for (int kk = 0; kk < 64; ++kk) {
      float a[4], b[4];
#pragma unroll
      for (int u = 0; u < 4; ++u) a[u] = As[tr + 16 * u][kk];
#pragma unroll
      for (int v = 0; v < 4; ++v) b[v] = Bs[tc + 16 * v][kk];
#pragma unroll
      for (int u = 0; u < 4; ++u)
#pragma unroll
        for (int v = 0; v < 4; ++v) acc[u][v] += a[u] * b[v];
    }
    __syncthreads();
  }
#pragma unroll
  for (int u = 0; u < 4; ++u)
#pragma unroll
    for (int v = 0; v < 4; ++v)
      C[(m0 + tr + 16 * u) * ldc + n0 + tc + 16 * v] = acc[u][v] * scale;
}

// ---------------- V = T @ X^T  (MFMA bf16-split, on-the-fly conversion) ----------------
__global__ void __launch_bounds__(256) k_vgemm(const float* __restrict__ T,
                                               const float* __restrict__ X,
                                               float* __restrict__ V) {
  __shared__ unsigned short Ah[128 * 72], Al[128 * 72], Bh[128 * 72], Bl[128 * 72];
  int bj = blockIdx.x, bi = blockIdx.y;
  int t = threadIdx.x;
  int wave = t >> 6, lane = t & 63;
  int m0 = (wave >> 1) * 64, n0 = (wave & 1) * 64;
  int lrow = lane & 15, lq = lane >> 4;
  f32x4 acc[4][4] = {};
  for (int kc = 0; kc < 512; kc += 64) {
#pragma unroll
    for (int f = 0; f < 8; ++f) {
      int lin = f * 256 + t;
      int r = lin >> 4, c4 = lin & 15;
      int sa = r * 72 + c4 * 4;
      float4 va = *(const float4*)&T[(bi * 128 + r) * 512 + kc + c4 * 4];
      cvt_write(va, Ah, Al, sa);
      int jg = bj * 128 + r;
      float4 vb = {0.f, 0.f, 0.f, 0.f};
      if (jg < NN) vb = *(const float4*)&X[(size_t)jg * 512 + kc + c4 * 4];
      cvt_write(vb, Bh, Bl, sa);
    }
    __syncthreads();
#pragma unroll
    for (int ks = 0; ks < 2; ++ks) {
      int kb = ks * 32 + lq * 8;
      bf16x8 ah[4], al[4], bh[4], bl[4];
#pragma unroll
      for (int mi = 0; mi < 4; ++mi) {
        int ro = (m0 + mi * 16 + lrow) * 72 + kb;
        ah[mi] = *(const bf16x8*)&Ah[ro];
        al[mi] = *(const bf16x8*)&Al[ro];
      }
#pragma unroll
      for (int nj = 0; nj < 4; ++nj) {
        int ro = (n0 + nj * 16 + lrow) * 72 + kb;
        bh[nj] = *(const bf16x8*)&Bh[ro];
        bl[nj] = *(const bf16x8*)&Bl[ro];
      }
#pragma unroll
      for (int mi = 0; mi < 4; ++mi)
#pragma unroll
        for (int nj = 0; nj < 4; ++nj) {
          acc[mi][nj] = __builtin_amdgcn_mfma_f32_16x16x32_bf16(ah[mi], bh[nj], acc[mi][nj], 0, 0, 0);
          acc[mi][nj] = __builtin_amdgcn_mfma_f32_16x16x32_bf16(ah[mi], bl[nj], acc[mi][nj], 0, 0, 0);
          acc[mi][nj] = __builtin_amdgcn_mfma_f32_16x16x32_bf16(al[mi], bh[nj], acc[mi][nj], 0, 0, 0);
        }
    }
    __syncthreads();
  }
#pragma unroll
  for (int mi = 0; mi < 4; ++mi)
#pragma unroll
    for (int nj = 0; nj < 4; ++nj)
#pragma unroll
      for (int r = 0; r < 4; ++r) {
        int row = bi * 128 + m0 + mi * 16 + lq * 4 + r;
        int col = bj * 128 + n0 + nj * 16 + lrow;
        if (col < NN) V[(size_t)row * NN + col] = acc[mi][nj][r];
      }
}

// ---------------- UUT += U @ U^T, U = V - m (MFMA bf16-split, split-K atomic) ----------------
__global__ void __launch_bounds__(256) k_uut(const float* __restrict__ V,
                                             const float* __restrict__ m,
                                             float* __restrict__ UUT) {
  __shared__ unsigned short Ah[128 * 72], Al[128 * 72], Bh[128 * 72], Bl[128 * 72];
  const int pi_[3] = {0, 0, 1}, pj_[3] = {0, 1, 1};
  int bi = pi_[blockIdx.x], bj = pj_[blockIdx.x];
  int j0 = blockIdx.y * 1000, jlim = j0 + 1000;
  int t = threadIdx.x;
  int wave = t >> 6, lane = t & 63;
  int m0 = (wave >> 1) * 64, n0 = (wave & 1) * 64;
  int lrow = lane & 15, lq = lane >> 4;
  f32x4 acc[4][4] = {};
  for (int ch = 0; ch < 16; ++ch) {
    int jc = j0 + ch * 64;
#pragma unroll
    for (int f = 0; f < 8; ++f) {
      int lin = f * 256 + t;
      int r = lin >> 4, c4 = lin & 15;
      int sa = r * 72 + c4 * 4;
      int jb = jc + c4 * 4;
      float4 va = {0.f, 0.f, 0.f, 0.f}, vb = {0.f, 0.f, 0.f, 0.f};
      if (jb < jlim) {
        float4 mm = *(const float4*)&m[jb];
        va = *(const float4*)&V[(size_t)(bi * 128 + r) * NN + jb];
        vb = *(const float4*)&V[(size_t)(bj * 128 + r) * NN + jb];
        va.x -= mm.x; va.y -= mm.y; va.z -= mm.z; va.w -= mm.w;
        vb.x -= mm.x; vb.y -= mm.y; vb.z -= mm.z; vb.w -= mm.w;
      }
      cvt_write(va, Ah, Al, sa);
      cvt_write(vb, Bh, Bl, sa);
    }
    __syncthreads();
#pragma unroll
    for (int ks = 0; ks < 2; ++ks) {
      int kb = ks * 32 + lq * 8;
      bf16x8 ah[4], al[4], bh[4], bl[4];
#pragma unroll
      for (int mi = 0; mi < 4; ++mi) {
        int ro = (m0 + mi * 16 + lrow) * 72 + kb;
        ah[mi] = *(const bf16x8*)&Ah[ro];
        al[mi] = *(const bf16x8*)&Al[ro];
      }
#pragma unroll
      for (int nj = 0; nj < 4; ++nj) {
        int ro = (n0 + nj * 16 + lrow) * 72 + kb;
        bh[nj] = *(const bf16x8*)&Bh[ro];
        bl[nj] = *(const bf16x8*)&Bl[ro];
      }
#pragma unroll
      for (int mi = 0; mi < 4; ++mi)
#pragma unroll
        for (int nj = 0; nj < 4; ++nj) {
          acc[mi][nj] = __builtin_amdgcn_mfma_f32_16x16x32_bf16(ah[mi], bh[nj], acc[mi][nj], 0, 0, 0);
          acc[mi][nj] = __builtin_amdgcn_mfma_f32_16x16x32_bf16(ah[mi], bl[nj], acc[mi][nj], 0, 0, 0);
          acc[mi][nj] = __builtin_amdgcn_mfma_f32_16x16x32_bf16(al[mi], bh[nj], acc[mi][nj], 0, 0, 0);
        }
    }
    __syncthreads();
  }
#pragma unroll
  for (int mi = 0; mi < 4; ++mi)
#pragma unroll
    for (int nj = 0; nj < 4; ++nj)
#pragma unroll
      for (int r = 0; r < 4; ++r) {
        int row = bi * 128 + m0 + mi * 16 + lq * 4 + r;
        int col = bj * 128 + n0 + nj * 16 + lrow;
        atomicAdd(&UUT[row * 256 + col], acc[mi][nj][r]);
      }
}

// ---------------- column sums & sumsq of X (atomic) ----------------
__global__ void k_colstatX(const float* __restrict__ X, float* __restrict__ colsum,
                           float* __restrict__ colss) {
  int b = blockIdx.x, t = threadIdx.x;
  int r0 = b * 196;
  int r1 = r0 + 196; if (r1 > NN) r1 = NN;
  float s1 = 0, ss1 = 0, s2 = 0, ss2 = 0;
  for (int r = r0; r < r1; ++r) {
    float v1 = X[(size_t)r * 512 + t], v2 = X[(size_t)r * 512 + t + 256];
    s1 += v1; ss1 += v1 * v1; s2 += v2; ss2 += v2 * v2;
  }
  atomicAdd(&colsum[t], s1);       atomicAdd(&colss[t], ss1);
  atomicAdd(&colsum[t + 256], s2); atomicAdd(&colss[t + 256], ss2);
}

// ---------------- per-row squared norm of X ----------------
__global__ void k_xsq(const float* __restrict__ X, float* __restrict__ xsq) {
  int row = blockIdx.x * 4 + (threadIdx.x >> 6);
  int lane = threadIdx.x & 63;
  const float* Xr = X + (size_t)row * 512;
  float s = 0.f;
#pragma unroll
  for (int d = 0; d < 8; ++d) { float v = Xr[lane + 64 * d]; s += v * v; }
  s = waveSum(s);
  if (lane == 0) xsq[row] = s;
}

// ---------------- column means of T ----------------
__global__ void k_colmeanT(const float* __restrict__ T, float* __restrict__ mu) {
  int c = threadIdx.x;
  float s = 0.f;
  for (int r = 0; r < 256; ++r) s += T[r * 512 + c];
  mu[c] = s * (1.0f / 256.0f);
}

// ---------------- Tc = T - mu, accumulate sum(Tc^2) ----------------
__global__ void k_centerT(const float* __restrict__ T, const float* __restrict__ mu,
                          float* __restrict__ Tc, float* __restrict__ scal) {
  __shared__ float red[4];
  int t = threadIdx.x;
  int base = blockIdx.x * 1024;
  float ss = 0.f;
#pragma unroll
  for (int p = 0; p < 4; ++p) {
    int l = base + p * 256 + t;
    float v = T[l] - mu[l & 511];
    Tc[l] = v;
    ss += v * v;
  }
  ss = waveSum(ss);
  if ((t & 63) == 0) red[t >> 6] = ss;
  __syncthreads();
  if (t == 0) atomicAdd(&scal[0], red[0] + red[1] + red[2] + red[3]);
}

// ---------------- trace of cov(X) ----------------
__global__ void k_trCX(const float* __restrict__ colsum, const float* __restrict__ colss,
                       float* __restrict__ scal) {
  __shared__ float red[8];
  int t = threadIdx.x;  // 512
  float mu = colsum[t] * (1.0f / 50000.0f);
  float v = (colss[t] - 50000.0f * mu * mu) * (1.0f / 49999.0f);
  v = waveSum(v);
  if ((t & 63) == 0) red[t >> 6] = v;
  __syncthreads();
  if (t == 0) {
    float s = 0;
    for (int i = 0; i < 8; ++i) s += red[i];
    scal[1] = s;
  }
}

// ---------------- colmeans of V -> m ----------------
__global__ void k_vstats(const float* __restrict__ V, float* __restrict__ m) {
  int j = blockIdx.x * 256 + threadIdx.x;
  if (j >= NN) return;
  float s = 0.f;
  for (int i = 0; i < 256; ++i) s += V[(size_t)i * NN + j];
  m[j] = s * (1.0f / 256.0f);
}

// ---------------- w_i = Tc_i . muX ----------------
__global__ void __launch_bounds__(256) k_wvec(const float* __restrict__ T,
                                              const float* __restrict__ colsum,
                                              float* __restrict__ w) {
  __shared__ float cs[512];
  __shared__ float red[4];
  int t = threadIdx.x;
  cs[t] = colsum[t] * (1.0f / 50000.0f);
  cs[t + 256] = colsum[t + 256] * (1.0f / 50000.0f);
  __syncthreads();
  float a = 0.f;
  for (int c = 0; c < 512; ++c) a += T[t * 512 + c] * cs[c];
  float s = waveSum(a);
  if ((t & 63) == 0) red[t >> 6] = s;
  __syncthreads();
  float mean = (red[0] + red[1] + red[2] + red[3]) * (1.0f / 256.0f);
  w[t] = a - mean;
}

// ---------------- H = (UUT - N w w^T)/(49999*255) + rhoX * TcTc/255 ----------------
__global__ void k_hfix(const float* __restrict__ UUT, const float* __restrict__ TcTc,
                       const float* __restrict__ w, const float* __restrict__ scal,
                       float* __restrict__ H) {
  int l = blockIdx.x * 256 + threadIdx.x;
  int i = l >> 8, j = l & 255;
  float u = (i >= 128 && j < 128) ? UUT[j * 256 + i] : UUT[i * 256 + j];
  float rho = scal[1] * (1e-3f / 512.0f);
  H[l] = (u - 50000.0f * w[i] * w[j]) * (1.0f / (49999.0f * 255.0f))
       + rho * TcTc[i * 256 + j] * (1.0f / 255.0f);
}

// ---------------- power iteration: scal[5] = safe lambda_max bound of H' ----------------
__global__ void __launch_bounds__(256) k_power(const float* __restrict__ H,
                                               float* __restrict__ scal) {
  __shared__ float v[256], nv[256], red[4];
  int t = threadIdx.x;
  float rt = scal[0] * (1.0f / 255.0f) * (1e-3f / 512.0f);
  v[t] = 1.0f;
  __syncthreads();
  float n2 = 256.0f, n3 = 256.0f;
  for (int it = 0; it < 3; ++it) {
    float s = rt * v[t];
    for (int j = 0; j < 256; ++j) s += H[t * 256 + j] * v[j];
    nv[t] = s;
    float ss = waveSum(s * s);
    if ((t & 63) == 0) red[t >> 6] = ss;
    __syncthreads();
    float norm2 = red[0] + red[1] + red[2] + red[3];
    if (it == 1) n2 = norm2;
    if (it == 2) n3 = norm2;
    v[t] = nv[t];
    __syncthreads();
  }
  float d = H[t * 256 + t] + rt;
#pragma unroll
  for (int off = 32; off > 0; off >>= 1) d = fmaxf(d, __shfl_xor(d, off));
  if ((t & 63) == 0) red[t >> 6] = d;
  __syncthreads();
  if (t == 0) {
    float lam = sqrtf(n3 / n2);
    float md = fmaxf(fmaxf(red[0], red[1]), fmaxf(red[2], red[3]));
    scal[5] = fmaxf(1.3f * lam, md);
  }
}

// ---------------- Y0 = (H + rt I)/s, Z0 = I ----------------
__global__ void k_nsinit(const float* __restrict__ H, const float* __restrict__ scal,
                         float* __restrict__ Y, float* __restrict__ Z) {
  int l = blockIdx.x * 256 + threadIdx.x;
  int i = l >> 8, j = l & 255;
  float rt = scal[0] * (1.0f / 255.0f) * (1e-3f / 512.0f);
  float inv = 1.0f / scal[5];
  Y[l] = (H[l] + ((i == j) ? rt : 0.f)) * inv;
  Z[l] = (i == j) ? 1.0f : 0.f;
}

// ---------------- NS update ----------------
__global__ void __launch_bounds__(256) k_ns_upd(const float* __restrict__ Y, const float* __restrict__ Z,
                                                const float* __restrict__ P,
                                                float* __restrict__ Yn, float* __restrict__ Zn) {
  __shared__ float As[64][65], Bs[64][65];
  int bi = blockIdx.x, bj = blockIdx.y, zz = blockIdx.z;
  const float* A = zz ? P : Y;
  const float* B = zz ? Z : P;
  const float* D = zz ? Z : Y;
  float* O = zz ? Zn : Yn;
  int t = threadIdx.x;
  int tr = t >> 4, tc = t & 15;
  float acc[4][4] = {{0.f}};
  for (int k0 = 0; k0 < 256; k0 += 64) {
#pragma unroll
    for (int p = 0; p < 16; ++p) {
      int l = t + 256 * p;
      int r = l >> 6, c = l & 63;
      As[r][c] = A[(bi * 64 + r) * 256 + k0 + c];
      Bs[r][c] = B[(k0 + r) * 256 + bj * 64 + c];
    }
    __syncthreads();
#pragma unroll 16
    for (int kk = 0; kk < 64; ++kk) {
      float a[4], b[4];
#pragma unroll
      for (int u = 0; u < 4; ++u) a[u] = As[tr + 16 * u][kk];
#pragma unroll
      for (int v = 0; v < 4; ++v) b[v] = Bs[kk][tc + 16 * v];
#pragma unroll
      for (int u = 0; u < 4; ++u)
#pragma unroll
        for (int v = 0; v < 4; ++v) acc[u][v] += a[u] * b[v];
    }
    __syncthreads();
  }
#pragma unroll
  for (int u = 0; u < 4; ++u)
#pragma unroll
    for (int v = 0; v < 4; ++v) {
      int idx = (bi * 64 + tr + 16 * u) * 256 + bj * 64 + tc + 16 * v;
      O[idx] = 1.5f * D[idx] - 0.5f * acc[u][v];
    }
}

// ---------------- S_total = sqrt(s)*tr(Y) + 256*sqrt(rt) ----------------
__global__ void k_ns_trace(const float* __restrict__ Y, float* __restrict__ scal) {
  __shared__ float red[4];
  int t = threadIdx.x;  // 256
  float v = Y[t * 256 + t];
  v = waveSum(v);
  if ((t & 63) == 0) red[t >> 6] = v;
  __syncthreads();
  if (t == 0) {
    float tr = red[0] + red[1] + red[2] + red[3];
    float rt = scal[0] * (1.0f / 255.0f) * (1e-3f / 512.0f);
    scal[2] = sqrtf(scal[5]) * tr + 256.0f * sqrtf(rt);
  }
}

// ---------------- stage 1: threshold-filter exact top-32 per (query, 1/8-slice) ----------------
// 256 threads; LDS candidate buffer (512) + running (tau_v, tau_i) = 32nd-best-so-far.
__global__ void __launch_bounds__(256) k_topk_part(const float* __restrict__ V,
                                                   const float* __restrict__ xsq,
                                                   float* __restrict__ candv,
                                                   int* __restrict__ candi) {
  __shared__ float bufv[512];
  __shared__ int bufi[512];
  __shared__ int lcount;
  __shared__ float tvs;
  __shared__ int tis;
  int part = blockIdx.x, q = blockIdx.y, t = threadIdx.x;
  int base = part * PCH;
  int lane = t & 63;
  if (t == 0) { lcount = 0; tvs = FLT_MAX; tis = 0x7fffffff; }
  __syncthreads();
  const float* rowV = V + (size_t)q * NN + base;
  const float* xs = xsq + base;

  auto flush = [&]() {
    __syncthreads();
    int c = lcount;
    for (int s = c + t; s < 512; s += 256) { bufv[s] = FLT_MAX; bufi[s] = 0x7fffffff; }
    __syncthreads();
    for (int ssz = 2; ssz <= 512; ssz <<= 1) {
      for (int st = ssz >> 1; st > 0; st >>= 1) {
        int i = 2 * t - (t & (st - 1));
        int j = i + st;
        bool up = ((i & ssz) == 0);
        float a = bufv[i], b = bufv[j];
        int ai = bufi[i], bi2 = bufi[j];
        bool agtb = (a > b) || (a == b && ai > bi2);
        if (agtb == up) { bufv[i] = b; bufv[j] = a; bufi[i] = bi2; bufi[j] = ai; }
        __syncthreads();
      }
    }
    if (t == 0) { lcount = 32; tvs = bufv[31]; tis = bufi[31]; }
    __syncthreads();
  };

  int ntile = (PCH + 255) >> 8;
  for (int tile = 0; tile < ntile; ++tile) {
    int j = tile * 256 + t;
    float val = 0.f; int idx = 0;
    bool pred = false;
    if (j < PCH) {
      val = xs[j] - 2.0f * rowV[j];
      idx = base + j;
      float tv = tvs; int ti = tis;
      pred = (val < tv) || (val == tv && idx < ti);
    }
    unsigned long long mask = __ballot(pred);
    if (mask) {
      int lead = __ffsll((unsigned long long)mask) - 1;
      int cnt = __popcll(mask);
      int basep = 0;
      if (lane == lead) basep = atomicAdd(&lcount, cnt);
      basep = __shfl(basep, lead);
      if (pred) {
        int off = __popcll(mask & ((1ull << lane) - 1ull));
        int slot = basep + off;
        bufv[slot] = val; bufi[slot] = idx;
      }
    }
    __syncthreads();
    if (lcount >= 256) flush();
  }
  flush();
  if (t < 32) {
    candv[(q * PARTS + part) * 32 + t] = bufv[t];
    candi[(q * PARTS + part) * 32 + t] = bufi[t];
  }
}

// ---------------- stage 2: bitonic-sort 256 candidates, emit top-32 indices ----------------
__global__ void __launch_bounds__(128) k_topk_final(const float* __restrict__ candv,
                                                    const int* __restrict__ candi,
                                                    int* __restrict__ runi) {
  __shared__ float v[256];
  __shared__ int ix[256];
  int q = blockIdx.x, t = threadIdx.x;
  v[t] = candv[q * 256 + t];
  v[t + 128] = candv[q * 256 + t + 128];
  ix[t] = candi[q * 256 + t];
  ix[t + 128] = candi[q * 256 + t + 128];
  __syncthreads();
  for (int ssz = 2; ssz <= 256; ssz <<= 1) {
    for (int st = ssz >> 1; st > 0; st >>= 1) {
      int i = 2 * t - (t & (st - 1));
      int j = i + st;
      bool up = ((i & ssz) == 0);
      float a = v[i], b = v[j];
      int ai = ix[i], bi = ix[j];
      bool agtb = (a > b) || (a == b && ai > bi);
      if (agtb == up) { v[i] = b; v[j] = a; ix[i] = bi; ix[j] = ai; }
      __syncthreads();
    }
  }
  if (t < 32) runi[q * 32 + t] = ix[t];
}

// ---------------- l2 to neighbors, softmax post_w, normalized pre_w ----------------
__global__ void __launch_bounds__(64) k_l2soft(const float* __restrict__ T, const float* __restrict__ X,
                                               const int* __restrict__ runi, const int* __restrict__ qidx,
                                               const float* __restrict__ prew, float* __restrict__ postw,
                                               float* __restrict__ prewn) {
  __shared__ float l2s[32];
  int b = blockIdx.x, lane = threadIdx.x;
  int qi = qidx[b];
  float pwv = (lane < 32) ? fmaxf(prew[qi * 32 + lane], 1e-8f) : 0.f;
  float psum = waveSum(pwv);
  if (lane < 32) prewn[b * 32 + lane] = pwv / psum;
  const float* Tb = T + b * 512;
  for (int n = 0; n < 32; ++n) {
    int nb = runi[b * 32 + n];
    const float* Xr = X + (size_t)nb * 512;
    float acc = 0.f;
#pragma unroll
    for (int d = 0; d < 8; ++d) {
      float df = Tb[lane + 64 * d] - Xr[lane + 64 * d];
      acc += df * df;
    }
    acc = waveSum(acc);
    if (lane == 0) l2s[n] = acc;
  }
  __syncthreads();
  float lg = (lane < 32) ? (-l2s[lane] * 10.0f) : -FLT_MAX;
  float mx = lg;
#pragma unroll
  for (int off = 32; off > 0; off >>= 1) mx = fmaxf(mx, __shfl_xor(mx, off));
  float e = (lane < 32) ? expf(lg - mx) : 0.f;
  float es = waveSum(e);
  float wv = e / es;
  wv = fmaxf(wv, 1e-8f);
  float ws2 = (lane < 32) ? wv : 0.f;
  ws2 = waveSum(ws2);
  if (lane < 32) postw[b * 32 + lane] = wv / ws2;
}

// ---------------- fused per-batch: Gram -> C -> median -> Sinkhorn(200) -> loss ----------------
__global__ void __launch_bounds__(256) k_batch(const float* __restrict__ X, const int* __restrict__ qidx,
                                               const int* __restrict__ pre_idx, const int* __restrict__ runi,
                                               const float* __restrict__ prewn, const float* __restrict__ postw,
                                               float* __restrict__ scal) {
  __shared__ float G[64][65];
  __shared__ float Cm[64][65];
  __shared__ float SB[4160];
  __shared__ int supp[64];
  __shared__ float pv[64], qv[64], uu[64], vv[64];
  __shared__ float rbuf[4][64];
  __shared__ float medsh;
  int b = blockIdx.x, t = threadIdx.x;
  if (t < 32) supp[t] = pre_idx[qidx[b] * 32 + t];
  else if (t < 64) supp[t] = runi[b * 32 + t - 32];
  __syncthreads();
  int tr = t >> 4, tc = t & 15;
  float acc[4][4] = {{0.f}};
  for (int kc = 0; kc < 512; kc += 64) {
    __syncthreads();
#pragma unroll
    for (int p2 = 0; p2 < 16; ++p2) {
      int l = t + 256 * p2;
      int r = l >> 6, c = l & 63;
      SB[r * 65 + c] = X[(size_t)supp[r] * 512 + kc + c];
    }
    __syncthreads();
#pragma unroll 8
    for (int kk = 0; kk < 64; ++kk) {
      float a[4], bb[4];
#pragma unroll
      for (int u = 0; u < 4; ++u) a[u] = SB[(tr * 4 + u) * 65 + kk];
#pragma unroll
      for (int v = 0; v < 4; ++v) bb[v] = SB[(tc * 4 + v) * 65 + kk];
#pragma unroll
      for (int u = 0; u < 4; ++u)
#pragma unroll
        for (int v = 0; v < 4; ++v) acc[u][v] += a[u] * bb[v];
    }
  }
  __syncthreads();
#pragma unroll
  for (int u = 0; u < 4; ++u)
#pragma unroll
    for (int v = 0; v < 4; ++v) G[tr * 4 + u][tc * 4 + v] = acc[u][v];
  __syncthreads();
  for (int l = t; l < 4096; l += 256) {
    int i = l >> 6, j = l & 63;
    float cc = fmaxf(G[i][i] + G[j][j] - 2.0f * G[i][j], 0.f);
    Cm[i][j] = cc;
    SB[l] = cc;
  }
  for (int ssz = 2; ssz <= 4096; ssz <<= 1) {
    for (int st = ssz >> 1; st > 0; st >>= 1) {
      __syncthreads();
      for (int l = t; l < 2048; l += 256) {
        int i = 2 * l - (l & (st - 1));
        int j = i + st;
        bool up = ((i & ssz) == 0);
        float a = SB[i], b2 = SB[j];
        if ((a > b2) == up) { SB[i] = b2; SB[j] = a; }
      }
    }
  }
  __syncthreads();
  if (t == 0) medsh = 0.5f * (SB[2047] + SB[2048]) + 1e-8f;
  __syncthreads();
  float inv = 1.0f / medsh;
  for (int l = t; l < 4096; l += 256) {
    int i = l >> 6, j = l & 63;
    float cn = Cm[i][j] * inv;
    Cm[i][j] = cn;
    G[i][j] = expf(-cn * 10.0f);
  }
  if (t < 64) {
    pv[t] = (t < 32) ? prewn[b * 32 + t] : 0.f;
    qv[t] = (t < 32) ? 0.f : postw[b * 32 + (t - 32)];
    uu[t] = 1.f; vv[t] = 1.f;
  }
  __syncthreads();
  int g = t >> 6, i0 = t & 63;
  for (int it = 0; it < 200; ++it) {
    float s2 = 0.f;
#pragma unroll
    for (int j2 = 0; j2 < 16; ++j2) s2 += G[i0][g * 16 + j2] * vv[g * 16 + j2];
    rbuf[g][i0] = s2;
    __syncthreads();
    if (t < 64) uu[t] = pv[t] / (rbuf[0][t] + rbuf[1][t] + rbuf[2][t] + rbuf[3][t] + 1e-16f);
    __syncthreads();
    s2 = 0.f;
#pragma unroll
    for (int j2 = 0; j2 < 16; ++j2) s2 += G[g * 16 + j2][i0] * uu[g * 16 + j2];
    rbuf[g][i0] = s2;
    __syncthreads();
    if (t < 64) vv[t] = qv[t] / (rbuf[0][t] + rbuf[1][t] + rbuf[2][t] + rbuf[3][t] + 1e-16f);
    __syncthreads();
  }
  float lacc = 0.f;
  for (int l = t; l < 4096; l += 256) {
    int i = l >> 6, j = l & 63;
    lacc += uu[i] * G[i][j] * vv[j] * Cm[i][j];
  }
  lacc = waveSum(lacc);
  if ((t & 63) == 0) rbuf[0][t >> 6] = lacc;
  __syncthreads();
  if (t == 0)
    atomicAdd(&scal[3], (rbuf[0][0] + rbuf[0][1] + rbuf[0][2] + rbuf[0][3]) * (1.0f / 256.0f));
}

// ---------------- sum(W^2) ----------------
__global__ void k_wreg(const float* __restrict__ W, float* __restrict__ scal) {
  __shared__ float red[4];
  int t = threadIdx.x;
  int base = blockIdx.x * 2048;
  float ss = 0.f;
#pragma unroll
  for (int p = 0; p < 8; ++p) {
    float v = W[base + p * 256 + t];
    ss += v * v;
  }
  ss = waveSum(ss);
  if ((t & 63) == 0) red[t >> 6] = ss;
  __syncthreads();
  if (t == 0) atomicAdd(&scal[4], red[0] + red[1] + red[2] + red[3]);
}

// ---------------- final combine ----------------
__global__ void k_combine(const float* __restrict__ mu_t, const float* __restrict__ colsum,
                          const float* __restrict__ scal, float* __restrict__ out) {
  __shared__ float red[8];
  int t = threadIdx.x;  // 512
  float dm = mu_t[t] - colsum[t] * (1.0f / 50000.0f);
  float v = dm * dm;
  v = waveSum(v);
  if ((t & 63) == 0) red[t >> 6] = v;
  __syncthreads();
  if (t == 0) {
    float term_mean = 0.f;
    for (int i = 0; i < 8; ++i) term_mean += red[i];
    float trCT = scal[0] * (1.0f / 255.0f);
    float trCX = scal[1];
    float S = scal[2];
    float term_cov = trCX * 1.001f + trCT * 1.001f - 2.0f * S;
    term_cov = fmaxf(term_cov, 0.f);
    float loss_dist = term_mean + term_cov;
    float loss_knn = scal[3];
    float loss_reg = 0.5f * scal[4];
    out[0] = loss_dist + loss_knn + 1e-4f * loss_reg;
    out[1] = loss_dist;
    out[2] = loss_knn;
  }
}

extern "C" void kernel_launch(void* const* d_in, const int* in_sizes, int n_in,
                              void* d_out, int out_size, void* d_ws, size_t ws_size,
                              hipStream_t stream) {
  const float* q = (const float*)d_in[0];
  const int* qidx = (const int*)d_in[1];
  const float* W = (const float*)d_in[2];
  const float* X = (const float*)d_in[3];
  const int* pre_idx = (const int*)d_in[4];
  const float* prew = (const float*)d_in[5];
  float* out = (float*)d_out;
  float* ws = (float*)d_ws;

  float* scal = ws + OFF_SC;
  float* colsum = ws + OFF_CS;
  float* colss = ws + OFF_CSS;
  float* T = ws + OFF_T;
  float* Tc = ws + OFF_TC;
  float* H = ws + OFF_H;
  float* mu_t = ws + OFF_MUT;
  float* xsq = ws + OFF_XSQ;
  int* runi = (int*)(ws + OFF_RUNI);
  float* postw = ws + OFF_PW;
  float* prewn = ws + OFF_PRW;
  float* V = ws + OFF_D2;
  float* UUT = ws + OFF_UUT;
  float* TcTc = ws + OFF_TCTC;
  float* wv = ws + OFF_W;
  float* m = ws + OFF_M;
  float* candv = ws + OFF_P;              // 256*256 floats; dead before NS Y2/Z2
  int* candi = (int*)(ws + OFF_P + 65536);

  hipMemsetAsync(d_ws, 0, (size_t)ZERO_F * 4, stream);

  // T = q @ W
  k_g64_nn<<<dim3(8, 4), 256, 0, stream>>>(q, W, T, 512, 512, 512, 512, 1.0f);
  // X stats
  k_colstatX<<<256, 256, 0, stream>>>(X, colsum, colss);
  k_xsq<<<12500, 256, 0, stream>>>(X, xsq);
  // T stats
  k_colmeanT<<<1, 512, 0, stream>>>(T, mu_t);
  k_centerT<<<128, 256, 0, stream>>>(T, mu_t, Tc, scal);
  k_trCX<<<1, 512, 0, stream>>>(colsum, colss, scal);
  // V = T @ X^T (MFMA)
  k_vgemm<<<dim3(391, 2), 256, 0, stream>>>(T, X, V);
  k_vstats<<<196, 256, 0, stream>>>(V, m);
  // kNN top-32 from d2 = xsq - 2V (threshold-filter)
  k_topk_part<<<dim3(PARTS, 256), 256, 0, stream>>>(V, xsq, candv, candi);
  k_topk_final<<<256, 128, 0, stream>>>(candv, candi, runi);
  // H assembly
  k_g64_nt<<<dim3(4, 4), 256, 0, stream>>>(Tc, Tc, TcTc, 512, 512, 512, 256, 1.0f);
  k_wvec<<<1, 256, 0, stream>>>(T, colsum, wv);
  k_uut<<<dim3(3, 50), 256, 0, stream>>>(V, m, UUT);
  k_hfix<<<256, 256, 0, stream>>>(UUT, TcTc, wv, scal, H);
  // spectral sum via coupled Newton-Schulz, power-iter scaling
  {
    float* Y = ws + OFF_TC;
    float* Z = ws + OFF_TC + 65536;
    float* Y2 = ws + OFF_P;
    float* Z2 = ws + OFF_P + 65536;
    float* Pm = ws + OFF_G;
    k_power<<<1, 256, 0, stream>>>(H, scal);
    k_nsinit<<<256, 256, 0, stream>>>(H, scal, Y, Z);
    for (int it = 0; it < NS_ITERS; ++it) {
      k_g64_nn<<<dim3(4, 4), 256, 0, stream>>>(Z, Y, Pm, 256, 256, 256, 256, 1.0f);
      k_ns_upd<<<dim3(4, 4, 2), 256, 0, stream>>>(Y, Z, Pm, Y2, Z2);
      float* tmp = Y; Y = Y2; Y2 = tmp;
      tmp = Z; Z = Z2; Z2 = tmp;
    }
    k_ns_trace<<<1, 256, 0, stream>>>(Y, scal);
  }
  // kNN OT loss
  k_l2soft<<<256, 64, 0, stream>>>(T, X, runi, qidx, prew, postw, prewn);
  k_batch<<<256, 256, 0, stream>>>(X, qidx, pre_idx, runi, prewn, postw, scal);
  k_wreg<<<128, 256, 0, stream>>>(W, scal);
  k_combine<<<1, 512, 0, stream>>>(mu_t, colsum, scal, out);
}